// Round 2
// baseline (29370.602 us; speedup 1.0000x reference)
//
#include <hip/hip_runtime.h>
#include <cstdint>
#include <cstddef>

#define B_      16
#define N_      2048
#define NOTE_   512
#define BEAT_H_ 128
#define MEAS_H_ 64
#define NBEATS_ 256
#define NMEAS_  64
#define OUT_    11
#define D_      10
// fin = 715 (512 note + 128 beat + 64 meas + 11 prev_out)
// tin = 203 (128 beat + 64 meas + 1 tempo + 10 beat_results)

__device__ __forceinline__ float sigm_(float x) { return 1.0f / (1.0f + expf(-x)); }

// ---------------------------------------------------------------------------
// pad flags: pad[b,i] = (sum_k note_emb[b,i,k] == 0)
// ---------------------------------------------------------------------------
__global__ __launch_bounds__(256) void pad_k(const float* __restrict__ note,
                                             int* __restrict__ padf) {
    int wave = threadIdx.x >> 6, lane = threadIdx.x & 63;
    int r = blockIdx.x * 4 + wave;
    const float* row = note + ((size_t)r << 9);
    float s = 0.f;
#pragma unroll
    for (int u = 0; u < 8; ++u) s += row[lane + (u << 6)];
#pragma unroll
    for (int off = 32; off; off >>= 1) s += __shfl_xor(s, off, 64);
    if (lane == 0) padf[r] = (s == 0.0f) ? 1 : 0;
}

// ---------------------------------------------------------------------------
// tempo_pre[b,q,j] = Wih_t[j,0:128]·beat_emb[b,q] + Wih_t[j,128:192]·meas_emb[b,cm(q)]
//                    + bih_t[j] + bhh_t[j]
// ---------------------------------------------------------------------------
__global__ __launch_bounds__(256) void tempo_pre_k(
    const float* __restrict__ beat, const float* __restrict__ meas,
    const int* __restrict__ bnum, const int* __restrict__ mnum,
    const float* __restrict__ Wih_t, const float* __restrict__ bih_t,
    const float* __restrict__ bhh_t, float* __restrict__ tpre) {
    __shared__ float sin_[16][192];
    int b = blockIdx.x, qt = blockIdx.y;
    int t = threadIdx.x;
    int bn0 = bnum[b << 11], mn0 = mnum[b << 11];
    for (int idx = t; idx < 16 * 192; idx += 256) {
        int qq = idx / 192, kk = idx - qq * 192;
        int q = qt * 16 + qq;
        float v;
        if (kk < 128) {
            v = beat[(size_t)(b * NBEATS_ + q) * 128 + kk];
        } else {
            int cm = ((q + bn0) >> 2) - mn0;
            if (cm > 63) cm = 63;
            if (cm < 0) cm = 0;
            v = meas[(size_t)(b * NMEAS_ + cm) * 64 + (kk - 128)];
        }
        sin_[qq][kk] = v;
    }
    __syncthreads();
    for (int half = 0; half < 2; ++half) {
        int j = t + half * 256;
        const float* wr = Wih_t + (size_t)j * 203;
        float bias = bih_t[j] + bhh_t[j];
        float acc[16] = {};
        for (int k = 0; k < 192; ++k) {
            float w = wr[k];
#pragma unroll
            for (int qq = 0; qq < 16; ++qq) acc[qq] += w * sin_[qq][k];
        }
        for (int qq = 0; qq < 16; ++qq)
            tpre[(size_t)(b * NBEATS_ + qt * 16 + qq) * 512 + j] = acc[qq] + bias;
    }
}

// ---------------------------------------------------------------------------
// fin_pre[r, j] = [note(512) | beat(128) | meas(64)] · Wih_f[j,0:704] + biases
// ---------------------------------------------------------------------------
__global__ __launch_bounds__(256) void fin_pre_gemm(
    const float* __restrict__ note, const float* __restrict__ beat,
    const float* __restrict__ meas, const int* __restrict__ bnum,
    const int* __restrict__ mnum, const float* __restrict__ Wih_f,
    const float* __restrict__ bih_f, const float* __restrict__ bhh_f,
    float* __restrict__ finp) {
    __shared__ float As[16][64];
    __shared__ float Bs[16][64];
    int t = threadIdx.x;
    int r0 = blockIdx.x * 64;
    int j0 = blockIdx.y * 64;

    int am = t >> 2, alane = t & 3;
    int r = r0 + am;
    int b = r >> 11;
    int rb = b << 11;
    int cb = bnum[r] - bnum[rb];
    int cm = mnum[r] - mnum[rb];
    const float* arow_note = note + ((size_t)r << 9);
    const float* arow_beat = beat + ((size_t)(b * NBEATS_ + cb) << 7);
    const float* arow_meas = meas + ((size_t)(b * NMEAS_ + cm) << 6);

    int jj = t >> 2, blane = t & 3;
    const float* brow = Wih_f + (size_t)(j0 + jj) * 715;

    int tm0 = (t & 15) * 4, tn0 = (t >> 4) * 4;
    float acc[4][4] = {};

    for (int k0 = 0; k0 < 704; k0 += 16) {
        int ka = k0 + alane * 4;
        float4 av;
        if (ka < 512)      av = *(const float4*)(arow_note + ka);
        else if (ka < 640) av = *(const float4*)(arow_beat + (ka - 512));
        else               av = *(const float4*)(arow_meas + (ka - 640));
        int kb = k0 + blane * 4;
        float b0 = brow[kb], b1 = brow[kb + 1], b2 = brow[kb + 2], b3 = brow[kb + 3];
        __syncthreads();
        As[alane * 4 + 0][am] = av.x;
        As[alane * 4 + 1][am] = av.y;
        As[alane * 4 + 2][am] = av.z;
        As[alane * 4 + 3][am] = av.w;
        Bs[blane * 4 + 0][jj] = b0;
        Bs[blane * 4 + 1][jj] = b1;
        Bs[blane * 4 + 2][jj] = b2;
        Bs[blane * 4 + 3][jj] = b3;
        __syncthreads();
#pragma unroll
        for (int kk = 0; kk < 16; ++kk) {
            float4 a4 = *(const float4*)&As[kk][tm0];
            float4 b4 = *(const float4*)&Bs[kk][tn0];
            float aa[4] = {a4.x, a4.y, a4.z, a4.w};
            float bb[4] = {b4.x, b4.y, b4.z, b4.w};
#pragma unroll
            for (int mi = 0; mi < 4; ++mi)
#pragma unroll
                for (int ni = 0; ni < 4; ++ni) acc[mi][ni] += aa[mi] * bb[ni];
        }
    }
    float bias[4];
#pragma unroll
    for (int ni = 0; ni < 4; ++ni) {
        int j = j0 + tn0 + ni;
        bias[ni] = bih_f[j] + bhh_f[j];
    }
#pragma unroll
    for (int mi = 0; mi < 4; ++mi) {
        int rr = r0 + tm0 + mi;
        float4 o;
        o.x = acc[mi][0] + bias[0];
        o.y = acc[mi][1] + bias[1];
        o.z = acc[mi][2] + bias[2];
        o.w = acc[mi][3] + bias[3];
        *(float4*)(finp + ((size_t)rr << 9) + j0 + tn0) = o;
    }
}

// ---------------------------------------------------------------------------
// sequential decoder: 1024 threads/block, half-row of Whh per thread (64 VGPR)
// 2 barriers per unchanged step, single-wave gate phase, prefetched loads,
// delayed output stores.
// ---------------------------------------------------------------------------
__global__ __launch_bounds__(1024, 4) void decode_seq(
    const float* __restrict__ finp, const float* __restrict__ tpre,
    const int* __restrict__ bnum, const int* __restrict__ padf,
    const float* __restrict__ Whh_f, const float* __restrict__ Wih_f,
    const float* __restrict__ Whh_t, const float* __restrict__ Wih_t,
    const float* __restrict__ W_fc, const float* __restrict__ b_fc,
    const float* __restrict__ W_tfc, const float* __restrict__ b_tfc,
    const float* __restrict__ Wa, const float* __restrict__ ba,
    const float* __restrict__ ctx, float* __restrict__ out) {
    __shared__ __align__(16) float hf_s[128];
    __shared__ float cf_s[128];
    __shared__ __align__(16) float ht_s[128];
    __shared__ float ct_s[128];
    __shared__ float g_s[512];
    __shared__ float prev_s[OUT_];     // [0]=tempo, [1..10]=out
    __shared__ float cur_res[D_];
    __shared__ float v_s[D_];
    __shared__ float c0_btfc[2];
    __shared__ float bfc_s[D_];
    __shared__ float wfc_s[D_ * 128];  // W_fc row-major [d][j]
    __shared__ float wtfc_s[128];
    __shared__ float wiht_s[512 * OUT_]; // tail cols of Wih_t per gate-row
    __shared__ short bn_s[N_];
    __shared__ short nextc_s[N_];      // next changed index > i
    __shared__ unsigned char pad_s[N_];
    __shared__ float xh[256][D_];      // circular history of out[1..10]

    int t = threadIdx.x, lane = t & 63, wave = t >> 6;
    int row = t >> 1, half = t & 1;
    int b = blockIdx.x;

    // half-row of Whh_f in registers: 64 VGPRs
    float4 whhf[16];
    {
        const float4* wfp = (const float4*)(Whh_f + (size_t)row * 128 + half * 64);
#pragma unroll
        for (int q = 0; q < 16; ++q) whhf[q] = wfp[q];
    }
    float wihf_t[OUT_];
#pragma unroll
    for (int u = 0; u < OUT_; ++u) wihf_t[u] = Wih_f[(size_t)row * 715 + 704 + u];

    for (int k = t; k < 512 * OUT_; k += 1024) {
        int r = k / OUT_, u = k - r * OUT_;
        wiht_s[k] = Wih_t[(size_t)r * 203 + 192 + u];
    }
    for (int k = t; k < D_ * 128; k += 1024) wfc_s[k] = W_fc[k];
    if (t < 128) wtfc_s[t] = W_tfc[t];
    if (t < D_) {
        bfc_s[t] = b_fc[t];
        cur_res[t] = 0.f;
        float vv = 0.f;
        for (int m = 0; m < D_; ++m) vv += ctx[m] * Wa[m * D_ + t];
        v_s[t] = vv;
    }
    if (t == 10) {
        float cc = 0.f;
        for (int m = 0; m < D_; ++m) cc += ba[m] * ctx[m];
        c0_btfc[0] = cc;
        c0_btfc[1] = b_tfc[0];
    }
    if (t < OUT_) prev_s[t] = 0.f;
    if (t < 128) { hf_s[t] = 0.f; cf_s[t] = 0.f; ht_s[t] = 0.f; ct_s[t] = 0.f; }
    for (int k = t; k < N_; k += 1024) {
        bn_s[k] = (short)bnum[(b << 11) + k];
        pad_s[k] = (unsigned char)padf[(b << 11) + k];
    }
    __syncthreads();
    for (int k = t; k < N_; k += 1024) {
        int j = k + 1, pv = bn_s[k];
        while (j < N_) {
            int bj = bn_s[j];
            if (bj != pv) break;
            pv = bj;
            ++j;
        }
        nextc_s[k] = (short)j;
    }
    __syncthreads();

    const float* finrow = finp + ((size_t)b << 11) * 512;
    int bn0 = bn_s[0];
    float gf_cur = 0.f, gf_pre = 0.f, gt_pre = 0.f;
    if (!half) {
        gf_cur = finrow[row];                              // row i=0
        gt_pre = tpre[(size_t)(b * NBEATS_) * 512 + row];  // cb=0 for i=0
    }
    int run_start = 0;
    int st_i = -1, st_pd = 0;

    for (int i = 0; i < N_; ++i) {
        int bni = bn_s[i];
        bool changed = (i == 0) || (bni != bn_s[i - 1]);
        int S_prev = run_start;
        if (changed) run_start = i;

        // delayed store of previous step's outputs (overlaps with matvec)
        if (t == 0 && st_i >= 0) {
            float* orow = out + (size_t)((b << 11) + st_i) * OUT_;
#pragma unroll
            for (int u = 0; u < OUT_; ++u) orow[u] = st_pd ? 0.f : prev_s[u];
        }
        // prefetch next fin row (consumed next iteration)
        if (!half) gf_pre = finrow[(size_t)(i + 1) * 512 + row];

        // recurrent half-matvec for final LSTM (hf from previous step)
        float acc = 0.f;
        {
            const float4* hp = (const float4*)(hf_s + half * 64);
#pragma unroll
            for (int q = 0; q < 16; ++q) {
                float4 wv = whhf[q], hv = hp[q];
                acc += wv.x * hv.x + wv.y * hv.y + wv.z * hv.z + wv.w * hv.w;
            }
        }

        if (changed) {
            // tempo recurrent half-matvec first (issues global loads early)
            float acct = 0.f;
            {
                const float4* wtp = (const float4*)(Whh_t + (size_t)row * 128 + half * 64);
                const float4* ht4 = (const float4*)(ht_s + half * 64);
#pragma unroll
                for (int q = 0; q < 16; ++q) {
                    float4 wv = wtp[q], hv = ht4[q];
                    acct += wv.x * hv.x + wv.y * hv.y + wv.z * hv.z + wv.w * hv.w;
                }
            }
            // attention over previous run [S_prev, i) on wave 0
            if (wave == 0) {
                int L = i - S_prev;
                float lmax = -1e30f;
                for (int tt = lane; tt < L; tt += 64) {
                    const float* xr = xh[(S_prev + tt) & 255];
                    float s = c0_btfc[0];
#pragma unroll
                    for (int d = 0; d < D_; ++d) s += xr[d] * v_s[d];
                    lmax = fmaxf(lmax, s);
                }
#pragma unroll
                for (int off = 32; off; off >>= 1)
                    lmax = fmaxf(lmax, __shfl_xor(lmax, off, 64));
                float lsum = 0.f, lacc[D_] = {};
                for (int tt = lane; tt < L; tt += 64) {
                    const float* xr = xh[(S_prev + tt) & 255];
                    float s = c0_btfc[0];
#pragma unroll
                    for (int d = 0; d < D_; ++d) s += xr[d] * v_s[d];
                    float w = expf(s - lmax);
                    lsum += w;
#pragma unroll
                    for (int d = 0; d < D_; ++d) lacc[d] += w * xr[d];
                }
#pragma unroll
                for (int off = 32; off; off >>= 1) {
                    lsum += __shfl_xor(lsum, off, 64);
#pragma unroll
                    for (int d = 0; d < D_; ++d) lacc[d] += __shfl_xor(lacc[d], off, 64);
                }
                if (lane == 0) {
                    if (L > 0) {
                        float inv = 1.0f / lsum;
#pragma unroll
                        for (int d = 0; d < D_; ++d) cur_res[d] = lacc[d] * inv;
                    } else {
#pragma unroll
                        for (int d = 0; d < D_; ++d) cur_res[d] = 0.f;
                    }
                }
            }
            __syncthreads();  // cur_res visible
            acct += __shfl_xor(acct, 1);
            if (!half) {
                float gt = gt_pre + acct;
                const float* wr = &wiht_s[row * OUT_];
                gt += wr[0] * prev_s[0];
#pragma unroll
                for (int d = 0; d < D_; ++d) gt += wr[1 + d] * cur_res[d];
                g_s[row] = gt;
            }
            __syncthreads();  // tempo gate vector ready
            if (wave == 0) {
                float p = 0.f;
#pragma unroll
                for (int h = 0; h < 2; ++h) {
                    int rr = lane + h * 64;
                    float gi = g_s[rr], gff = g_s[128 + rr], gg = g_s[256 + rr],
                          go = g_s[384 + rr];
                    float c2 = sigm_(gff) * ct_s[rr] + sigm_(gi) * tanhf(gg);
                    float h2 = sigm_(go) * tanhf(c2);
                    ct_s[rr] = c2;
                    ht_s[rr] = h2;
                    p += h2 * wtfc_s[rr];
                }
#pragma unroll
                for (int off = 32; off; off >>= 1) p += __shfl_xor(p, off, 64);
                if (lane == 0) prev_s[0] = p + c0_btfc[1];
            }
            __syncthreads();  // prev_s[0], ht/ct visible
            // prefetch tpre row for the NEXT changed step
            {
                int j = nextc_s[i];
                if (!half && j < N_)
                    gt_pre = tpre[(size_t)(b * NBEATS_ + (bn_s[j] - bn0)) * 512 + row];
            }
        }

        // final-LSTM gate vector
        acc += __shfl_xor(acc, 1);
        if (!half) {
            float g = gf_cur + acc;
#pragma unroll
            for (int u = 0; u < OUT_; ++u) g += wihf_t[u] * prev_s[u];
            g_s[row] = g;
        }
        gf_cur = gf_pre;
        __syncthreads();  // B1: g_s ready
        if (wave == 0) {
            float h2v[2];
#pragma unroll
            for (int h = 0; h < 2; ++h) {
                int rr = lane + h * 64;
                float gi = g_s[rr], gff = g_s[128 + rr], gg = g_s[256 + rr],
                      go = g_s[384 + rr];
                float c2 = sigm_(gff) * cf_s[rr] + sigm_(gi) * tanhf(gg);
                float h2 = sigm_(go) * tanhf(c2);
                cf_s[rr] = c2;
                hf_s[rr] = h2;
                h2v[h] = h2;
            }
            float po[D_];
#pragma unroll
            for (int d = 0; d < D_; ++d)
                po[d] = h2v[0] * wfc_s[d * 128 + lane] + h2v[1] * wfc_s[d * 128 + lane + 64];
#pragma unroll
            for (int off = 32; off; off >>= 1) {
#pragma unroll
                for (int d = 0; d < D_; ++d) po[d] += __shfl_xor(po[d], off, 64);
            }
            if (lane == 0) {
#pragma unroll
                for (int d = 0; d < D_; ++d) {
                    float od = po[d] + bfc_s[d];
                    prev_s[1 + d] = od;
                    xh[i & 255][d] = od;
                }
            }
        }
        st_i = i;
        st_pd = pad_s[i];
        __syncthreads();  // Bend: hf/prev/xh visible for next step
    }
    if (t == 0) {
        float* orow = out + (size_t)((b << 11) + st_i) * OUT_;
#pragma unroll
        for (int u = 0; u < OUT_; ++u) orow[u] = st_pd ? 0.f : prev_s[u];
    }
}

// ---------------------------------------------------------------------------
extern "C" void kernel_launch(void* const* d_in, const int* in_sizes, int n_in,
                              void* d_out, int out_size, void* d_ws, size_t ws_size,
                              hipStream_t stream) {
    const float* note  = (const float*)d_in[0];
    const float* beat  = (const float*)d_in[1];
    const float* meas  = (const float*)d_in[2];
    const int*   bnum  = (const int*)d_in[3];
    const int*   mnum  = (const int*)d_in[4];
    const float* Wa    = (const float*)d_in[5];
    const float* ba    = (const float*)d_in[6];
    const float* ctx   = (const float*)d_in[7];
    const float* Wih_t = (const float*)d_in[8];
    const float* Whh_t = (const float*)d_in[9];
    const float* bih_t = (const float*)d_in[10];
    const float* bhh_t = (const float*)d_in[11];
    const float* Wih_f = (const float*)d_in[12];
    const float* Whh_f = (const float*)d_in[13];
    const float* bih_f = (const float*)d_in[14];
    const float* bhh_f = (const float*)d_in[15];
    const float* W_fc  = (const float*)d_in[16];
    const float* b_fc  = (const float*)d_in[17];
    const float* W_tfc = (const float*)d_in[18];
    const float* b_tfc = (const float*)d_in[19];
    float* out = (float*)d_out;

    char* ws = (char*)d_ws;
    float* finp = (float*)ws;                                   // 64 MB
    float* tpre = (float*)(ws + (size_t)64 * 1024 * 1024);      // 8 MB
    int*   padf = (int*)(ws + (size_t)72 * 1024 * 1024);        // 128 KB

    pad_k<<<8192, 256, 0, stream>>>(note, padf);
    tempo_pre_k<<<dim3(16, 16), 256, 0, stream>>>(beat, meas, bnum, mnum, Wih_t,
                                                  bih_t, bhh_t, tpre);
    fin_pre_gemm<<<dim3(512, 8), 256, 0, stream>>>(note, beat, meas, bnum, mnum,
                                                   Wih_f, bih_f, bhh_f, finp);
    decode_seq<<<16, 1024, 0, stream>>>(finp, tpre, bnum, padf, Whh_f, Wih_f, Whh_t,
                                        Wih_t, W_fc, b_fc, W_tfc, b_tfc, Wa, ba, ctx,
                                        out);
}

// Round 4
// 22597.205 us; speedup vs baseline: 1.2997x; 1.2997x over previous
//
#include <hip/hip_runtime.h>
#include <cstdint>
#include <cstddef>

#define B_      16
#define N_      2048
#define NOTE_   512
#define BEAT_H_ 128
#define MEAS_H_ 64
#define NBEATS_ 256
#define NMEAS_  64
#define OUT_    11
#define D_      10
// fin = 715 (512 note + 128 beat + 64 meas + 11 prev_out)
// tin = 203 (128 beat + 64 meas + 1 tempo + 10 beat_results)

__device__ __forceinline__ float sigm_(float x) { return 1.0f / (1.0f + expf(-x)); }

// NOTE: parameter names must not collide with float4 member names (x,y,z,w)!
#define DOT4(va, vb) ((va).x * (vb).x + (va).y * (vb).y + (va).z * (vb).z + (va).w * (vb).w)

// ---------------------------------------------------------------------------
// pad flags: pad[b,i] = (sum_k note_emb[b,i,k] == 0)
// ---------------------------------------------------------------------------
__global__ __launch_bounds__(256) void pad_k(const float* __restrict__ note,
                                             int* __restrict__ padf) {
    int wave = threadIdx.x >> 6, lane = threadIdx.x & 63;
    int r = blockIdx.x * 4 + wave;
    const float* row = note + ((size_t)r << 9);
    float s = 0.f;
#pragma unroll
    for (int u = 0; u < 8; ++u) s += row[lane + (u << 6)];
#pragma unroll
    for (int off = 32; off; off >>= 1) s += __shfl_xor(s, off, 64);
    if (lane == 0) padf[r] = (s == 0.0f) ? 1 : 0;
}

// ---------------------------------------------------------------------------
// tempo_pre[b,q,j] = Wih_t[j,0:128]·beat_emb[b,q] + Wih_t[j,128:192]·meas_emb[b,cm(q)]
//                    + bih_t[j] + bhh_t[j]
// ---------------------------------------------------------------------------
__global__ __launch_bounds__(256) void tempo_pre_k(
    const float* __restrict__ beat, const float* __restrict__ meas,
    const int* __restrict__ bnum, const int* __restrict__ mnum,
    const float* __restrict__ Wih_t, const float* __restrict__ bih_t,
    const float* __restrict__ bhh_t, float* __restrict__ tpre) {
    __shared__ float sin_[16][192];
    int b = blockIdx.x, qt = blockIdx.y;
    int t = threadIdx.x;
    int bn0 = bnum[b << 11], mn0 = mnum[b << 11];
    for (int idx = t; idx < 16 * 192; idx += 256) {
        int qq = idx / 192, kk = idx - qq * 192;
        int q = qt * 16 + qq;
        float v;
        if (kk < 128) {
            v = beat[(size_t)(b * NBEATS_ + q) * 128 + kk];
        } else {
            int cm = ((q + bn0) >> 2) - mn0;
            if (cm > 63) cm = 63;
            if (cm < 0) cm = 0;
            v = meas[(size_t)(b * NMEAS_ + cm) * 64 + (kk - 128)];
        }
        sin_[qq][kk] = v;
    }
    __syncthreads();
    for (int half = 0; half < 2; ++half) {
        int j = t + half * 256;
        const float* wr = Wih_t + (size_t)j * 203;
        float bias = bih_t[j] + bhh_t[j];
        float acc[16] = {};
        for (int k = 0; k < 192; ++k) {
            float w = wr[k];
#pragma unroll
            for (int qq = 0; qq < 16; ++qq) acc[qq] += w * sin_[qq][k];
        }
        for (int qq = 0; qq < 16; ++qq)
            tpre[(size_t)(b * NBEATS_ + qt * 16 + qq) * 512 + j] = acc[qq] + bias;
    }
}

// ---------------------------------------------------------------------------
// fin_pre[r, j] = [note(512) | beat(128) | meas(64)] · Wih_f[j,0:704] + biases
// ---------------------------------------------------------------------------
__global__ __launch_bounds__(256) void fin_pre_gemm(
    const float* __restrict__ note, const float* __restrict__ beat,
    const float* __restrict__ meas, const int* __restrict__ bnum,
    const int* __restrict__ mnum, const float* __restrict__ Wih_f,
    const float* __restrict__ bih_f, const float* __restrict__ bhh_f,
    float* __restrict__ finp) {
    __shared__ float As[16][64];
    __shared__ float Bs[16][64];
    int t = threadIdx.x;
    int r0 = blockIdx.x * 64;
    int j0 = blockIdx.y * 64;

    int am = t >> 2, alane = t & 3;
    int r = r0 + am;
    int b = r >> 11;
    int rb = b << 11;
    int cb = bnum[r] - bnum[rb];
    int cm = mnum[r] - mnum[rb];
    const float* arow_note = note + ((size_t)r << 9);
    const float* arow_beat = beat + ((size_t)(b * NBEATS_ + cb) << 7);
    const float* arow_meas = meas + ((size_t)(b * NMEAS_ + cm) << 6);

    int jj = t >> 2, blane = t & 3;
    const float* brow = Wih_f + (size_t)(j0 + jj) * 715;

    int tm0 = (t & 15) * 4, tn0 = (t >> 4) * 4;
    float acc[4][4] = {};

    for (int k0 = 0; k0 < 704; k0 += 16) {
        int ka = k0 + alane * 4;
        float4 av;
        if (ka < 512)      av = *(const float4*)(arow_note + ka);
        else if (ka < 640) av = *(const float4*)(arow_beat + (ka - 512));
        else               av = *(const float4*)(arow_meas + (ka - 640));
        int kb = k0 + blane * 4;
        float b0 = brow[kb], b1 = brow[kb + 1], b2 = brow[kb + 2], b3 = brow[kb + 3];
        __syncthreads();
        As[alane * 4 + 0][am] = av.x;
        As[alane * 4 + 1][am] = av.y;
        As[alane * 4 + 2][am] = av.z;
        As[alane * 4 + 3][am] = av.w;
        Bs[blane * 4 + 0][jj] = b0;
        Bs[blane * 4 + 1][jj] = b1;
        Bs[blane * 4 + 2][jj] = b2;
        Bs[blane * 4 + 3][jj] = b3;
        __syncthreads();
#pragma unroll
        for (int kk = 0; kk < 16; ++kk) {
            float4 a4 = *(const float4*)&As[kk][tm0];
            float4 b4 = *(const float4*)&Bs[kk][tn0];
            float aa[4] = {a4.x, a4.y, a4.z, a4.w};
            float bb[4] = {b4.x, b4.y, b4.z, b4.w};
#pragma unroll
            for (int mi = 0; mi < 4; ++mi)
#pragma unroll
                for (int ni = 0; ni < 4; ++ni) acc[mi][ni] += aa[mi] * bb[ni];
        }
    }
    float bias[4];
#pragma unroll
    for (int ni = 0; ni < 4; ++ni) {
        int j = j0 + tn0 + ni;
        bias[ni] = bih_f[j] + bhh_f[j];
    }
#pragma unroll
    for (int mi = 0; mi < 4; ++mi) {
        int rr = r0 + tm0 + mi;
        float4 o;
        o.x = acc[mi][0] + bias[0];
        o.y = acc[mi][1] + bias[1];
        o.z = acc[mi][2] + bias[2];
        o.w = acc[mi][3] + bias[3];
        *(float4*)(finp + ((size_t)rr << 9) + j0 + tn0) = o;
    }
}

// ---------------------------------------------------------------------------
// sequential decoder: 1024 threads, half-row of Whh_f per thread held in 16
// NAMED float4 registers (no array => no spill), 2 barriers/unchanged step.
// ---------------------------------------------------------------------------
__global__ __launch_bounds__(1024, 4) void decode_seq(
    const float* __restrict__ finp, const float* __restrict__ tpre,
    const int* __restrict__ bnum, const int* __restrict__ padf,
    const float* __restrict__ Whh_f, const float* __restrict__ Wih_f,
    const float* __restrict__ Whh_t, const float* __restrict__ Wih_t,
    const float* __restrict__ W_fc, const float* __restrict__ b_fc,
    const float* __restrict__ W_tfc, const float* __restrict__ b_tfc,
    const float* __restrict__ Wa, const float* __restrict__ ba,
    const float* __restrict__ ctx, float* __restrict__ out) {
    __shared__ __align__(16) float hf_s[128];
    __shared__ float cf_s[128];
    __shared__ __align__(16) float ht_s[128];
    __shared__ float ct_s[128];
    __shared__ float g_s[512];
    __shared__ float prev_s[OUT_];       // [0]=tempo, [1..10]=out
    __shared__ float cur_res[D_];
    __shared__ float v_s[D_];
    __shared__ float c0_btfc[2];
    __shared__ float bfc_s[D_];
    __shared__ float wfc_s[D_ * 128];    // W_fc row-major [d][j]
    __shared__ float wtfc_s[128];
    __shared__ float wiht_s[512 * OUT_]; // tail cols of Wih_t per gate-row
    __shared__ short bn_s[N_];
    __shared__ short nextc_s[N_];        // next changed index > i
    __shared__ unsigned char pad_s[N_];
    __shared__ float xh[256][OUT_];      // history of out[1..10]; row stride 11 (bank-safe)

    int t = threadIdx.x, lane = t & 63, wave = t >> 6;
    int row = t >> 1, half = t & 1;
    int b = blockIdx.x;

    // half-row of Whh_f in 16 NAMED float4 registers (compiler-proof residency)
    float4 w0, w1, w2, w3, w4, w5, w6, w7, w8, w9, w10, w11, w12, w13, w14, w15;
    {
        const float4* wfp = (const float4*)(Whh_f + (size_t)row * 128 + (half << 6));
        w0 = wfp[0];  w1 = wfp[1];  w2 = wfp[2];  w3 = wfp[3];
        w4 = wfp[4];  w5 = wfp[5];  w6 = wfp[6];  w7 = wfp[7];
        w8 = wfp[8];  w9 = wfp[9];  w10 = wfp[10]; w11 = wfp[11];
        w12 = wfp[12]; w13 = wfp[13]; w14 = wfp[14]; w15 = wfp[15];
    }
    float wihf_t[OUT_];
#pragma unroll
    for (int u = 0; u < OUT_; ++u) wihf_t[u] = Wih_f[(size_t)row * 715 + 704 + u];

    for (int k = t; k < 512 * OUT_; k += 1024) {
        int r = k / OUT_, u = k - r * OUT_;
        wiht_s[k] = Wih_t[(size_t)r * 203 + 192 + u];
    }
    for (int k = t; k < D_ * 128; k += 1024) wfc_s[k] = W_fc[k];
    if (t < 128) wtfc_s[t] = W_tfc[t];
    if (t < D_) {
        bfc_s[t] = b_fc[t];
        cur_res[t] = 0.f;
        float vv = 0.f;
        for (int m = 0; m < D_; ++m) vv += ctx[m] * Wa[m * D_ + t];
        v_s[t] = vv;
    }
    if (t == 10) {
        float cc = 0.f;
        for (int m = 0; m < D_; ++m) cc += ba[m] * ctx[m];
        c0_btfc[0] = cc;
        c0_btfc[1] = b_tfc[0];
    }
    if (t < OUT_) prev_s[t] = 0.f;
    if (t < 128) { hf_s[t] = 0.f; cf_s[t] = 0.f; ht_s[t] = 0.f; ct_s[t] = 0.f; }
    for (int k = t; k < N_; k += 1024) {
        bn_s[k] = (short)bnum[(b << 11) + k];
        pad_s[k] = (unsigned char)padf[(b << 11) + k];
    }
    __syncthreads();
    for (int k = t; k < N_; k += 1024) {
        int j = k + 1, pv = bn_s[k];
        while (j < N_ && bn_s[j] == pv) ++j;
        nextc_s[k] = (short)j;
    }
    __syncthreads();

    const float* finrow = finp + ((size_t)b << 11) * 512;
    int bn0 = bn_s[0];
    float gf_cur = 0.f, gf_pre = 0.f, gt_pre = 0.f;
    if (!half) {
        gf_cur = finrow[row];                              // row i=0
        gt_pre = tpre[(size_t)(b * NBEATS_) * 512 + row];  // cb=0 at i=0
    }
    int run_start = 0;

    for (int i = 0; i < N_; ++i) {
        int bni = bn_s[i];
        bool changed = (i == 0) || (bni != bn_s[i - 1]);
        int S_prev = run_start;
        if (changed) run_start = i;

        // delayed store of previous step's outputs (11 lanes, overlaps matvec)
        if (t < OUT_ && i > 0) {
            int pi = i - 1;
            float v = prev_s[t];
            out[(size_t)((b << 11) + pi) * OUT_ + t] = pad_s[pi] ? 0.f : v;
        }
        // prefetch next fin row (consumed next iteration)
        if (!half) gf_pre = finrow[(size_t)(i + 1) * 512 + row];

        // recurrent half-matvec for final LSTM (hf from previous step; LDS broadcast)
        float acc;
        {
            const float4* hp = (const float4*)hf_s + (half << 4);
            float a0 = DOT4(w0, hp[0]) + DOT4(w1, hp[1]) + DOT4(w2, hp[2]) + DOT4(w3, hp[3]);
            float a1 = DOT4(w4, hp[4]) + DOT4(w5, hp[5]) + DOT4(w6, hp[6]) + DOT4(w7, hp[7]);
            float a2 = DOT4(w8, hp[8]) + DOT4(w9, hp[9]) + DOT4(w10, hp[10]) + DOT4(w11, hp[11]);
            float a3 = DOT4(w12, hp[12]) + DOT4(w13, hp[13]) + DOT4(w14, hp[14]) + DOT4(w15, hp[15]);
            acc = (a0 + a1) + (a2 + a3);
        }

        if (changed) {
            // tempo recurrent half-matvec; chunked (4 float4 at a time) to cap
            // transient VGPR pressure — changed steps only (~1/8 of steps)
            float acct = 0.f;
            {
                const float4* wtp = (const float4*)(Whh_t + (size_t)row * 128 + (half << 6));
                const float4* htp = (const float4*)ht_s + (half << 4);
#pragma unroll 1
                for (int c = 0; c < 4; ++c) {
                    float4 a0 = wtp[c * 4 + 0], a1 = wtp[c * 4 + 1];
                    float4 a2 = wtp[c * 4 + 2], a3 = wtp[c * 4 + 3];
                    acct += DOT4(a0, htp[c * 4 + 0]) + DOT4(a1, htp[c * 4 + 1]) +
                            DOT4(a2, htp[c * 4 + 2]) + DOT4(a3, htp[c * 4 + 3]);
                }
            }
            // attention over previous run [S_prev, i) on wave 0
            if (wave == 0) {
                int L = i - S_prev;
                float lmax = -1e30f;
                for (int tt = lane; tt < L; tt += 64) {
                    const float* xr = xh[(S_prev + tt) & 255];
                    float s = c0_btfc[0];
#pragma unroll
                    for (int d = 0; d < D_; ++d) s += xr[d] * v_s[d];
                    lmax = fmaxf(lmax, s);
                }
#pragma unroll
                for (int off = 32; off; off >>= 1)
                    lmax = fmaxf(lmax, __shfl_xor(lmax, off, 64));
                float lsum = 0.f, lacc[D_] = {};
                for (int tt = lane; tt < L; tt += 64) {
                    const float* xr = xh[(S_prev + tt) & 255];
                    float s = c0_btfc[0];
#pragma unroll
                    for (int d = 0; d < D_; ++d) s += xr[d] * v_s[d];
                    float w = expf(s - lmax);
                    lsum += w;
#pragma unroll
                    for (int d = 0; d < D_; ++d) lacc[d] += w * xr[d];
                }
#pragma unroll
                for (int off = 32; off; off >>= 1) {
                    lsum += __shfl_xor(lsum, off, 64);
#pragma unroll
                    for (int d = 0; d < D_; ++d) lacc[d] += __shfl_xor(lacc[d], off, 64);
                }
                if (lane == 0) {
                    if (L > 0) {
                        float inv = 1.0f / lsum;
#pragma unroll
                        for (int d = 0; d < D_; ++d) cur_res[d] = lacc[d] * inv;
                    } else {
#pragma unroll
                        for (int d = 0; d < D_; ++d) cur_res[d] = 0.f;
                    }
                }
            }
            __syncthreads();  // cur_res visible
            acct += __shfl_xor(acct, 1);
            if (!half) {
                float gt = gt_pre + acct;
                const float* wr = &wiht_s[row * OUT_];
                gt += wr[0] * prev_s[0];
#pragma unroll
                for (int d = 0; d < D_; ++d) gt += wr[1 + d] * cur_res[d];
                g_s[row] = gt;
            }
            __syncthreads();  // tempo gate vector ready
            if (wave == 0) {
                float p = 0.f;
#pragma unroll
                for (int h = 0; h < 2; ++h) {
                    int rr = lane + h * 64;
                    float gi = g_s[rr], gff = g_s[128 + rr], gg = g_s[256 + rr],
                          go = g_s[384 + rr];
                    float c2 = sigm_(gff) * ct_s[rr] + sigm_(gi) * tanhf(gg);
                    float h2 = sigm_(go) * tanhf(c2);
                    ct_s[rr] = c2;
                    ht_s[rr] = h2;
                    p += h2 * wtfc_s[rr];
                }
#pragma unroll
                for (int off = 32; off; off >>= 1) p += __shfl_xor(p, off, 64);
                if (lane == 0) prev_s[0] = p + c0_btfc[1];
            }
            __syncthreads();  // prev_s[0], ht/ct visible
            // prefetch tpre row for the NEXT changed step
            {
                int j = nextc_s[i];
                if (!half && j < N_)
                    gt_pre = tpre[(size_t)(b * NBEATS_ + (bn_s[j] - bn0)) * 512 + row];
            }
        }

        // final-LSTM gate vector
        acc += __shfl_xor(acc, 1);
        if (!half) {
            float g = gf_cur + acc;
#pragma unroll
            for (int u = 0; u < OUT_; ++u) g += wihf_t[u] * prev_s[u];
            g_s[row] = g;
        }
        gf_cur = gf_pre;
        __syncthreads();  // B1: g_s ready
        if (wave == 0) {
            float h2v[2];
#pragma unroll
            for (int h = 0; h < 2; ++h) {
                int rr = lane + h * 64;
                float gi = g_s[rr], gff = g_s[128 + rr], gg = g_s[256 + rr],
                      go = g_s[384 + rr];
                float c2 = sigm_(gff) * cf_s[rr] + sigm_(gi) * tanhf(gg);
                float h2 = sigm_(go) * tanhf(c2);
                cf_s[rr] = c2;
                hf_s[rr] = h2;
                h2v[h] = h2;
            }
            float po[D_];
#pragma unroll
            for (int d = 0; d < D_; ++d)
                po[d] = h2v[0] * wfc_s[d * 128 + lane] + h2v[1] * wfc_s[d * 128 + lane + 64];
#pragma unroll
            for (int off = 32; off; off >>= 1) {
#pragma unroll
                for (int d = 0; d < D_; ++d) po[d] += __shfl_xor(po[d], off, 64);
            }
            if (lane == 0) {
#pragma unroll
                for (int d = 0; d < D_; ++d) {
                    float od = po[d] + bfc_s[d];
                    prev_s[1 + d] = od;
                    xh[i & 255][d] = od;
                }
            }
        }
        __syncthreads();  // Bend: hf/prev/xh visible for next step
    }
    if (t < OUT_) {
        float v = prev_s[t];
        out[(size_t)((b << 11) + (N_ - 1)) * OUT_ + t] = pad_s[N_ - 1] ? 0.f : v;
    }
}

// ---------------------------------------------------------------------------
extern "C" void kernel_launch(void* const* d_in, const int* in_sizes, int n_in,
                              void* d_out, int out_size, void* d_ws, size_t ws_size,
                              hipStream_t stream) {
    const float* note  = (const float*)d_in[0];
    const float* beat  = (const float*)d_in[1];
    const float* meas  = (const float*)d_in[2];
    const int*   bnum  = (const int*)d_in[3];
    const int*   mnum  = (const int*)d_in[4];
    const float* Wa    = (const float*)d_in[5];
    const float* ba    = (const float*)d_in[6];
    const float* ctx   = (const float*)d_in[7];
    const float* Wih_t = (const float*)d_in[8];
    const float* Whh_t = (const float*)d_in[9];
    const float* bih_t = (const float*)d_in[10];
    const float* bhh_t = (const float*)d_in[11];
    const float* Wih_f = (const float*)d_in[12];
    const float* Whh_f = (const float*)d_in[13];
    const float* bih_f = (const float*)d_in[14];
    const float* bhh_f = (const float*)d_in[15];
    const float* W_fc  = (const float*)d_in[16];
    const float* b_fc  = (const float*)d_in[17];
    const float* W_tfc = (const float*)d_in[18];
    const float* b_tfc = (const float*)d_in[19];
    float* out = (float*)d_out;

    char* ws = (char*)d_ws;
    float* finp = (float*)ws;                                   // 64 MB
    float* tpre = (float*)(ws + (size_t)64 * 1024 * 1024);      // 8 MB
    int*   padf = (int*)(ws + (size_t)72 * 1024 * 1024);        // 128 KB

    pad_k<<<8192, 256, 0, stream>>>(note, padf);
    tempo_pre_k<<<dim3(16, 16), 256, 0, stream>>>(beat, meas, bnum, mnum, Wih_t,
                                                  bih_t, bhh_t, tpre);
    fin_pre_gemm<<<dim3(512, 8), 256, 0, stream>>>(note, beat, meas, bnum, mnum,
                                                   Wih_f, bih_f, bhh_f, finp);
    decode_seq<<<16, 1024, 0, stream>>>(finp, tpre, bnum, padf, Whh_f, Wih_f, Whh_t,
                                        Wih_t, W_fc, b_fc, W_tfc, b_tfc, Wa, ba, ctx,
                                        out);
}

// Round 5
// 10496.258 us; speedup vs baseline: 2.7982x; 2.1529x over previous
//
#include <hip/hip_runtime.h>
#include <cstdint>
#include <cstddef>

#define B_      16
#define N_      2048
#define NOTE_   512
#define BEAT_H_ 128
#define MEAS_H_ 64
#define NBEATS_ 256
#define NMEAS_  64
#define OUT_    11
#define D_      10
// fin = 715 (512 note + 128 beat + 64 meas + 11 prev_out)
// tin = 203 (128 beat + 64 meas + 1 tempo + 10 beat_results)

__device__ __forceinline__ float sigm_(float x) { return 1.0f / (1.0f + expf(-x)); }

// NOTE: parameter names must not collide with float4 member names (x,y,z,w)!
#define DOT4(va, vb) ((va).x * (vb).x + (va).y * (vb).y + (va).z * (vb).z + (va).w * (vb).w)

// Folded recurrent weights: Whh_eff = Whh_f + Wih_f[:,705:715] @ W_fc
// bias_eff = Wih_f[:,705:715] @ b_fc ; wtail0 = Wih_f[:,704]
__device__ float g_whh_eff[512 * 128];
__device__ float g_bias_eff[512];
__device__ float g_wtail0[512];

// ---------------------------------------------------------------------------
__global__ __launch_bounds__(256) void pad_k(const float* __restrict__ note,
                                             int* __restrict__ padf) {
    int wave = threadIdx.x >> 6, lane = threadIdx.x & 63;
    int r = blockIdx.x * 4 + wave;
    const float* row = note + ((size_t)r << 9);
    float s = 0.f;
#pragma unroll
    for (int u = 0; u < 8; ++u) s += row[lane + (u << 6)];
#pragma unroll
    for (int off = 32; off; off >>= 1) s += __shfl_xor(s, off, 64);
    if (lane == 0) padf[r] = (s == 0.0f) ? 1 : 0;
}

// ---------------------------------------------------------------------------
__global__ __launch_bounds__(128) void fold_whh(
    const float* __restrict__ Whh_f, const float* __restrict__ Wih_f,
    const float* __restrict__ W_fc, const float* __restrict__ b_fc) {
    int gr = blockIdx.x;   // 512
    int t = threadIdx.x;   // 128
    __shared__ float tail[OUT_];
    if (t < OUT_) tail[t] = Wih_f[(size_t)gr * 715 + 704 + t];
    __syncthreads();
    float m = Whh_f[(size_t)gr * 128 + t];
#pragma unroll
    for (int d = 0; d < D_; ++d) m += tail[1 + d] * W_fc[d * 128 + t];
    g_whh_eff[(size_t)gr * 128 + t] = m;
    if (t == 0) {
        float bb = 0.f;
#pragma unroll
        for (int d = 0; d < D_; ++d) bb += tail[1 + d] * b_fc[d];
        g_bias_eff[gr] = bb;
        g_wtail0[gr] = tail[0];
    }
}

// ---------------------------------------------------------------------------
__global__ __launch_bounds__(256) void tempo_pre_k(
    const float* __restrict__ beat, const float* __restrict__ meas,
    const int* __restrict__ bnum, const int* __restrict__ mnum,
    const float* __restrict__ Wih_t, const float* __restrict__ bih_t,
    const float* __restrict__ bhh_t, float* __restrict__ tpre) {
    __shared__ float sin_[16][192];
    int b = blockIdx.x, qt = blockIdx.y;
    int t = threadIdx.x;
    int bn0 = bnum[b << 11], mn0 = mnum[b << 11];
    for (int idx = t; idx < 16 * 192; idx += 256) {
        int qq = idx / 192, kk = idx - qq * 192;
        int q = qt * 16 + qq;
        float v;
        if (kk < 128) {
            v = beat[(size_t)(b * NBEATS_ + q) * 128 + kk];
        } else {
            int cm = ((q + bn0) >> 2) - mn0;
            if (cm > 63) cm = 63;
            if (cm < 0) cm = 0;
            v = meas[(size_t)(b * NMEAS_ + cm) * 64 + (kk - 128)];
        }
        sin_[qq][kk] = v;
    }
    __syncthreads();
    for (int half = 0; half < 2; ++half) {
        int j = t + half * 256;
        const float* wr = Wih_t + (size_t)j * 203;
        float bias = bih_t[j] + bhh_t[j];
        float acc[16] = {};
        for (int k = 0; k < 192; ++k) {
            float w = wr[k];
#pragma unroll
            for (int qq = 0; qq < 16; ++qq) acc[qq] += w * sin_[qq][k];
        }
        for (int qq = 0; qq < 16; ++qq)
            tpre[(size_t)(b * NBEATS_ + qt * 16 + qq) * 512 + j] = acc[qq] + bias;
    }
}

// ---------------------------------------------------------------------------
__global__ __launch_bounds__(256) void fin_pre_gemm(
    const float* __restrict__ note, const float* __restrict__ beat,
    const float* __restrict__ meas, const int* __restrict__ bnum,
    const int* __restrict__ mnum, const float* __restrict__ Wih_f,
    const float* __restrict__ bih_f, const float* __restrict__ bhh_f,
    float* __restrict__ finp) {
    __shared__ float As[16][64];
    __shared__ float Bs[16][64];
    int t = threadIdx.x;
    int r0 = blockIdx.x * 64;
    int j0 = blockIdx.y * 64;

    int am = t >> 2, alane = t & 3;
    int r = r0 + am;
    int b = r >> 11;
    int rb = b << 11;
    int cb = bnum[r] - bnum[rb];
    int cm = mnum[r] - mnum[rb];
    const float* arow_note = note + ((size_t)r << 9);
    const float* arow_beat = beat + ((size_t)(b * NBEATS_ + cb) << 7);
    const float* arow_meas = meas + ((size_t)(b * NMEAS_ + cm) << 6);

    int jj = t >> 2, blane = t & 3;
    const float* brow = Wih_f + (size_t)(j0 + jj) * 715;

    int tm0 = (t & 15) * 4, tn0 = (t >> 4) * 4;
    float acc[4][4] = {};

    for (int k0 = 0; k0 < 704; k0 += 16) {
        int ka = k0 + alane * 4;
        float4 av;
        if (ka < 512)      av = *(const float4*)(arow_note + ka);
        else if (ka < 640) av = *(const float4*)(arow_beat + (ka - 512));
        else               av = *(const float4*)(arow_meas + (ka - 640));
        int kb = k0 + blane * 4;
        float b0 = brow[kb], b1 = brow[kb + 1], b2 = brow[kb + 2], b3 = brow[kb + 3];
        __syncthreads();
        As[alane * 4 + 0][am] = av.x;
        As[alane * 4 + 1][am] = av.y;
        As[alane * 4 + 2][am] = av.z;
        As[alane * 4 + 3][am] = av.w;
        Bs[blane * 4 + 0][jj] = b0;
        Bs[blane * 4 + 1][jj] = b1;
        Bs[blane * 4 + 2][jj] = b2;
        Bs[blane * 4 + 3][jj] = b3;
        __syncthreads();
#pragma unroll
        for (int kk = 0; kk < 16; ++kk) {
            float4 a4 = *(const float4*)&As[kk][tm0];
            float4 b4 = *(const float4*)&Bs[kk][tn0];
            float aa[4] = {a4.x, a4.y, a4.z, a4.w};
            float bb[4] = {b4.x, b4.y, b4.z, b4.w};
#pragma unroll
            for (int mi = 0; mi < 4; ++mi)
#pragma unroll
                for (int ni = 0; ni < 4; ++ni) acc[mi][ni] += aa[mi] * bb[ni];
        }
    }
    float bias[4];
#pragma unroll
    for (int ni = 0; ni < 4; ++ni) {
        int j = j0 + tn0 + ni;
        bias[ni] = bih_f[j] + bhh_f[j];
    }
#pragma unroll
    for (int mi = 0; mi < 4; ++mi) {
        int rr = r0 + tm0 + mi;
        float4 o;
        o.x = acc[mi][0] + bias[0];
        o.y = acc[mi][1] + bias[1];
        o.z = acc[mi][2] + bias[2];
        o.w = acc[mi][3] + bias[3];
        *(float4*)(finp + ((size_t)rr << 9) + j0 + tn0) = o;
    }
}

// ---------------------------------------------------------------------------
// sequential decoder: 1024 threads, amdgpu_waves_per_eu(4,4) pins the VGPR
// budget at 128 so the 64-VGPR folded weight half-row stays resident.
// Unchanged step: 2 barriers; out/xh finalize runs one step behind on wave1;
// nonlinearity split across wave0+wave2.
// ---------------------------------------------------------------------------
__global__ __launch_bounds__(1024)
__attribute__((amdgpu_waves_per_eu(4, 4)))
void decode_seq(
    const float* __restrict__ finp, const float* __restrict__ tpre,
    const int* __restrict__ bnum, const int* __restrict__ padf,
    const float* __restrict__ Whh_t, const float* __restrict__ Wih_t,
    const float* __restrict__ W_fc, const float* __restrict__ b_fc,
    const float* __restrict__ W_tfc, const float* __restrict__ b_tfc,
    const float* __restrict__ Wa, const float* __restrict__ ba,
    const float* __restrict__ ctx, float* __restrict__ out) {
    __shared__ __align__(16) float hf_s[128];
    __shared__ float cf_s[128];
    __shared__ __align__(16) float ht_s[128];
    __shared__ float ct_s[128];
    __shared__ float g_s[512];
    __shared__ float gt_s[512];
    __shared__ float wtail0_s[512];
    __shared__ float wiht_s[512 * OUT_];  // tempo-gate tail cols [gr][0..10]
    __shared__ float wfcT[128][12];       // W_fc transposed [r][d]
    __shared__ float wtfc_s[128];
    __shared__ float bfc_s[12];
    __shared__ float cur_res[12];
    __shared__ float v_s[12];
    __shared__ float sc_s[4];             // [0]=ba·ctx, [1]=b_tfc, [2]=tempo scalar
    __shared__ short bn_s[N_];
    __shared__ short nextc_s[N_];
    __shared__ unsigned char pad_s[N_];
    __shared__ float xh[256][12];         // out-history ring (stride 12)

    int t = threadIdx.x, lane = t & 63, wave = t >> 6;
    int gr = t >> 1, half = t & 1;
    int b = blockIdx.x;

    // folded weight half-row in 16 named float4 (64 VGPR)
    float4 w0, w1, w2, w3, w4, w5, w6, w7, w8, w9, w10, w11, w12, w13, w14, w15;
    {
        const float4* wfp = (const float4*)(g_whh_eff + (size_t)gr * 128 + (half << 6));
        w0 = wfp[0];   w1 = wfp[1];   w2 = wfp[2];   w3 = wfp[3];
        w4 = wfp[4];   w5 = wfp[5];   w6 = wfp[6];   w7 = wfp[7];
        w8 = wfp[8];   w9 = wfp[9];   w10 = wfp[10]; w11 = wfp[11];
        w12 = wfp[12]; w13 = wfp[13]; w14 = wfp[14]; w15 = wfp[15];
    }
    float bias_r = g_bias_eff[gr];
    float wtail0_r = g_wtail0[gr];

    for (int k = t; k < 512 * OUT_; k += 1024) {
        int r = k / OUT_, u = k - r * OUT_;
        wiht_s[k] = Wih_t[(size_t)r * 203 + 192 + u];
    }
    for (int k = t; k < 128 * D_; k += 1024) {
        int d = k >> 7, r = k & 127;
        wfcT[r][d] = W_fc[k];
    }
    if (t < 512) wtail0_s[t] = g_wtail0[t];
    if (t < 128) { wtfc_s[t] = W_tfc[t]; hf_s[t] = 0.f; cf_s[t] = 0.f; ht_s[t] = 0.f; ct_s[t] = 0.f; }
    if (t < D_) {
        bfc_s[t] = b_fc[t];
        cur_res[t] = 0.f;
        float vv = 0.f;
        for (int m = 0; m < D_; ++m) vv += ctx[m] * Wa[m * D_ + t];
        v_s[t] = vv;
    }
    if (t == 10) {
        float cc = 0.f;
        for (int m = 0; m < D_; ++m) cc += ba[m] * ctx[m];
        sc_s[0] = cc;
        sc_s[1] = b_tfc[0];
        sc_s[2] = 0.f;
    }
    for (int k = t; k < N_; k += 1024) {
        bn_s[k] = (short)bnum[(b << 11) + k];
        pad_s[k] = (unsigned char)padf[(b << 11) + k];
    }
    __syncthreads();
    for (int k = t; k < N_; k += 1024) {
        int j = k + 1, pv = bn_s[k];
        while (j < N_ && bn_s[j] == pv) ++j;
        nextc_s[k] = (short)j;
    }
    __syncthreads();

    const float* finrow = finp + ((size_t)b << 11) * 512;
    int bn0 = bn_s[0];
    float gf_cur = 0.f, gf_pre = 0.f, gt_pre = 0.f;
    if (!half) {
        gf_cur = finrow[gr];
        gt_pre = tpre[(size_t)(b * NBEATS_) * 512 + gr];
    }
    int run_start = 0;

    for (int i = 0; i < N_; ++i) {
        int bni = bn_s[i];
        bool changed = (i == 0) || (bni != bn_s[i - 1]);
        int S_prev = run_start;
        if (changed) run_start = i;

        // prefetch next fin row (drained at B1; ~L3 latency hidden by phase work)
        if (!half) gf_pre = finrow[(size_t)(i + 1) * 512 + gr];
        float prev0 = sc_s[2];

        // main recurrent half-matvec (folded weights; hf_s = h(i-1))
        float acc;
        {
            const float4* hp = (const float4*)hf_s + (half << 4);
            float a0 = DOT4(w0, hp[0]) + DOT4(w1, hp[1]) + DOT4(w2, hp[2]) + DOT4(w3, hp[3]);
            float a1 = DOT4(w4, hp[4]) + DOT4(w5, hp[5]) + DOT4(w6, hp[6]) + DOT4(w7, hp[7]);
            float a2 = DOT4(w8, hp[8]) + DOT4(w9, hp[9]) + DOT4(w10, hp[10]) + DOT4(w11, hp[11]);
            float a3 = DOT4(w12, hp[12]) + DOT4(w13, hp[13]) + DOT4(w14, hp[14]) + DOT4(w15, hp[15]);
            acc = (a0 + a1) + (a2 + a3);
        }
        acc += __shfl_xor(acc, 1);
        if (!half) {
            float g = gf_cur + acc;
            if (i > 0) g += bias_r;                 // folded out-feedback bias (prev_out=0 at i=0)
            if (!changed) g += wtail0_r * prev0;    // tempo term (changed: added post-update)
            g_s[gr] = g;
        }
        gf_cur = gf_pre;

        // wave1: finalize step i-1 outputs (off critical path; hf_s still = h(i-1))
        if (wave == 1 && i > 0) {
            int dd = lane >> 3, rl = lane & 7;
            int d2 = 8 + dd;
            float po1 = 0.f, po2 = 0.f;
            for (int k2 = 0; k2 < 16; ++k2) {
                int r = rl + (k2 << 3);
                float hv = hf_s[r];
                po1 += hv * wfcT[r][dd];
                if (d2 < D_) po2 += hv * wfcT[r][d2];
            }
            po1 += __shfl_xor(po1, 1); po1 += __shfl_xor(po1, 2); po1 += __shfl_xor(po1, 4);
            po2 += __shfl_xor(po2, 1); po2 += __shfl_xor(po2, 2); po2 += __shfl_xor(po2, 4);
            int pi = i - 1;
            int pd = pad_s[pi];
            float* orow = out + (size_t)((b << 11) + pi) * OUT_;
            if (rl == 0) {
                float od = po1 + bfc_s[dd];
                xh[pi & 255][dd] = od;
                orow[1 + dd] = pd ? 0.f : od;
                if (d2 < D_) {
                    float od2 = po2 + bfc_s[d2];
                    xh[pi & 255][d2] = od2;
                    orow[1 + d2] = pd ? 0.f : od2;
                }
            }
            if (lane == 1) orow[0] = pd ? 0.f : prev0;
        }

        if (changed) {
            // tempo gate partial: tpre + Whh_t·ht + wiht0*tempo_old
            float acct = 0.f;
            {
                const float4* wtp = (const float4*)(Whh_t + (size_t)gr * 128 + (half << 6));
                const float4* htp = (const float4*)ht_s + (half << 4);
#pragma unroll 1
                for (int c = 0; c < 4; ++c) {
                    float4 t0 = wtp[c * 4 + 0], t1 = wtp[c * 4 + 1];
                    float4 t2 = wtp[c * 4 + 2], t3 = wtp[c * 4 + 3];
                    acct += DOT4(t0, htp[c * 4 + 0]) + DOT4(t1, htp[c * 4 + 1]) +
                            DOT4(t2, htp[c * 4 + 2]) + DOT4(t3, htp[c * 4 + 3]);
                }
            }
            acct += __shfl_xor(acct, 1);
            if (!half) gt_s[gr] = gt_pre + acct + wiht_s[gr * OUT_] * prev0;
        }
        __syncthreads();  // B1

        if (!changed) {
            if (wave == 0 || wave == 2) {
                int rr = lane + ((wave >> 1) << 6);
                float gi = g_s[rr], gff = g_s[128 + rr], gg = g_s[256 + rr], go = g_s[384 + rr];
                float c2 = sigm_(gff) * cf_s[rr] + sigm_(gi) * tanhf(gg);
                float h2 = sigm_(go) * tanhf(c2);
                cf_s[rr] = c2;
                hf_s[rr] = h2;
            }
        } else {
            // attention over previous run [S_prev, i) on wave 0
            if (wave == 0) {
                int L = i - S_prev;
                float lmax = -1e30f;
                for (int tt = lane; tt < L; tt += 64) {
                    const float* xr = xh[(S_prev + tt) & 255];
                    float s = sc_s[0];
#pragma unroll
                    for (int d = 0; d < D_; ++d) s += xr[d] * v_s[d];
                    lmax = fmaxf(lmax, s);
                }
#pragma unroll
                for (int off = 32; off; off >>= 1)
                    lmax = fmaxf(lmax, __shfl_xor(lmax, off, 64));
                float lsum = 0.f, lacc[D_] = {};
                for (int tt = lane; tt < L; tt += 64) {
                    const float* xr = xh[(S_prev + tt) & 255];
                    float s = sc_s[0];
#pragma unroll
                    for (int d = 0; d < D_; ++d) s += xr[d] * v_s[d];
                    float w = expf(s - lmax);
                    lsum += w;
#pragma unroll
                    for (int d = 0; d < D_; ++d) lacc[d] += w * xr[d];
                }
#pragma unroll
                for (int off = 32; off; off >>= 1) {
                    lsum += __shfl_xor(lsum, off, 64);
#pragma unroll
                    for (int d = 0; d < D_; ++d) lacc[d] += __shfl_xor(lacc[d], off, 64);
                }
                if (lane == 0) {
                    if (L > 0) {
                        float inv = 1.0f / lsum;
#pragma unroll
                        for (int d = 0; d < D_; ++d) cur_res[d] = lacc[d] * inv;
                    } else {
#pragma unroll
                        for (int d = 0; d < D_; ++d) cur_res[d] = 0.f;
                    }
                }
            }
            __syncthreads();  // B_c2: cur_res visible
            if (!half) {
                float gv = gt_s[gr];
                const float* wr = &wiht_s[gr * OUT_];
#pragma unroll
                for (int d = 0; d < D_; ++d) gv += wr[1 + d] * cur_res[d];
                gt_s[gr] = gv;
            }
            __syncthreads();  // B_c3: tempo gate vector ready
            if (wave == 0) {
                // tempo LSTM nonlin (both batches) + tempo-fc reduce
                float p = 0.f;
#pragma unroll
                for (int hb = 0; hb < 2; ++hb) {
                    int rr = lane + (hb << 6);
                    float gi = gt_s[rr], gff = gt_s[128 + rr], gg = gt_s[256 + rr],
                          go = gt_s[384 + rr];
                    float c2 = sigm_(gff) * ct_s[rr] + sigm_(gi) * tanhf(gg);
                    float h2 = sigm_(go) * tanhf(c2);
                    ct_s[rr] = c2;
                    ht_s[rr] = h2;
                    p += h2 * wtfc_s[rr];
                }
#pragma unroll
                for (int off = 32; off; off >>= 1) p += __shfl_xor(p, off, 64);
                float tnew = p + sc_s[1];
                if (lane == 0) sc_s[2] = tnew;
                // final LSTM nonlin (both batches) with tempo term added now
#pragma unroll
                for (int hb = 0; hb < 2; ++hb) {
                    int rr = lane + (hb << 6);
                    float gi = g_s[rr] + wtail0_s[rr] * tnew;
                    float gff = g_s[128 + rr] + wtail0_s[128 + rr] * tnew;
                    float gg = g_s[256 + rr] + wtail0_s[256 + rr] * tnew;
                    float go = g_s[384 + rr] + wtail0_s[384 + rr] * tnew;
                    float c2 = sigm_(gff) * cf_s[rr] + sigm_(gi) * tanhf(gg);
                    float h2 = sigm_(go) * tanhf(c2);
                    cf_s[rr] = c2;
                    hf_s[rr] = h2;
                }
            }
            // prefetch tpre row for next changed step
            {
                int j = nextc_s[i];
                if (!half && j < N_)
                    gt_pre = tpre[(size_t)(b * NBEATS_ + (bn_s[j] - bn0)) * 512 + gr];
            }
        }
        __syncthreads();  // Bend
    }

    // epilogue: finalize outputs for i = N_-1 (hf_s = h(N-1))
    if (wave == 1) {
        int dd = lane >> 3, rl = lane & 7;
        int d2 = 8 + dd;
        float po1 = 0.f, po2 = 0.f;
        for (int k2 = 0; k2 < 16; ++k2) {
            int r = rl + (k2 << 3);
            float hv = hf_s[r];
            po1 += hv * wfcT[r][dd];
            if (d2 < D_) po2 += hv * wfcT[r][d2];
        }
        po1 += __shfl_xor(po1, 1); po1 += __shfl_xor(po1, 2); po1 += __shfl_xor(po1, 4);
        po2 += __shfl_xor(po2, 1); po2 += __shfl_xor(po2, 2); po2 += __shfl_xor(po2, 4);
        int pi = N_ - 1;
        int pd = pad_s[pi];
        float* orow = out + (size_t)((b << 11) + pi) * OUT_;
        if (rl == 0) {
            orow[1 + dd] = pd ? 0.f : (po1 + bfc_s[dd]);
            if (d2 < D_) orow[1 + d2] = pd ? 0.f : (po2 + bfc_s[d2]);
        }
        if (lane == 1) orow[0] = pd ? 0.f : sc_s[2];
    }
}

// ---------------------------------------------------------------------------
extern "C" void kernel_launch(void* const* d_in, const int* in_sizes, int n_in,
                              void* d_out, int out_size, void* d_ws, size_t ws_size,
                              hipStream_t stream) {
    const float* note  = (const float*)d_in[0];
    const float* beat  = (const float*)d_in[1];
    const float* meas  = (const float*)d_in[2];
    const int*   bnum  = (const int*)d_in[3];
    const int*   mnum  = (const int*)d_in[4];
    const float* Wa    = (const float*)d_in[5];
    const float* ba    = (const float*)d_in[6];
    const float* ctx   = (const float*)d_in[7];
    const float* Wih_t = (const float*)d_in[8];
    const float* Whh_t = (const float*)d_in[9];
    const float* bih_t = (const float*)d_in[10];
    const float* bhh_t = (const float*)d_in[11];
    const float* Wih_f = (const float*)d_in[12];
    const float* Whh_f = (const float*)d_in[13];
    const float* bih_f = (const float*)d_in[14];
    const float* bhh_f = (const float*)d_in[15];
    const float* W_fc  = (const float*)d_in[16];
    const float* b_fc  = (const float*)d_in[17];
    const float* W_tfc = (const float*)d_in[18];
    const float* b_tfc = (const float*)d_in[19];
    float* out = (float*)d_out;

    char* ws = (char*)d_ws;
    float* finp = (float*)ws;                                   // 64 MB
    float* tpre = (float*)(ws + (size_t)64 * 1024 * 1024);      // 8 MB
    int*   padf = (int*)(ws + (size_t)72 * 1024 * 1024);        // 128 KB

    pad_k<<<8192, 256, 0, stream>>>(note, padf);
    fold_whh<<<512, 128, 0, stream>>>(Whh_f, Wih_f, W_fc, b_fc);
    tempo_pre_k<<<dim3(16, 16), 256, 0, stream>>>(beat, meas, bnum, mnum, Wih_t,
                                                  bih_t, bhh_t, tpre);
    fin_pre_gemm<<<dim3(512, 8), 256, 0, stream>>>(note, beat, meas, bnum, mnum,
                                                   Wih_f, bih_f, bhh_f, finp);
    decode_seq<<<16, 1024, 0, stream>>>(finp, tpre, bnum, padf, Whh_t, Wih_t,
                                        W_fc, b_fc, W_tfc, b_tfc, Wa, ba, ctx,
                                        out);
}

// Round 6
// 10081.469 us; speedup vs baseline: 2.9133x; 1.0411x over previous
//
#include <hip/hip_runtime.h>
#include <cstdint>
#include <cstddef>

#define B_      16
#define N_      2048
#define NOTE_   512
#define BEAT_H_ 128
#define MEAS_H_ 64
#define NBEATS_ 256
#define NMEAS_  64
#define OUT_    11
#define D_      10
// fin = 715 (512 note + 128 beat + 64 meas + 11 prev_out)
// tin = 203 (128 beat + 64 meas + 1 tempo + 10 beat_results)

__device__ __forceinline__ float sigm_(float x) { return 1.0f / (1.0f + expf(-x)); }

// NOTE: parameter names must not collide with float4 member names (x,y,z,w)!
#define DOT4(va, vb) ((va).x * (vb).x + (va).y * (vb).y + (va).z * (vb).z + (va).w * (vb).w)

// Folded recurrent weights: Whh_eff = Whh_f + Wih_f[:,705:715] @ W_fc
// bias_eff = Wih_f[:,705:715] @ b_fc ; wtail0 = Wih_f[:,704]
__device__ float g_whh_eff[512 * 128];
__device__ float g_bias_eff[512];
__device__ float g_wtail0[512];

// ---------------------------------------------------------------------------
__global__ __launch_bounds__(256) void pad_k(const float* __restrict__ note,
                                             int* __restrict__ padf) {
    int wave = threadIdx.x >> 6, lane = threadIdx.x & 63;
    int r = blockIdx.x * 4 + wave;
    const float* row = note + ((size_t)r << 9);
    float s = 0.f;
#pragma unroll
    for (int u = 0; u < 8; ++u) s += row[lane + (u << 6)];
#pragma unroll
    for (int off = 32; off; off >>= 1) s += __shfl_xor(s, off, 64);
    if (lane == 0) padf[r] = (s == 0.0f) ? 1 : 0;
}

// ---------------------------------------------------------------------------
__global__ __launch_bounds__(128) void fold_whh(
    const float* __restrict__ Whh_f, const float* __restrict__ Wih_f,
    const float* __restrict__ W_fc, const float* __restrict__ b_fc) {
    int gr = blockIdx.x;   // 512
    int t = threadIdx.x;   // 128
    __shared__ float tail[OUT_];
    if (t < OUT_) tail[t] = Wih_f[(size_t)gr * 715 + 704 + t];
    __syncthreads();
    float m = Whh_f[(size_t)gr * 128 + t];
#pragma unroll
    for (int d = 0; d < D_; ++d) m += tail[1 + d] * W_fc[d * 128 + t];
    g_whh_eff[(size_t)gr * 128 + t] = m;
    if (t == 0) {
        float bb = 0.f;
#pragma unroll
        for (int d = 0; d < D_; ++d) bb += tail[1 + d] * b_fc[d];
        g_bias_eff[gr] = bb;
        g_wtail0[gr] = tail[0];
    }
}

// ---------------------------------------------------------------------------
__global__ __launch_bounds__(256) void tempo_pre_k(
    const float* __restrict__ beat, const float* __restrict__ meas,
    const int* __restrict__ bnum, const int* __restrict__ mnum,
    const float* __restrict__ Wih_t, const float* __restrict__ bih_t,
    const float* __restrict__ bhh_t, float* __restrict__ tpre) {
    __shared__ float sin_[16][192];
    int b = blockIdx.x, qt = blockIdx.y;
    int t = threadIdx.x;
    int bn0 = bnum[b << 11], mn0 = mnum[b << 11];
    for (int idx = t; idx < 16 * 192; idx += 256) {
        int qq = idx / 192, kk = idx - qq * 192;
        int q = qt * 16 + qq;
        float v;
        if (kk < 128) {
            v = beat[(size_t)(b * NBEATS_ + q) * 128 + kk];
        } else {
            int cm = ((q + bn0) >> 2) - mn0;
            if (cm > 63) cm = 63;
            if (cm < 0) cm = 0;
            v = meas[(size_t)(b * NMEAS_ + cm) * 64 + (kk - 128)];
        }
        sin_[qq][kk] = v;
    }
    __syncthreads();
    for (int half = 0; half < 2; ++half) {
        int j = t + half * 256;
        const float* wr = Wih_t + (size_t)j * 203;
        float bias = bih_t[j] + bhh_t[j];
        float acc[16] = {};
        for (int k = 0; k < 192; ++k) {
            float w = wr[k];
#pragma unroll
            for (int qq = 0; qq < 16; ++qq) acc[qq] += w * sin_[qq][k];
        }
        for (int qq = 0; qq < 16; ++qq)
            tpre[(size_t)(b * NBEATS_ + qt * 16 + qq) * 512 + j] = acc[qq] + bias;
    }
}

// ---------------------------------------------------------------------------
__global__ __launch_bounds__(256) void fin_pre_gemm(
    const float* __restrict__ note, const float* __restrict__ beat,
    const float* __restrict__ meas, const int* __restrict__ bnum,
    const int* __restrict__ mnum, const float* __restrict__ Wih_f,
    const float* __restrict__ bih_f, const float* __restrict__ bhh_f,
    float* __restrict__ finp) {
    __shared__ float As[16][64];
    __shared__ float Bs[16][64];
    int t = threadIdx.x;
    int r0 = blockIdx.x * 64;
    int j0 = blockIdx.y * 64;

    int am = t >> 2, alane = t & 3;
    int r = r0 + am;
    int b = r >> 11;
    int rb = b << 11;
    int cb = bnum[r] - bnum[rb];
    int cm = mnum[r] - mnum[rb];
    const float* arow_note = note + ((size_t)r << 9);
    const float* arow_beat = beat + ((size_t)(b * NBEATS_ + cb) << 7);
    const float* arow_meas = meas + ((size_t)(b * NMEAS_ + cm) << 6);

    int jj = t >> 2, blane = t & 3;
    const float* brow = Wih_f + (size_t)(j0 + jj) * 715;

    int tm0 = (t & 15) * 4, tn0 = (t >> 4) * 4;
    float acc[4][4] = {};

    for (int k0 = 0; k0 < 704; k0 += 16) {
        int ka = k0 + alane * 4;
        float4 av;
        if (ka < 512)      av = *(const float4*)(arow_note + ka);
        else if (ka < 640) av = *(const float4*)(arow_beat + (ka - 512));
        else               av = *(const float4*)(arow_meas + (ka - 640));
        int kb = k0 + blane * 4;
        float b0 = brow[kb], b1 = brow[kb + 1], b2 = brow[kb + 2], b3 = brow[kb + 3];
        __syncthreads();
        As[alane * 4 + 0][am] = av.x;
        As[alane * 4 + 1][am] = av.y;
        As[alane * 4 + 2][am] = av.z;
        As[alane * 4 + 3][am] = av.w;
        Bs[blane * 4 + 0][jj] = b0;
        Bs[blane * 4 + 1][jj] = b1;
        Bs[blane * 4 + 2][jj] = b2;
        Bs[blane * 4 + 3][jj] = b3;
        __syncthreads();
#pragma unroll
        for (int kk = 0; kk < 16; ++kk) {
            float4 a4 = *(const float4*)&As[kk][tm0];
            float4 b4 = *(const float4*)&Bs[kk][tn0];
            float aa[4] = {a4.x, a4.y, a4.z, a4.w};
            float bb[4] = {b4.x, b4.y, b4.z, b4.w};
#pragma unroll
            for (int mi = 0; mi < 4; ++mi)
#pragma unroll
                for (int ni = 0; ni < 4; ++ni) acc[mi][ni] += aa[mi] * bb[ni];
        }
    }
    float bias[4];
#pragma unroll
    for (int ni = 0; ni < 4; ++ni) {
        int j = j0 + tn0 + ni;
        bias[ni] = bih_f[j] + bhh_f[j];
    }
#pragma unroll
    for (int mi = 0; mi < 4; ++mi) {
        int rr = r0 + tm0 + mi;
        float4 o;
        o.x = acc[mi][0] + bias[0];
        o.y = acc[mi][1] + bias[1];
        o.z = acc[mi][2] + bias[2];
        o.w = acc[mi][3] + bias[3];
        *(float4*)(finp + ((size_t)rr << 9) + j0 + tn0) = o;
    }
}

// ---------------------------------------------------------------------------
// sequential decoder: 512 threads, FULL 128-float folded weight row per thread
// in 32 named float4s. waves_per_eu(2,2) => 256-VGPR budget, so weights stay
// resident (no remat incentive). 2 barriers per unchanged step.
// ---------------------------------------------------------------------------
__global__ __launch_bounds__(512)
__attribute__((amdgpu_waves_per_eu(2, 2)))
void decode_seq(
    const float* __restrict__ finp, const float* __restrict__ tpre,
    const int* __restrict__ bnum, const int* __restrict__ padf,
    const float* __restrict__ Whh_t, const float* __restrict__ Wih_t,
    const float* __restrict__ W_fc, const float* __restrict__ b_fc,
    const float* __restrict__ W_tfc, const float* __restrict__ b_tfc,
    const float* __restrict__ Wa, const float* __restrict__ ba,
    const float* __restrict__ ctx, float* __restrict__ out) {
    __shared__ __align__(16) float hf_s[128];
    __shared__ float cf_s[128];
    __shared__ __align__(16) float ht_s[128];
    __shared__ float ct_s[128];
    __shared__ float g_s[512];
    __shared__ float gt_s[512];
    __shared__ float wtail0_s[512];
    __shared__ float wiht_s[512 * OUT_];  // tempo-gate tail cols [gr][0..10]
    __shared__ float wfcT[128][12];       // W_fc transposed [r][d]
    __shared__ float wtfc_s[128];
    __shared__ float bfc_s[12];
    __shared__ float cur_res[12];
    __shared__ float v_s[12];
    __shared__ float sc_s[4];             // [0]=ba·ctx, [1]=b_tfc, [2]=tempo scalar
    __shared__ short bn_s[N_];
    __shared__ short nextc_s[N_];
    __shared__ unsigned char pad_s[N_];
    __shared__ float xh[256][12];         // out-history ring (stride 12)

    int t = threadIdx.x, lane = t & 63, wave = t >> 6;
    int b = blockIdx.x;

    // full folded weight row in 32 named float4 (128 VGPR)
    float4 w0, w1, w2, w3, w4, w5, w6, w7, w8, w9, w10, w11, w12, w13, w14, w15;
    float4 u0, u1, u2, u3, u4, u5, u6, u7, u8, u9, u10, u11, u12, u13, u14, u15;
    {
        const float4* wfp = (const float4*)(g_whh_eff + (size_t)t * 128);
        w0 = wfp[0];   w1 = wfp[1];   w2 = wfp[2];   w3 = wfp[3];
        w4 = wfp[4];   w5 = wfp[5];   w6 = wfp[6];   w7 = wfp[7];
        w8 = wfp[8];   w9 = wfp[9];   w10 = wfp[10]; w11 = wfp[11];
        w12 = wfp[12]; w13 = wfp[13]; w14 = wfp[14]; w15 = wfp[15];
        u0 = wfp[16];  u1 = wfp[17];  u2 = wfp[18];  u3 = wfp[19];
        u4 = wfp[20];  u5 = wfp[21];  u6 = wfp[22];  u7 = wfp[23];
        u8 = wfp[24];  u9 = wfp[25];  u10 = wfp[26]; u11 = wfp[27];
        u12 = wfp[28]; u13 = wfp[29]; u14 = wfp[30]; u15 = wfp[31];
    }
    float bias_r = g_bias_eff[t];
    float wtail0_r = g_wtail0[t];

    for (int k = t; k < 512 * OUT_; k += 512) {
        int r = k / OUT_, u = k - r * OUT_;
        wiht_s[k] = Wih_t[(size_t)r * 203 + 192 + u];
    }
    for (int k = t; k < 128 * D_; k += 512) {
        int d = k >> 7, r = k & 127;
        wfcT[r][d] = W_fc[k];
    }
    wtail0_s[t] = g_wtail0[t];
    if (t < 128) { wtfc_s[t] = W_tfc[t]; hf_s[t] = 0.f; cf_s[t] = 0.f; ht_s[t] = 0.f; ct_s[t] = 0.f; }
    if (t < D_) {
        bfc_s[t] = b_fc[t];
        cur_res[t] = 0.f;
        float vv = 0.f;
        for (int m = 0; m < D_; ++m) vv += ctx[m] * Wa[m * D_ + t];
        v_s[t] = vv;
    }
    if (t == 10) {
        float cc = 0.f;
        for (int m = 0; m < D_; ++m) cc += ba[m] * ctx[m];
        sc_s[0] = cc;
        sc_s[1] = b_tfc[0];
        sc_s[2] = 0.f;
    }
    for (int k = t; k < N_; k += 512) {
        bn_s[k] = (short)bnum[(b << 11) + k];
        pad_s[k] = (unsigned char)padf[(b << 11) + k];
    }
    __syncthreads();
    for (int k = t; k < N_; k += 512) {
        int j = k + 1, pv = bn_s[k];
        while (j < N_ && bn_s[j] == pv) ++j;
        nextc_s[k] = (short)j;
    }
    __syncthreads();

    const float* finrow = finp + ((size_t)b << 11) * 512;
    int bn0 = bn_s[0];
    float gf_cur = finrow[t];
    float gf_pre = 0.f;
    float gt_pre = tpre[(size_t)(b * NBEATS_) * 512 + t];
    int run_start = 0;

    for (int i = 0; i < N_; ++i) {
        int bni = bn_s[i];
        bool changed = (i == 0) || (bni != bn_s[i - 1]);
        int S_prev = run_start;
        if (changed) run_start = i;

        // prefetch next fin row (consumed next iteration)
        gf_pre = finrow[(size_t)(i + 1) * 512 + t];
        float prev0 = sc_s[2];

        // main recurrent matvec (folded weights; hf_s = h(i-1), uniform b128 broadcast)
        float acc;
        {
            const float4* hp = (const float4*)hf_s;
            float a0 = DOT4(w0, hp[0]) + DOT4(w1, hp[1]) + DOT4(w2, hp[2]) + DOT4(w3, hp[3]);
            float a1 = DOT4(w4, hp[4]) + DOT4(w5, hp[5]) + DOT4(w6, hp[6]) + DOT4(w7, hp[7]);
            float a2 = DOT4(w8, hp[8]) + DOT4(w9, hp[9]) + DOT4(w10, hp[10]) + DOT4(w11, hp[11]);
            float a3 = DOT4(w12, hp[12]) + DOT4(w13, hp[13]) + DOT4(w14, hp[14]) + DOT4(w15, hp[15]);
            float a4 = DOT4(u0, hp[16]) + DOT4(u1, hp[17]) + DOT4(u2, hp[18]) + DOT4(u3, hp[19]);
            float a5 = DOT4(u4, hp[20]) + DOT4(u5, hp[21]) + DOT4(u6, hp[22]) + DOT4(u7, hp[23]);
            float a6 = DOT4(u8, hp[24]) + DOT4(u9, hp[25]) + DOT4(u10, hp[26]) + DOT4(u11, hp[27]);
            float a7 = DOT4(u12, hp[28]) + DOT4(u13, hp[29]) + DOT4(u14, hp[30]) + DOT4(u15, hp[31]);
            acc = ((a0 + a1) + (a2 + a3)) + ((a4 + a5) + (a6 + a7));
        }
        {
            float g = gf_cur + acc;
            if (i > 0) g += bias_r;                 // folded out-feedback bias (prev_out=0 at i=0)
            if (!changed) g += wtail0_r * prev0;    // tempo term (changed: added post-update)
            g_s[t] = g;
        }
        gf_cur = gf_pre;

        // wave1: finalize step i-1 outputs (off critical path; hf_s still = h(i-1))
        if (wave == 1 && i > 0) {
            int dd = lane >> 3, rl = lane & 7;
            int d2 = 8 + dd;
            float po1 = 0.f, po2 = 0.f;
            for (int k2 = 0; k2 < 16; ++k2) {
                int r = rl + (k2 << 3);
                float hv = hf_s[r];
                po1 += hv * wfcT[r][dd];
                if (d2 < D_) po2 += hv * wfcT[r][d2];
            }
            po1 += __shfl_xor(po1, 1); po1 += __shfl_xor(po1, 2); po1 += __shfl_xor(po1, 4);
            po2 += __shfl_xor(po2, 1); po2 += __shfl_xor(po2, 2); po2 += __shfl_xor(po2, 4);
            int pi = i - 1;
            int pd = pad_s[pi];
            float* orow = out + (size_t)((b << 11) + pi) * OUT_;
            if (rl == 0) {
                float od = po1 + bfc_s[dd];
                xh[pi & 255][dd] = od;
                orow[1 + dd] = pd ? 0.f : od;
                if (d2 < D_) {
                    float od2 = po2 + bfc_s[d2];
                    xh[pi & 255][d2] = od2;
                    orow[1 + d2] = pd ? 0.f : od2;
                }
            }
            if (lane == 1) orow[0] = pd ? 0.f : prev0;
        }

        if (changed) {
            // tempo gate partial: tpre + Whh_t·ht + wiht0*tempo_old
            // full-row from global (L2-resident); chunked to cap transient VGPRs
            float acct = 0.f;
            {
                const float4* wtp = (const float4*)(Whh_t + (size_t)t * 128);
                const float4* htp = (const float4*)ht_s;
#pragma unroll 1
                for (int c = 0; c < 8; ++c) {
                    float4 t0 = wtp[c * 4 + 0], t1 = wtp[c * 4 + 1];
                    float4 t2 = wtp[c * 4 + 2], t3 = wtp[c * 4 + 3];
                    acct += DOT4(t0, htp[c * 4 + 0]) + DOT4(t1, htp[c * 4 + 1]) +
                            DOT4(t2, htp[c * 4 + 2]) + DOT4(t3, htp[c * 4 + 3]);
                }
            }
            gt_s[t] = gt_pre + acct + wiht_s[t * OUT_] * prev0;
        }
        __syncthreads();  // B1

        if (!changed) {
            if (wave < 2) {
                int rr = lane + (wave << 6);
                float gi = g_s[rr], gff = g_s[128 + rr], gg = g_s[256 + rr], go = g_s[384 + rr];
                float c2 = sigm_(gff) * cf_s[rr] + sigm_(gi) * tanhf(gg);
                float h2 = sigm_(go) * tanhf(c2);
                cf_s[rr] = c2;
                hf_s[rr] = h2;
            }
        } else {
            // attention over previous run [S_prev, i) on wave 0
            if (wave == 0) {
                int L = i - S_prev;
                float lmax = -1e30f;
                for (int tt = lane; tt < L; tt += 64) {
                    const float* xr = xh[(S_prev + tt) & 255];
                    float s = sc_s[0];
#pragma unroll
                    for (int d = 0; d < D_; ++d) s += xr[d] * v_s[d];
                    lmax = fmaxf(lmax, s);
                }
#pragma unroll
                for (int off = 32; off; off >>= 1)
                    lmax = fmaxf(lmax, __shfl_xor(lmax, off, 64));
                float lsum = 0.f, lacc[D_] = {};
                for (int tt = lane; tt < L; tt += 64) {
                    const float* xr = xh[(S_prev + tt) & 255];
                    float s = sc_s[0];
#pragma unroll
                    for (int d = 0; d < D_; ++d) s += xr[d] * v_s[d];
                    float w = expf(s - lmax);
                    lsum += w;
#pragma unroll
                    for (int d = 0; d < D_; ++d) lacc[d] += w * xr[d];
                }
#pragma unroll
                for (int off = 32; off; off >>= 1) {
                    lsum += __shfl_xor(lsum, off, 64);
#pragma unroll
                    for (int d = 0; d < D_; ++d) lacc[d] += __shfl_xor(lacc[d], off, 64);
                }
                if (lane == 0) {
                    if (L > 0) {
                        float inv = 1.0f / lsum;
#pragma unroll
                        for (int d = 0; d < D_; ++d) cur_res[d] = lacc[d] * inv;
                    } else {
#pragma unroll
                        for (int d = 0; d < D_; ++d) cur_res[d] = 0.f;
                    }
                }
            }
            __syncthreads();  // B_c2: cur_res visible
            {
                float gv = gt_s[t];
                const float* wr = &wiht_s[t * OUT_];
#pragma unroll
                for (int d = 0; d < D_; ++d) gv += wr[1 + d] * cur_res[d];
                gt_s[t] = gv;
            }
            __syncthreads();  // B_c3: tempo gate vector ready
            if (wave == 0) {
                // tempo LSTM nonlin (both halves) + tempo-fc reduce
                float p = 0.f;
#pragma unroll
                for (int hb = 0; hb < 2; ++hb) {
                    int rr = lane + (hb << 6);
                    float gi = gt_s[rr], gff = gt_s[128 + rr], gg = gt_s[256 + rr],
                          go = gt_s[384 + rr];
                    float c2 = sigm_(gff) * ct_s[rr] + sigm_(gi) * tanhf(gg);
                    float h2 = sigm_(go) * tanhf(c2);
                    ct_s[rr] = c2;
                    ht_s[rr] = h2;
                    p += h2 * wtfc_s[rr];
                }
#pragma unroll
                for (int off = 32; off; off >>= 1) p += __shfl_xor(p, off, 64);
                float tnew = p + sc_s[1];
                if (lane == 0) sc_s[2] = tnew;
                // final LSTM nonlin (both halves) with tempo term added now
#pragma unroll
                for (int hb = 0; hb < 2; ++hb) {
                    int rr = lane + (hb << 6);
                    float gi = g_s[rr] + wtail0_s[rr] * tnew;
                    float gff = g_s[128 + rr] + wtail0_s[128 + rr] * tnew;
                    float gg = g_s[256 + rr] + wtail0_s[256 + rr] * tnew;
                    float go = g_s[384 + rr] + wtail0_s[384 + rr] * tnew;
                    float c2 = sigm_(gff) * cf_s[rr] + sigm_(gi) * tanhf(gg);
                    float h2 = sigm_(go) * tanhf(c2);
                    cf_s[rr] = c2;
                    hf_s[rr] = h2;
                }
            }
            // prefetch tpre row for next changed step
            {
                int j = nextc_s[i];
                if (j < N_)
                    gt_pre = tpre[(size_t)(b * NBEATS_ + (bn_s[j] - bn0)) * 512 + t];
            }
        }
        __syncthreads();  // Bend
    }

    // epilogue: finalize outputs for i = N_-1 (hf_s = h(N-1))
    if (wave == 1) {
        int dd = lane >> 3, rl = lane & 7;
        int d2 = 8 + dd;
        float po1 = 0.f, po2 = 0.f;
        for (int k2 = 0; k2 < 16; ++k2) {
            int r = rl + (k2 << 3);
            float hv = hf_s[r];
            po1 += hv * wfcT[r][dd];
            if (d2 < D_) po2 += hv * wfcT[r][d2];
        }
        po1 += __shfl_xor(po1, 1); po1 += __shfl_xor(po1, 2); po1 += __shfl_xor(po1, 4);
        po2 += __shfl_xor(po2, 1); po2 += __shfl_xor(po2, 2); po2 += __shfl_xor(po2, 4);
        int pi = N_ - 1;
        int pd = pad_s[pi];
        float* orow = out + (size_t)((b << 11) + pi) * OUT_;
        if (rl == 0) {
            orow[1 + dd] = pd ? 0.f : (po1 + bfc_s[dd]);
            if (d2 < D_) orow[1 + d2] = pd ? 0.f : (po2 + bfc_s[d2]);
        }
        if (lane == 1) orow[0] = pd ? 0.f : sc_s[2];
    }
}

// ---------------------------------------------------------------------------
extern "C" void kernel_launch(void* const* d_in, const int* in_sizes, int n_in,
                              void* d_out, int out_size, void* d_ws, size_t ws_size,
                              hipStream_t stream) {
    const float* note  = (const float*)d_in[0];
    const float* beat  = (const float*)d_in[1];
    const float* meas  = (const float*)d_in[2];
    const int*   bnum  = (const int*)d_in[3];
    const int*   mnum  = (const int*)d_in[4];
    const float* Wa    = (const float*)d_in[5];
    const float* ba    = (const float*)d_in[6];
    const float* ctx   = (const float*)d_in[7];
    const float* Wih_t = (const float*)d_in[8];
    const float* Whh_t = (const float*)d_in[9];
    const float* bih_t = (const float*)d_in[10];
    const float* bhh_t = (const float*)d_in[11];
    const float* Wih_f = (const float*)d_in[12];
    const float* Whh_f = (const float*)d_in[13];
    const float* bih_f = (const float*)d_in[14];
    const float* bhh_f = (const float*)d_in[15];
    const float* W_fc  = (const float*)d_in[16];
    const float* b_fc  = (const float*)d_in[17];
    const float* W_tfc = (const float*)d_in[18];
    const float* b_tfc = (const float*)d_in[19];
    float* out = (float*)d_out;

    char* ws = (char*)d_ws;
    float* finp = (float*)ws;                                   // 64 MB
    float* tpre = (float*)(ws + (size_t)64 * 1024 * 1024);      // 8 MB
    int*   padf = (int*)(ws + (size_t)72 * 1024 * 1024);        // 128 KB

    pad_k<<<8192, 256, 0, stream>>>(note, padf);
    fold_whh<<<512, 128, 0, stream>>>(Whh_f, Wih_f, W_fc, b_fc);
    tempo_pre_k<<<dim3(16, 16), 256, 0, stream>>>(beat, meas, bnum, mnum, Wih_t,
                                                  bih_t, bhh_t, tpre);
    fin_pre_gemm<<<dim3(512, 8), 256, 0, stream>>>(note, beat, meas, bnum, mnum,
                                                   Wih_f, bih_f, bhh_f, finp);
    decode_seq<<<16, 512, 0, stream>>>(finp, tpre, bnum, padf, Whh_t, Wih_t,
                                       W_fc, b_fc, W_tfc, b_tfc, Wa, ba, ctx,
                                       out);
}

// Round 7
// 9934.031 us; speedup vs baseline: 2.9566x; 1.0148x over previous
//
#include <hip/hip_runtime.h>
#include <cstdint>
#include <cstddef>

#define B_      16
#define N_      2048
#define NOTE_   512
#define BEAT_H_ 128
#define MEAS_H_ 64
#define NBEATS_ 256
#define NMEAS_  64
#define OUT_    11
#define D_      10
// fin = 715 (512 note + 128 beat + 64 meas + 11 prev_out)
// tin = 203 (128 beat + 64 meas + 1 tempo + 10 beat_results)

__device__ __forceinline__ float sigm_(float x) { return 1.0f / (1.0f + expf(-x)); }

// NOTE: parameter names must not collide with float4 member names (x,y,z,w)!
#define DOT4(va, vb) ((va).x * (vb).x + (va).y * (vb).y + (va).z * (vb).z + (va).w * (vb).w)

// Folded recurrent weights: Whh_eff = Whh_f + Wih_f[:,705:715] @ W_fc
// bias_eff = Wih_f[:,705:715] @ b_fc ; wtail0 = Wih_f[:,704]
__device__ float g_whh_eff[512 * 128];
__device__ float g_bias_eff[512];
__device__ float g_wtail0[512];

// ---------------------------------------------------------------------------
__global__ __launch_bounds__(256) void pad_k(const float* __restrict__ note,
                                             int* __restrict__ padf) {
    int wave = threadIdx.x >> 6, lane = threadIdx.x & 63;
    int r = blockIdx.x * 4 + wave;
    const float* row = note + ((size_t)r << 9);
    float s = 0.f;
#pragma unroll
    for (int u = 0; u < 8; ++u) s += row[lane + (u << 6)];
#pragma unroll
    for (int off = 32; off; off >>= 1) s += __shfl_xor(s, off, 64);
    if (lane == 0) padf[r] = (s == 0.0f) ? 1 : 0;
}

// ---------------------------------------------------------------------------
__global__ __launch_bounds__(128) void fold_whh(
    const float* __restrict__ Whh_f, const float* __restrict__ Wih_f,
    const float* __restrict__ W_fc, const float* __restrict__ b_fc) {
    int gr = blockIdx.x;   // 512
    int t = threadIdx.x;   // 128
    __shared__ float tail[OUT_];
    if (t < OUT_) tail[t] = Wih_f[(size_t)gr * 715 + 704 + t];
    __syncthreads();
    float m = Whh_f[(size_t)gr * 128 + t];
#pragma unroll
    for (int d = 0; d < D_; ++d) m += tail[1 + d] * W_fc[d * 128 + t];
    g_whh_eff[(size_t)gr * 128 + t] = m;
    if (t == 0) {
        float bb = 0.f;
#pragma unroll
        for (int d = 0; d < D_; ++d) bb += tail[1 + d] * b_fc[d];
        g_bias_eff[gr] = bb;
        g_wtail0[gr] = tail[0];
    }
}

// ---------------------------------------------------------------------------
__global__ __launch_bounds__(256) void tempo_pre_k(
    const float* __restrict__ beat, const float* __restrict__ meas,
    const int* __restrict__ bnum, const int* __restrict__ mnum,
    const float* __restrict__ Wih_t, const float* __restrict__ bih_t,
    const float* __restrict__ bhh_t, float* __restrict__ tpre) {
    __shared__ float sin_[16][192];
    int b = blockIdx.x, qt = blockIdx.y;
    int t = threadIdx.x;
    int bn0 = bnum[b << 11], mn0 = mnum[b << 11];
    for (int idx = t; idx < 16 * 192; idx += 256) {
        int qq = idx / 192, kk = idx - qq * 192;
        int q = qt * 16 + qq;
        float v;
        if (kk < 128) {
            v = beat[(size_t)(b * NBEATS_ + q) * 128 + kk];
        } else {
            int cm = ((q + bn0) >> 2) - mn0;
            if (cm > 63) cm = 63;
            if (cm < 0) cm = 0;
            v = meas[(size_t)(b * NMEAS_ + cm) * 64 + (kk - 128)];
        }
        sin_[qq][kk] = v;
    }
    __syncthreads();
    for (int half = 0; half < 2; ++half) {
        int j = t + half * 256;
        const float* wr = Wih_t + (size_t)j * 203;
        float bias = bih_t[j] + bhh_t[j];
        float acc[16] = {};
        for (int k = 0; k < 192; ++k) {
            float w = wr[k];
#pragma unroll
            for (int qq = 0; qq < 16; ++qq) acc[qq] += w * sin_[qq][k];
        }
        for (int qq = 0; qq < 16; ++qq)
            tpre[(size_t)(b * NBEATS_ + qt * 16 + qq) * 512 + j] = acc[qq] + bias;
    }
}

// ---------------------------------------------------------------------------
__global__ __launch_bounds__(256) void fin_pre_gemm(
    const float* __restrict__ note, const float* __restrict__ beat,
    const float* __restrict__ meas, const int* __restrict__ bnum,
    const int* __restrict__ mnum, const float* __restrict__ Wih_f,
    const float* __restrict__ bih_f, const float* __restrict__ bhh_f,
    float* __restrict__ finp) {
    __shared__ float As[16][64];
    __shared__ float Bs[16][64];
    int t = threadIdx.x;
    int r0 = blockIdx.x * 64;
    int j0 = blockIdx.y * 64;

    int am = t >> 2, alane = t & 3;
    int r = r0 + am;
    int b = r >> 11;
    int rb = b << 11;
    int cb = bnum[r] - bnum[rb];
    int cm = mnum[r] - mnum[rb];
    const float* arow_note = note + ((size_t)r << 9);
    const float* arow_beat = beat + ((size_t)(b * NBEATS_ + cb) << 7);
    const float* arow_meas = meas + ((size_t)(b * NMEAS_ + cm) << 6);

    int jj = t >> 2, blane = t & 3;
    const float* brow = Wih_f + (size_t)(j0 + jj) * 715;

    int tm0 = (t & 15) * 4, tn0 = (t >> 4) * 4;
    float acc[4][4] = {};

    for (int k0 = 0; k0 < 704; k0 += 16) {
        int ka = k0 + alane * 4;
        float4 av;
        if (ka < 512)      av = *(const float4*)(arow_note + ka);
        else if (ka < 640) av = *(const float4*)(arow_beat + (ka - 512));
        else               av = *(const float4*)(arow_meas + (ka - 640));
        int kb = k0 + blane * 4;
        float b0 = brow[kb], b1 = brow[kb + 1], b2 = brow[kb + 2], b3 = brow[kb + 3];
        __syncthreads();
        As[alane * 4 + 0][am] = av.x;
        As[alane * 4 + 1][am] = av.y;
        As[alane * 4 + 2][am] = av.z;
        As[alane * 4 + 3][am] = av.w;
        Bs[blane * 4 + 0][jj] = b0;
        Bs[blane * 4 + 1][jj] = b1;
        Bs[blane * 4 + 2][jj] = b2;
        Bs[blane * 4 + 3][jj] = b3;
        __syncthreads();
#pragma unroll
        for (int kk = 0; kk < 16; ++kk) {
            float4 a4 = *(const float4*)&As[kk][tm0];
            float4 b4 = *(const float4*)&Bs[kk][tn0];
            float aa[4] = {a4.x, a4.y, a4.z, a4.w};
            float bb[4] = {b4.x, b4.y, b4.z, b4.w};
#pragma unroll
            for (int mi = 0; mi < 4; ++mi)
#pragma unroll
                for (int ni = 0; ni < 4; ++ni) acc[mi][ni] += aa[mi] * bb[ni];
        }
    }
    float bias[4];
#pragma unroll
    for (int ni = 0; ni < 4; ++ni) {
        int j = j0 + tn0 + ni;
        bias[ni] = bih_f[j] + bhh_f[j];
    }
#pragma unroll
    for (int mi = 0; mi < 4; ++mi) {
        int rr = r0 + tm0 + mi;
        float4 o;
        o.x = acc[mi][0] + bias[0];
        o.y = acc[mi][1] + bias[1];
        o.z = acc[mi][2] + bias[2];
        o.w = acc[mi][3] + bias[3];
        *(float4*)(finp + ((size_t)rr << 9) + j0 + tn0) = o;
    }
}

// ---------------------------------------------------------------------------
// sequential decoder: 512 threads, FULL 128-float folded weight row per thread
// in 32 named float4s. LDS deliberately >80KB so only ONE block fits per CU:
// the RA targets LDS-limited occupancy (observed r4-r6: VGPR budget = 512 /
// LDS-limited waves-per-EU), so 1 block/CU => 2 waves/EU => 256-VGPR budget
// => weights stay resident instead of being rematerialized from L2 each step.
// ---------------------------------------------------------------------------
__global__ __launch_bounds__(512)
__attribute__((amdgpu_waves_per_eu(2, 2)))
void decode_seq(
    const float* __restrict__ finp, const float* __restrict__ tpre,
    const int* __restrict__ bnum, const int* __restrict__ padf,
    const float* __restrict__ Whh_t, const float* __restrict__ Wih_t,
    const float* __restrict__ W_fc, const float* __restrict__ b_fc,
    const float* __restrict__ W_tfc, const float* __restrict__ b_tfc,
    const float* __restrict__ Wa, const float* __restrict__ ba,
    const float* __restrict__ ctx, float* __restrict__ out) {
    __shared__ __align__(16) float hf_s[128];
    __shared__ float cf_s[128];
    __shared__ __align__(16) float ht_s[128];
    __shared__ float ct_s[128];
    __shared__ float g_s[512];
    __shared__ float gt_s[512];
    __shared__ float wtail0_s[512];
    __shared__ float wiht_s[512 * OUT_];  // tempo-gate tail cols [gr][0..10]
    __shared__ float wfcT[128][12];       // W_fc transposed [r][d]
    __shared__ float wtfc_s[128];
    __shared__ float bfc_s[12];
    __shared__ float cur_res[12];
    __shared__ float v_s[12];
    __shared__ float sc_s[4];             // [0]=ba·ctx, [1]=b_tfc, [2]=tempo scalar
    __shared__ short bn_s[N_];
    __shared__ short nextc_s[N_];
    __shared__ unsigned char pad_s[N_];
    __shared__ float xh[1024][12];        // out-history ring (stride 12); 48KB
                                          // sized to push LDS > 80KB (1 blk/CU)

    int t = threadIdx.x, lane = t & 63, wave = t >> 6;
    int b = blockIdx.x;

    // full folded weight row in 32 named float4 (128 VGPR)
    float4 w0, w1, w2, w3, w4, w5, w6, w7, w8, w9, w10, w11, w12, w13, w14, w15;
    float4 u0, u1, u2, u3, u4, u5, u6, u7, u8, u9, u10, u11, u12, u13, u14, u15;
    {
        const float4* wfp = (const float4*)(g_whh_eff + (size_t)t * 128);
        w0 = wfp[0];   w1 = wfp[1];   w2 = wfp[2];   w3 = wfp[3];
        w4 = wfp[4];   w5 = wfp[5];   w6 = wfp[6];   w7 = wfp[7];
        w8 = wfp[8];   w9 = wfp[9];   w10 = wfp[10]; w11 = wfp[11];
        w12 = wfp[12]; w13 = wfp[13]; w14 = wfp[14]; w15 = wfp[15];
        u0 = wfp[16];  u1 = wfp[17];  u2 = wfp[18];  u3 = wfp[19];
        u4 = wfp[20];  u5 = wfp[21];  u6 = wfp[22];  u7 = wfp[23];
        u8 = wfp[24];  u9 = wfp[25];  u10 = wfp[26]; u11 = wfp[27];
        u12 = wfp[28]; u13 = wfp[29]; u14 = wfp[30]; u15 = wfp[31];
    }
    float bias_r = g_bias_eff[t];
    float wtail0_r = g_wtail0[t];

    for (int k = t; k < 512 * OUT_; k += 512) {
        int r = k / OUT_, u = k - r * OUT_;
        wiht_s[k] = Wih_t[(size_t)r * 203 + 192 + u];
    }
    for (int k = t; k < 128 * D_; k += 512) {
        int d = k >> 7, r = k & 127;
        wfcT[r][d] = W_fc[k];
    }
    wtail0_s[t] = g_wtail0[t];
    if (t < 128) { wtfc_s[t] = W_tfc[t]; hf_s[t] = 0.f; cf_s[t] = 0.f; ht_s[t] = 0.f; ct_s[t] = 0.f; }
    if (t < D_) {
        bfc_s[t] = b_fc[t];
        cur_res[t] = 0.f;
        float vv = 0.f;
        for (int m = 0; m < D_; ++m) vv += ctx[m] * Wa[m * D_ + t];
        v_s[t] = vv;
    }
    if (t == 10) {
        float cc = 0.f;
        for (int m = 0; m < D_; ++m) cc += ba[m] * ctx[m];
        sc_s[0] = cc;
        sc_s[1] = b_tfc[0];
        sc_s[2] = 0.f;
    }
    for (int k = t; k < N_; k += 512) {
        bn_s[k] = (short)bnum[(b << 11) + k];
        pad_s[k] = (unsigned char)padf[(b << 11) + k];
    }
    __syncthreads();
    for (int k = t; k < N_; k += 512) {
        int j = k + 1, pv = bn_s[k];
        while (j < N_ && bn_s[j] == pv) ++j;
        nextc_s[k] = (short)j;
    }
    __syncthreads();

    const float* finrow = finp + ((size_t)b << 11) * 512;
    int bn0 = bn_s[0];
    float gf_cur = finrow[t];
    float gf_pre = 0.f;
    float gt_pre = tpre[(size_t)(b * NBEATS_) * 512 + t];
    int run_start = 0;

    for (int i = 0; i < N_; ++i) {
        int bni = bn_s[i];
        bool changed = (i == 0) || (bni != bn_s[i - 1]);
        int S_prev = run_start;
        if (changed) run_start = i;

        // prefetch next fin row (consumed next iteration)
        gf_pre = finrow[(size_t)(i + 1) * 512 + t];
        float prev0 = sc_s[2];

        // main recurrent matvec (folded weights; hf_s = h(i-1), uniform b128 broadcast)
        float acc;
        {
            const float4* hp = (const float4*)hf_s;
            float a0 = DOT4(w0, hp[0]) + DOT4(w1, hp[1]) + DOT4(w2, hp[2]) + DOT4(w3, hp[3]);
            float a1 = DOT4(w4, hp[4]) + DOT4(w5, hp[5]) + DOT4(w6, hp[6]) + DOT4(w7, hp[7]);
            float a2 = DOT4(w8, hp[8]) + DOT4(w9, hp[9]) + DOT4(w10, hp[10]) + DOT4(w11, hp[11]);
            float a3 = DOT4(w12, hp[12]) + DOT4(w13, hp[13]) + DOT4(w14, hp[14]) + DOT4(w15, hp[15]);
            float a4 = DOT4(u0, hp[16]) + DOT4(u1, hp[17]) + DOT4(u2, hp[18]) + DOT4(u3, hp[19]);
            float a5 = DOT4(u4, hp[20]) + DOT4(u5, hp[21]) + DOT4(u6, hp[22]) + DOT4(u7, hp[23]);
            float a6 = DOT4(u8, hp[24]) + DOT4(u9, hp[25]) + DOT4(u10, hp[26]) + DOT4(u11, hp[27]);
            float a7 = DOT4(u12, hp[28]) + DOT4(u13, hp[29]) + DOT4(u14, hp[30]) + DOT4(u15, hp[31]);
            acc = ((a0 + a1) + (a2 + a3)) + ((a4 + a5) + (a6 + a7));
        }
        {
            float g = gf_cur + acc;
            if (i > 0) g += bias_r;                 // folded out-feedback bias (prev_out=0 at i=0)
            if (!changed) g += wtail0_r * prev0;    // tempo term (changed: added post-update)
            g_s[t] = g;
        }
        gf_cur = gf_pre;

        // wave1: finalize step i-1 outputs (off critical path; hf_s still = h(i-1))
        if (wave == 1 && i > 0) {
            int dd = lane >> 3, rl = lane & 7;
            int d2 = 8 + dd;
            float po1 = 0.f, po2 = 0.f;
            for (int k2 = 0; k2 < 16; ++k2) {
                int r = rl + (k2 << 3);
                float hv = hf_s[r];
                po1 += hv * wfcT[r][dd];
                if (d2 < D_) po2 += hv * wfcT[r][d2];
            }
            po1 += __shfl_xor(po1, 1); po1 += __shfl_xor(po1, 2); po1 += __shfl_xor(po1, 4);
            po2 += __shfl_xor(po2, 1); po2 += __shfl_xor(po2, 2); po2 += __shfl_xor(po2, 4);
            int pi = i - 1;
            int pd = pad_s[pi];
            float* orow = out + (size_t)((b << 11) + pi) * OUT_;
            if (rl == 0) {
                float od = po1 + bfc_s[dd];
                xh[pi & 1023][dd] = od;
                orow[1 + dd] = pd ? 0.f : od;
                if (d2 < D_) {
                    float od2 = po2 + bfc_s[d2];
                    xh[pi & 1023][d2] = od2;
                    orow[1 + d2] = pd ? 0.f : od2;
                }
            }
            if (lane == 1) orow[0] = pd ? 0.f : prev0;
        }

        if (changed) {
            // tempo gate partial: tpre + Whh_t·ht + wiht0*tempo_old
            // full-row from global (L2-resident); chunked to cap transient VGPRs
            float acct = 0.f;
            {
                const float4* wtp = (const float4*)(Whh_t + (size_t)t * 128);
                const float4* htp = (const float4*)ht_s;
#pragma unroll 1
                for (int c = 0; c < 8; ++c) {
                    float4 t0 = wtp[c * 4 + 0], t1 = wtp[c * 4 + 1];
                    float4 t2 = wtp[c * 4 + 2], t3 = wtp[c * 4 + 3];
                    acct += DOT4(t0, htp[c * 4 + 0]) + DOT4(t1, htp[c * 4 + 1]) +
                            DOT4(t2, htp[c * 4 + 2]) + DOT4(t3, htp[c * 4 + 3]);
                }
            }
            gt_s[t] = gt_pre + acct + wiht_s[t * OUT_] * prev0;
        }
        __syncthreads();  // B1

        if (!changed) {
            if (wave < 2) {
                int rr = lane + (wave << 6);
                float gi = g_s[rr], gff = g_s[128 + rr], gg = g_s[256 + rr], go = g_s[384 + rr];
                float c2 = sigm_(gff) * cf_s[rr] + sigm_(gi) * tanhf(gg);
                float h2 = sigm_(go) * tanhf(c2);
                cf_s[rr] = c2;
                hf_s[rr] = h2;
            }
        } else {
            // attention over previous run [S_prev, i) on wave 0
            if (wave == 0) {
                int L = i - S_prev;
                float lmax = -1e30f;
                for (int tt = lane; tt < L; tt += 64) {
                    const float* xr = xh[(S_prev + tt) & 1023];
                    float s = sc_s[0];
#pragma unroll
                    for (int d = 0; d < D_; ++d) s += xr[d] * v_s[d];
                    lmax = fmaxf(lmax, s);
                }
#pragma unroll
                for (int off = 32; off; off >>= 1)
                    lmax = fmaxf(lmax, __shfl_xor(lmax, off, 64));
                float lsum = 0.f, lacc[D_] = {};
                for (int tt = lane; tt < L; tt += 64) {
                    const float* xr = xh[(S_prev + tt) & 1023];
                    float s = sc_s[0];
#pragma unroll
                    for (int d = 0; d < D_; ++d) s += xr[d] * v_s[d];
                    float w = expf(s - lmax);
                    lsum += w;
#pragma unroll
                    for (int d = 0; d < D_; ++d) lacc[d] += w * xr[d];
                }
#pragma unroll
                for (int off = 32; off; off >>= 1) {
                    lsum += __shfl_xor(lsum, off, 64);
#pragma unroll
                    for (int d = 0; d < D_; ++d) lacc[d] += __shfl_xor(lacc[d], off, 64);
                }
                if (lane == 0) {
                    if (L > 0) {
                        float inv = 1.0f / lsum;
#pragma unroll
                        for (int d = 0; d < D_; ++d) cur_res[d] = lacc[d] * inv;
                    } else {
#pragma unroll
                        for (int d = 0; d < D_; ++d) cur_res[d] = 0.f;
                    }
                }
            }
            __syncthreads();  // B_c2: cur_res visible
            {
                float gv = gt_s[t];
                const float* wr = &wiht_s[t * OUT_];
#pragma unroll
                for (int d = 0; d < D_; ++d) gv += wr[1 + d] * cur_res[d];
                gt_s[t] = gv;
            }
            __syncthreads();  // B_c3: tempo gate vector ready
            if (wave == 0) {
                // tempo LSTM nonlin (both halves) + tempo-fc reduce
                float p = 0.f;
#pragma unroll
                for (int hb = 0; hb < 2; ++hb) {
                    int rr = lane + (hb << 6);
                    float gi = gt_s[rr], gff = gt_s[128 + rr], gg = gt_s[256 + rr],
                          go = gt_s[384 + rr];
                    float c2 = sigm_(gff) * ct_s[rr] + sigm_(gi) * tanhf(gg);
                    float h2 = sigm_(go) * tanhf(c2);
                    ct_s[rr] = c2;
                    ht_s[rr] = h2;
                    p += h2 * wtfc_s[rr];
                }
#pragma unroll
                for (int off = 32; off; off >>= 1) p += __shfl_xor(p, off, 64);
                float tnew = p + sc_s[1];
                if (lane == 0) sc_s[2] = tnew;
                // final LSTM nonlin (both halves) with tempo term added now
#pragma unroll
                for (int hb = 0; hb < 2; ++hb) {
                    int rr = lane + (hb << 6);
                    float gi = g_s[rr] + wtail0_s[rr] * tnew;
                    float gff = g_s[128 + rr] + wtail0_s[128 + rr] * tnew;
                    float gg = g_s[256 + rr] + wtail0_s[256 + rr] * tnew;
                    float go = g_s[384 + rr] + wtail0_s[384 + rr] * tnew;
                    float c2 = sigm_(gff) * cf_s[rr] + sigm_(gi) * tanhf(gg);
                    float h2 = sigm_(go) * tanhf(c2);
                    cf_s[rr] = c2;
                    hf_s[rr] = h2;
                }
            }
            // prefetch tpre row for next changed step
            {
                int j = nextc_s[i];
                if (j < N_)
                    gt_pre = tpre[(size_t)(b * NBEATS_ + (bn_s[j] - bn0)) * 512 + t];
            }
        }
        __syncthreads();  // Bend
    }

    // epilogue: finalize outputs for i = N_-1 (hf_s = h(N-1))
    if (wave == 1) {
        int dd = lane >> 3, rl = lane & 7;
        int d2 = 8 + dd;
        float po1 = 0.f, po2 = 0.f;
        for (int k2 = 0; k2 < 16; ++k2) {
            int r = rl + (k2 << 3);
            float hv = hf_s[r];
            po1 += hv * wfcT[r][dd];
            if (d2 < D_) po2 += hv * wfcT[r][d2];
        }
        po1 += __shfl_xor(po1, 1); po1 += __shfl_xor(po1, 2); po1 += __shfl_xor(po1, 4);
        po2 += __shfl_xor(po2, 1); po2 += __shfl_xor(po2, 2); po2 += __shfl_xor(po2, 4);
        int pi = N_ - 1;
        int pd = pad_s[pi];
        float* orow = out + (size_t)((b << 11) + pi) * OUT_;
        if (rl == 0) {
            orow[1 + dd] = pd ? 0.f : (po1 + bfc_s[dd]);
            if (d2 < D_) orow[1 + d2] = pd ? 0.f : (po2 + bfc_s[d2]);
        }
        if (lane == 1) orow[0] = pd ? 0.f : sc_s[2];
    }
}

// ---------------------------------------------------------------------------
extern "C" void kernel_launch(void* const* d_in, const int* in_sizes, int n_in,
                              void* d_out, int out_size, void* d_ws, size_t ws_size,
                              hipStream_t stream) {
    const float* note  = (const float*)d_in[0];
    const float* beat  = (const float*)d_in[1];
    const float* meas  = (const float*)d_in[2];
    const int*   bnum  = (const int*)d_in[3];
    const int*   mnum  = (const int*)d_in[4];
    const float* Wa    = (const float*)d_in[5];
    const float* ba    = (const float*)d_in[6];
    const float* ctx   = (const float*)d_in[7];
    const float* Wih_t = (const float*)d_in[8];
    const float* Whh_t = (const float*)d_in[9];
    const float* bih_t = (const float*)d_in[10];
    const float* bhh_t = (const float*)d_in[11];
    const float* Wih_f = (const float*)d_in[12];
    const float* Whh_f = (const float*)d_in[13];
    const float* bih_f = (const float*)d_in[14];
    const float* bhh_f = (const float*)d_in[15];
    const float* W_fc  = (const float*)d_in[16];
    const float* b_fc  = (const float*)d_in[17];
    const float* W_tfc = (const float*)d_in[18];
    const float* b_tfc = (const float*)d_in[19];
    float* out = (float*)d_out;

    char* ws = (char*)d_ws;
    float* finp = (float*)ws;                                   // 64 MB
    float* tpre = (float*)(ws + (size_t)64 * 1024 * 1024);      // 8 MB
    int*   padf = (int*)(ws + (size_t)72 * 1024 * 1024);        // 128 KB

    pad_k<<<8192, 256, 0, stream>>>(note, padf);
    fold_whh<<<512, 128, 0, stream>>>(Whh_f, Wih_f, W_fc, b_fc);
    tempo_pre_k<<<dim3(16, 16), 256, 0, stream>>>(beat, meas, bnum, mnum, Wih_t,
                                                  bih_t, bhh_t, tpre);
    fin_pre_gemm<<<dim3(512, 8), 256, 0, stream>>>(note, beat, meas, bnum, mnum,
                                                   Wih_f, bih_f, bhh_f, finp);
    decode_seq<<<16, 512, 0, stream>>>(finp, tpre, bnum, padf, Whh_t, Wih_t,
                                       W_fc, b_fc, W_tfc, b_tfc, Wa, ba, ctx,
                                       out);
}

// Round 8
// 6766.973 us; speedup vs baseline: 4.3403x; 1.4680x over previous
//
#include <hip/hip_runtime.h>
#include <cstdint>
#include <cstddef>

#define B_      16
#define N_      2048
#define NOTE_   512
#define BEAT_H_ 128
#define MEAS_H_ 64
#define NBEATS_ 256
#define NMEAS_  64
#define OUT_    11
#define D_      10
#define WSTRIDE 136   // fp16 weight row stride: 68 dwords == 4 mod 32 -> bank-spread
// fin = 715 (512 note + 128 beat + 64 meas + 11 prev_out)
// tin = 203 (128 beat + 64 meas + 1 tempo + 10 beat_results)

typedef _Float16 h2v __attribute__((ext_vector_type(2)));

__device__ __forceinline__ float sigm_(float x) { return 1.0f / (1.0f + expf(-x)); }

#define DOT4(va, vb) ((va).x * (vb).x + (va).y * (vb).y + (va).z * (vb).z + (va).w * (vb).w)

__device__ __forceinline__ float dot2f_(unsigned wu, unsigned hu, float c) {
    union { unsigned u; h2v h; } a, bb;
    a.u = wu; bb.u = hu;
#if __has_builtin(__builtin_amdgcn_fdot2)
    return __builtin_amdgcn_fdot2(a.h, bb.h, c, false);
#else
    return c + (float)a.h[0] * (float)bb.h[0] + (float)a.h[1] * (float)bb.h[1];
#endif
}

// Folded recurrent weights (fp16, padded stride): Whh_eff = Whh_f + Wih_f[:,705:715] @ W_fc
__device__ __align__(16) _Float16 g_whh_h16[512 * WSTRIDE];
__device__ float g_bias_eff[512];
__device__ float g_wtail0[512];

// ---------------------------------------------------------------------------
__global__ __launch_bounds__(256) void pad_k(const float* __restrict__ note,
                                             int* __restrict__ padf) {
    int wave = threadIdx.x >> 6, lane = threadIdx.x & 63;
    int r = blockIdx.x * 4 + wave;
    const float* row = note + ((size_t)r << 9);
    float s = 0.f;
#pragma unroll
    for (int u = 0; u < 8; ++u) s += row[lane + (u << 6)];
#pragma unroll
    for (int off = 32; off; off >>= 1) s += __shfl_xor(s, off, 64);
    if (lane == 0) padf[r] = (s == 0.0f) ? 1 : 0;
}

// ---------------------------------------------------------------------------
__global__ __launch_bounds__(128) void fold_whh(
    const float* __restrict__ Whh_f, const float* __restrict__ Wih_f,
    const float* __restrict__ W_fc, const float* __restrict__ b_fc) {
    int gr = blockIdx.x;   // 512
    int t = threadIdx.x;   // 128
    __shared__ float tail[OUT_];
    if (t < OUT_) tail[t] = Wih_f[(size_t)gr * 715 + 704 + t];
    __syncthreads();
    float m = Whh_f[(size_t)gr * 128 + t];
#pragma unroll
    for (int d = 0; d < D_; ++d) m += tail[1 + d] * W_fc[d * 128 + t];
    g_whh_h16[(size_t)gr * WSTRIDE + t] = (_Float16)m;
    if (t < 8) g_whh_h16[(size_t)gr * WSTRIDE + 128 + t] = (_Float16)0.f;
    if (t == 0) {
        float bb = 0.f;
#pragma unroll
        for (int d = 0; d < D_; ++d) bb += tail[1 + d] * b_fc[d];
        g_bias_eff[gr] = bb;
        g_wtail0[gr] = tail[0];
    }
}

// ---------------------------------------------------------------------------
__global__ __launch_bounds__(256) void tempo_pre_k(
    const float* __restrict__ beat, const float* __restrict__ meas,
    const int* __restrict__ bnum, const int* __restrict__ mnum,
    const float* __restrict__ Wih_t, const float* __restrict__ bih_t,
    const float* __restrict__ bhh_t, float* __restrict__ tpre) {
    __shared__ float sin_[16][192];
    int b = blockIdx.x, qt = blockIdx.y;
    int t = threadIdx.x;
    int bn0 = bnum[b << 11], mn0 = mnum[b << 11];
    for (int idx = t; idx < 16 * 192; idx += 256) {
        int qq = idx / 192, kk = idx - qq * 192;
        int q = qt * 16 + qq;
        float v;
        if (kk < 128) {
            v = beat[(size_t)(b * NBEATS_ + q) * 128 + kk];
        } else {
            int cm = ((q + bn0) >> 2) - mn0;
            if (cm > 63) cm = 63;
            if (cm < 0) cm = 0;
            v = meas[(size_t)(b * NMEAS_ + cm) * 64 + (kk - 128)];
        }
        sin_[qq][kk] = v;
    }
    __syncthreads();
    for (int half = 0; half < 2; ++half) {
        int j = t + half * 256;
        const float* wr = Wih_t + (size_t)j * 203;
        float bias = bih_t[j] + bhh_t[j];
        float acc[16] = {};
        for (int k = 0; k < 192; ++k) {
            float w = wr[k];
#pragma unroll
            for (int qq = 0; qq < 16; ++qq) acc[qq] += w * sin_[qq][k];
        }
        for (int qq = 0; qq < 16; ++qq)
            tpre[(size_t)(b * NBEATS_ + qt * 16 + qq) * 512 + j] = acc[qq] + bias;
    }
}

// ---------------------------------------------------------------------------
__global__ __launch_bounds__(256) void fin_pre_gemm(
    const float* __restrict__ note, const float* __restrict__ beat,
    const float* __restrict__ meas, const int* __restrict__ bnum,
    const int* __restrict__ mnum, const float* __restrict__ Wih_f,
    const float* __restrict__ bih_f, const float* __restrict__ bhh_f,
    float* __restrict__ finp) {
    __shared__ float As[16][64];
    __shared__ float Bs[16][64];
    int t = threadIdx.x;
    int r0 = blockIdx.x * 64;
    int j0 = blockIdx.y * 64;

    int am = t >> 2, alane = t & 3;
    int r = r0 + am;
    int b = r >> 11;
    int rb = b << 11;
    int cb = bnum[r] - bnum[rb];
    int cm = mnum[r] - mnum[rb];
    const float* arow_note = note + ((size_t)r << 9);
    const float* arow_beat = beat + ((size_t)(b * NBEATS_ + cb) << 7);
    const float* arow_meas = meas + ((size_t)(b * NMEAS_ + cm) << 6);

    int jj = t >> 2, blane = t & 3;
    const float* brow = Wih_f + (size_t)(j0 + jj) * 715;

    int tm0 = (t & 15) * 4, tn0 = (t >> 4) * 4;
    float acc[4][4] = {};

    for (int k0 = 0; k0 < 704; k0 += 16) {
        int ka = k0 + alane * 4;
        float4 av;
        if (ka < 512)      av = *(const float4*)(arow_note + ka);
        else if (ka < 640) av = *(const float4*)(arow_beat + (ka - 512));
        else               av = *(const float4*)(arow_meas + (ka - 640));
        int kb = k0 + blane * 4;
        float b0 = brow[kb], b1 = brow[kb + 1], b2 = brow[kb + 2], b3 = brow[kb + 3];
        __syncthreads();
        As[alane * 4 + 0][am] = av.x;
        As[alane * 4 + 1][am] = av.y;
        As[alane * 4 + 2][am] = av.z;
        As[alane * 4 + 3][am] = av.w;
        Bs[blane * 4 + 0][jj] = b0;
        Bs[blane * 4 + 1][jj] = b1;
        Bs[blane * 4 + 2][jj] = b2;
        Bs[blane * 4 + 3][jj] = b3;
        __syncthreads();
#pragma unroll
        for (int kk = 0; kk < 16; ++kk) {
            float4 a4 = *(const float4*)&As[kk][tm0];
            float4 b4 = *(const float4*)&Bs[kk][tn0];
            float aa[4] = {a4.x, a4.y, a4.z, a4.w};
            float bb[4] = {b4.x, b4.y, b4.z, b4.w};
#pragma unroll
            for (int mi = 0; mi < 4; ++mi)
#pragma unroll
                for (int ni = 0; ni < 4; ++ni) acc[mi][ni] += aa[mi] * bb[ni];
        }
    }
    float bias[4];
#pragma unroll
    for (int ni = 0; ni < 4; ++ni) {
        int j = j0 + tn0 + ni;
        bias[ni] = bih_f[j] + bhh_f[j];
    }
#pragma unroll
    for (int mi = 0; mi < 4; ++mi) {
        int rr = r0 + tm0 + mi;
        float4 o;
        o.x = acc[mi][0] + bias[0];
        o.y = acc[mi][1] + bias[1];
        o.z = acc[mi][2] + bias[2];
        o.w = acc[mi][3] + bias[3];
        *(float4*)(finp + ((size_t)rr << 9) + j0 + tn0) = o;
    }
}

// ---------------------------------------------------------------------------
// sequential decoder: folded Whh as fp16 in LDS (no register-residency fight),
// h packed fp16 per step, fdot2 matvec. xh history in global ws (64B rows).
// Run-compressed beat bookkeeping (prefix-scan at init).
// ---------------------------------------------------------------------------
__global__ __launch_bounds__(512) void decode_seq(
    const float* __restrict__ finp, const float* __restrict__ tpre,
    const int* __restrict__ bnum, const int* __restrict__ padf,
    const float* __restrict__ Whh_t, const float* __restrict__ Wih_t,
    const float* __restrict__ W_fc, const float* __restrict__ b_fc,
    const float* __restrict__ W_tfc, const float* __restrict__ b_tfc,
    const float* __restrict__ Wa, const float* __restrict__ ba,
    const float* __restrict__ ctx, float* __restrict__ out,
    float* __restrict__ xg) {
    __shared__ __align__(16) _Float16 whh16_s[512 * WSTRIDE];  // 139264 B
    __shared__ __align__(16) _Float16 h16_s[128];
    __shared__ __align__(16) float hf_s[128];
    __shared__ float cf_s[128];
    __shared__ __align__(16) float ht_s[128];
    __shared__ float ct_s[128];
    __shared__ float g_s[512];
    __shared__ float gt_s[512];
    __shared__ float wtail0_s[512];
    __shared__ float wfcT[128][12];       // W_fc transposed [r][d]
    __shared__ float wtfc_s[128];
    __shared__ float bfc_s[12];
    __shared__ float cur_res[12];
    __shared__ float v_s[12];
    __shared__ float sc_s[4];             // [0]=ba.ctx, [1]=b_tfc, [2]=tempo scalar
    __shared__ unsigned long long padw_s[32];
    __shared__ unsigned short run_start_s[300];
    __shared__ short run_cb_s[300];
    __shared__ int nruns_s;

    int t = threadIdx.x, lane = t & 63, wave = t >> 6;
    int b = blockIdx.x;

    // ---- weights: global fp16 -> LDS (flat copy, 8704 uint4) ----
    {
        const uint4* src = (const uint4*)g_whh_h16;
        uint4* dst = (uint4*)whh16_s;
#pragma unroll
        for (int k = 0; k < 17; ++k) dst[t + 512 * k] = src[t + 512 * k];
    }
    float bias_r = g_bias_eff[t];
    float wtail0_r = g_wtail0[t];
    wtail0_s[t] = wtail0_r;
    float wiht_r[OUT_];
#pragma unroll
    for (int u = 0; u < OUT_; ++u) wiht_r[u] = Wih_t[(size_t)t * 203 + 192 + u];
    for (int k = t; k < 128 * D_; k += 512) {
        int d = k >> 7, r = k & 127;
        wfcT[r][d] = W_fc[k];
    }
    if (t < 128) {
        wtfc_s[t] = W_tfc[t];
        hf_s[t] = 0.f; cf_s[t] = 0.f; ht_s[t] = 0.f; ct_s[t] = 0.f;
        h16_s[t] = (_Float16)0.f;
    }
    if (t < D_) {
        bfc_s[t] = b_fc[t];
        cur_res[t] = 0.f;
        float vv = 0.f;
        for (int m = 0; m < D_; ++m) vv += ctx[m] * Wa[m * D_ + t];
        v_s[t] = vv;
    }
    if (t == 10) {
        float cc = 0.f;
        for (int m = 0; m < D_; ++m) cc += ba[m] * ctx[m];
        sc_s[0] = cc;
        sc_s[1] = b_tfc[0];
        sc_s[2] = 0.f;
    }
    // pad bitmask: waves 2..5 build 8 words each via ballot
    if (wave >= 2 && wave < 6) {
        for (int jj = 0; jj < 8; ++jj) {
            int j = (wave - 2) * 8 + jj;
            int pv = padf[(b << 11) + j * 64 + lane];
            unsigned long long m = __ballot(pv != 0);
            if (lane == 0) padw_s[j] = m;
        }
    }
    // runs: per-thread counts over 4 contiguous indices
    const int* bnb = bnum + (b << 11);
    int bn0 = bnb[0];
    int base = t * 4;
    int bvm = (base == 0) ? 0 : bnb[base - 1];
    int bv0 = bnb[base], bv1 = bnb[base + 1], bv2 = bnb[base + 2], bv3 = bnb[base + 3];
    if (base == 0) bvm = bv0 - 1;  // force change at i=0
    int c = (bv0 != bvm) + (bv1 != bv0) + (bv2 != bv1) + (bv3 != bv2);
    ((int*)g_s)[t] = c;
    __syncthreads();
    if (wave == 0) {
        int c8[8], s = 0;
#pragma unroll
        for (int j = 0; j < 8; ++j) { c8[j] = ((int*)g_s)[lane * 8 + j]; s += c8[j]; }
        int incl = s;
#pragma unroll
        for (int off = 1; off < 64; off <<= 1) {
            int n = __shfl_up(incl, off, 64);
            if (lane >= off) incl += n;
        }
        int run = incl - s;
#pragma unroll
        for (int j = 0; j < 8; ++j) { ((int*)gt_s)[lane * 8 + j] = run; run += c8[j]; }
        if (lane == 63) nruns_s = incl;
    }
    __syncthreads();
    {
        int O = ((int*)gt_s)[t];
        if (bv0 != bvm) { run_start_s[O] = (unsigned short)(base + 0); run_cb_s[O] = (short)(bv0 - bn0); O++; }
        if (bv1 != bv0) { run_start_s[O] = (unsigned short)(base + 1); run_cb_s[O] = (short)(bv1 - bn0); O++; }
        if (bv2 != bv1) { run_start_s[O] = (unsigned short)(base + 2); run_cb_s[O] = (short)(bv2 - bn0); O++; }
        if (bv3 != bv2) { run_start_s[O] = (unsigned short)(base + 3); run_cb_s[O] = (short)(bv3 - bn0); O++; }
    }
    __syncthreads();
    int nruns_r = nruns_s;

    const float* finrow = finp + ((size_t)b << 11) * 512;
    float* xgb = xg + ((size_t)(b << 11)) * 16;
    float gf_cur = finrow[t];
    float gt_pre = tpre[(size_t)(b * NBEATS_) * 512 + t];  // run0 cb = 0
    int cur_run = -1, next_start = 0, run_s = 0, S_prev = 0;

    for (int i = 0; i < N_; ++i) {
        bool changed = (i == next_start);
        if (changed) {
            cur_run++;
            S_prev = run_s;
            run_s = i;
            next_start = (cur_run + 1 < nruns_r) ? (int)run_start_s[cur_run + 1] : 4096;
        }
        float gf_pre = finrow[(size_t)(i + 1) * 512 + t];
        float prev0 = sc_s[2];

        // ---- main matvec: fp16 weights (LDS) x fp16 h (LDS broadcast), fp32 acc ----
        float acc;
        {
            const uint4* wq = (const uint4*)(whh16_s + (size_t)t * WSTRIDE);
            const uint4* hq = (const uint4*)h16_s;
            float a0 = 0.f, a1 = 0.f, a2 = 0.f, a3 = 0.f;
#pragma unroll
            for (int k = 0; k < 16; ++k) {
                uint4 W = wq[k];
                uint4 H = hq[k];
                a0 = dot2f_(W.x, H.x, a0);
                a1 = dot2f_(W.y, H.y, a1);
                a2 = dot2f_(W.z, H.z, a2);
                a3 = dot2f_(W.w, H.w, a3);
            }
            acc = (a0 + a1) + (a2 + a3);
        }
        {
            float g = gf_cur + acc;
            if (i > 0) g += bias_r;               // folded out-feedback bias
            if (!changed) g += wtail0_r * prev0;  // tempo term (changed: added post-update)
            g_s[t] = g;
        }
        gf_cur = gf_pre;

        // wave1: finalize step i-1 outputs (hf_s still = h(i-1))
        if (wave == 1 && i > 0) {
            int dd = lane >> 3, rl = lane & 7;
            int d2 = 8 + dd;
            float po1 = 0.f, po2 = 0.f;
            for (int k2 = 0; k2 < 16; ++k2) {
                int r = rl + (k2 << 3);
                float hv = hf_s[r];
                po1 += hv * wfcT[r][dd];
                if (d2 < D_) po2 += hv * wfcT[r][d2];
            }
            po1 += __shfl_xor(po1, 1); po1 += __shfl_xor(po1, 2); po1 += __shfl_xor(po1, 4);
            po2 += __shfl_xor(po2, 1); po2 += __shfl_xor(po2, 2); po2 += __shfl_xor(po2, 4);
            int pi = i - 1;
            int pd = (int)((padw_s[pi >> 6] >> (pi & 63)) & 1ULL);
            float* orow = out + (size_t)((b << 11) + pi) * OUT_;
            float* xrow = xgb + (size_t)pi * 16;
            if (rl == 0) {
                float od = po1 + bfc_s[dd];
                xrow[dd] = od;
                orow[1 + dd] = pd ? 0.f : od;
                if (d2 < D_) {
                    float od2 = po2 + bfc_s[d2];
                    xrow[d2] = od2;
                    orow[1 + d2] = pd ? 0.f : od2;
                }
            }
            if (lane == 1) orow[0] = pd ? 0.f : prev0;
        }

        if (changed) {
            // tempo gate partial: tpre + Whh_t.ht (fp32 from global/L2) + wiht0*prev0
            float acct = 0.f;
            {
                const float4* wtp = (const float4*)(Whh_t + (size_t)t * 128);
                const float4* htp = (const float4*)ht_s;
#pragma unroll 1
                for (int cc = 0; cc < 8; ++cc) {
                    float4 t0 = wtp[cc * 4 + 0], t1 = wtp[cc * 4 + 1];
                    float4 t2 = wtp[cc * 4 + 2], t3 = wtp[cc * 4 + 3];
                    acct += DOT4(t0, htp[cc * 4 + 0]) + DOT4(t1, htp[cc * 4 + 1]) +
                            DOT4(t2, htp[cc * 4 + 2]) + DOT4(t3, htp[cc * 4 + 3]);
                }
            }
            gt_s[t] = gt_pre + acct + wiht_r[0] * prev0;
        }
        __syncthreads();  // B1

        if (!changed) {
            if (wave < 2) {
                int rr = lane + (wave << 6);
                float gi = g_s[rr], gff = g_s[128 + rr], gg = g_s[256 + rr], go = g_s[384 + rr];
                float c2 = sigm_(gff) * cf_s[rr] + sigm_(gi) * tanhf(gg);
                float h2 = sigm_(go) * tanhf(c2);
                cf_s[rr] = c2;
                hf_s[rr] = h2;
                h16_s[rr] = (_Float16)h2;
            }
        } else {
            // attention over previous run [S_prev, i) on wave 0, x from global xg
            if (wave == 0) {
                int L = i - S_prev;
                const float4* xb = (const float4*)(xgb + (size_t)S_prev * 16);
                float lmax = -1e30f;
                for (int tt = lane; tt < L; tt += 64) {
                    float4 q0 = xb[tt * 4 + 0], q1 = xb[tt * 4 + 1], q2 = xb[tt * 4 + 2];
                    float s = sc_s[0] + q0.x * v_s[0] + q0.y * v_s[1] + q0.z * v_s[2] +
                              q0.w * v_s[3] + q1.x * v_s[4] + q1.y * v_s[5] +
                              q1.z * v_s[6] + q1.w * v_s[7] + q2.x * v_s[8] + q2.y * v_s[9];
                    lmax = fmaxf(lmax, s);
                }
#pragma unroll
                for (int off = 32; off; off >>= 1)
                    lmax = fmaxf(lmax, __shfl_xor(lmax, off, 64));
                float lsum = 0.f, lacc[D_] = {};
                for (int tt = lane; tt < L; tt += 64) {
                    float4 q0 = xb[tt * 4 + 0], q1 = xb[tt * 4 + 1], q2 = xb[tt * 4 + 2];
                    float s = sc_s[0] + q0.x * v_s[0] + q0.y * v_s[1] + q0.z * v_s[2] +
                              q0.w * v_s[3] + q1.x * v_s[4] + q1.y * v_s[5] +
                              q1.z * v_s[6] + q1.w * v_s[7] + q2.x * v_s[8] + q2.y * v_s[9];
                    float w = expf(s - lmax);
                    lsum += w;
                    lacc[0] += w * q0.x; lacc[1] += w * q0.y; lacc[2] += w * q0.z;
                    lacc[3] += w * q0.w; lacc[4] += w * q1.x; lacc[5] += w * q1.y;
                    lacc[6] += w * q1.z; lacc[7] += w * q1.w; lacc[8] += w * q2.x;
                    lacc[9] += w * q2.y;
                }
#pragma unroll
                for (int off = 32; off; off >>= 1) {
                    lsum += __shfl_xor(lsum, off, 64);
#pragma unroll
                    for (int d = 0; d < D_; ++d) lacc[d] += __shfl_xor(lacc[d], off, 64);
                }
                if (lane == 0) {
                    if (L > 0) {
                        float inv = 1.0f / lsum;
#pragma unroll
                        for (int d = 0; d < D_; ++d) cur_res[d] = lacc[d] * inv;
                    } else {
#pragma unroll
                        for (int d = 0; d < D_; ++d) cur_res[d] = 0.f;
                    }
                }
            }
            __syncthreads();  // B_c2: cur_res visible
            {
                float gv = gt_s[t];
#pragma unroll
                for (int d = 0; d < D_; ++d) gv += wiht_r[1 + d] * cur_res[d];
                gt_s[t] = gv;
            }
            __syncthreads();  // B_c3: tempo gate vector ready
            if (wave == 0) {
                float p = 0.f;
#pragma unroll
                for (int hb = 0; hb < 2; ++hb) {
                    int rr = lane + (hb << 6);
                    float gi = gt_s[rr], gff = gt_s[128 + rr], gg = gt_s[256 + rr],
                          go = gt_s[384 + rr];
                    float c2 = sigm_(gff) * ct_s[rr] + sigm_(gi) * tanhf(gg);
                    float h2 = sigm_(go) * tanhf(c2);
                    ct_s[rr] = c2;
                    ht_s[rr] = h2;
                    p += h2 * wtfc_s[rr];
                }
#pragma unroll
                for (int off = 32; off; off >>= 1) p += __shfl_xor(p, off, 64);
                float tnew = p + sc_s[1];
                if (lane == 0) sc_s[2] = tnew;
#pragma unroll
                for (int hb = 0; hb < 2; ++hb) {
                    int rr = lane + (hb << 6);
                    float gi = g_s[rr] + wtail0_s[rr] * tnew;
                    float gff = g_s[128 + rr] + wtail0_s[128 + rr] * tnew;
                    float gg = g_s[256 + rr] + wtail0_s[256 + rr] * tnew;
                    float go = g_s[384 + rr] + wtail0_s[384 + rr] * tnew;
                    float c2 = sigm_(gff) * cf_s[rr] + sigm_(gi) * tanhf(gg);
                    float h2 = sigm_(go) * tanhf(c2);
                    cf_s[rr] = c2;
                    hf_s[rr] = h2;
                    h16_s[rr] = (_Float16)h2;
                }
            }
            // prefetch tpre row for next run
            if (cur_run + 1 < nruns_r)
                gt_pre = tpre[(size_t)(b * NBEATS_ + (int)run_cb_s[cur_run + 1]) * 512 + t];
        }
        __syncthreads();  // Bend
    }

    // epilogue: outputs for i = N_-1
    if (wave == 1) {
        int dd = lane >> 3, rl = lane & 7;
        int d2 = 8 + dd;
        float po1 = 0.f, po2 = 0.f;
        for (int k2 = 0; k2 < 16; ++k2) {
            int r = rl + (k2 << 3);
            float hv = hf_s[r];
            po1 += hv * wfcT[r][dd];
            if (d2 < D_) po2 += hv * wfcT[r][d2];
        }
        po1 += __shfl_xor(po1, 1); po1 += __shfl_xor(po1, 2); po1 += __shfl_xor(po1, 4);
        po2 += __shfl_xor(po2, 1); po2 += __shfl_xor(po2, 2); po2 += __shfl_xor(po2, 4);
        int pi = N_ - 1;
        int pd = (int)((padw_s[pi >> 6] >> (pi & 63)) & 1ULL);
        float* orow = out + (size_t)((b << 11) + pi) * OUT_;
        if (rl == 0) {
            orow[1 + dd] = pd ? 0.f : (po1 + bfc_s[dd]);
            if (d2 < D_) orow[1 + d2] = pd ? 0.f : (po2 + bfc_s[d2]);
        }
        if (lane == 1) orow[0] = pd ? 0.f : sc_s[2];
    }
}

// ---------------------------------------------------------------------------
extern "C" void kernel_launch(void* const* d_in, const int* in_sizes, int n_in,
                              void* d_out, int out_size, void* d_ws, size_t ws_size,
                              hipStream_t stream) {
    const float* note  = (const float*)d_in[0];
    const float* beat  = (const float*)d_in[1];
    const float* meas  = (const float*)d_in[2];
    const int*   bnum  = (const int*)d_in[3];
    const int*   mnum  = (const int*)d_in[4];
    const float* Wa    = (const float*)d_in[5];
    const float* ba    = (const float*)d_in[6];
    const float* ctx   = (const float*)d_in[7];
    const float* Wih_t = (const float*)d_in[8];
    const float* Whh_t = (const float*)d_in[9];
    const float* bih_t = (const float*)d_in[10];
    const float* bhh_t = (const float*)d_in[11];
    const float* Wih_f = (const float*)d_in[12];
    const float* Whh_f = (const float*)d_in[13];
    const float* bih_f = (const float*)d_in[14];
    const float* bhh_f = (const float*)d_in[15];
    const float* W_fc  = (const float*)d_in[16];
    const float* b_fc  = (const float*)d_in[17];
    const float* W_tfc = (const float*)d_in[18];
    const float* b_tfc = (const float*)d_in[19];
    float* out = (float*)d_out;

    char* ws = (char*)d_ws;
    float* finp = (float*)ws;                                   // 64 MB
    float* tpre = (float*)(ws + (size_t)64 * 1024 * 1024);      // 8 MB
    int*   padf = (int*)(ws + (size_t)72 * 1024 * 1024);        // 128 KB
    float* xg   = (float*)(ws + (size_t)73 * 1024 * 1024);      // 16*2048*16*4 = 2 MB

    pad_k<<<8192, 256, 0, stream>>>(note, padf);
    fold_whh<<<512, 128, 0, stream>>>(Whh_f, Wih_f, W_fc, b_fc);
    tempo_pre_k<<<dim3(16, 16), 256, 0, stream>>>(beat, meas, bnum, mnum, Wih_t,
                                                  bih_t, bhh_t, tpre);
    fin_pre_gemm<<<dim3(512, 8), 256, 0, stream>>>(note, beat, meas, bnum, mnum,
                                                   Wih_f, bih_f, bhh_f, finp);
    decode_seq<<<16, 512, 0, stream>>>(finp, tpre, bnum, padf, Whh_t, Wih_t,
                                       W_fc, b_fc, W_tfc, b_tfc, Wa, ba, ctx,
                                       out, xg);
}

// Round 11
// 5833.740 us; speedup vs baseline: 5.0346x; 1.1600x over previous
//
#include <hip/hip_runtime.h>
#include <cstdint>
#include <cstddef>

#define B_      16
#define N_      2048
#define NOTE_   512
#define BEAT_H_ 128
#define MEAS_H_ 64
#define NBEATS_ 256
#define NMEAS_  64
#define OUT_    11
#define D_      10
#define TSTRIDE 136   // fp16 Whh_t LDS row stride (halfs); r8-measured conflict-free
// fin = 715 (512 note + 128 beat + 64 meas + 11 prev_out)
// tin = 203 (128 beat + 64 meas + 1 tempo + 10 beat_results)

typedef float f32x4 __attribute__((ext_vector_type(4)));
typedef unsigned int u32x4 __attribute__((ext_vector_type(4)));
typedef _Float16 h2v __attribute__((ext_vector_type(2)));

__device__ __forceinline__ float sigm_(float x) { return 1.0f / (1.0f + expf(-x)); }

#define DOT4(va, vb) ((va).x * (vb).x + (va).y * (vb).y + (va).z * (vb).z + (va).w * (vb).w)

__device__ __forceinline__ float dot2f_(unsigned wu, unsigned hu, float c) {
    union { unsigned u; h2v h; } a, bb;
    a.u = wu; bb.u = hu;
#if __has_builtin(__builtin_amdgcn_fdot2)
    return __builtin_amdgcn_fdot2(a.h, bb.h, c, false);
#else
    return c + (float)a.h[0] * (float)bb.h[0] + (float)a.h[1] * (float)bb.h[1];
#endif
}

// Folded recurrent weights (fp32): Whh_eff = Whh_f + Wih_f[:,705:715] @ W_fc
// bias_eff = Wih_f[:,705:715] @ b_fc ; wtail0 = Wih_f[:,704]
__device__ float g_whh_eff[512 * 128];
__device__ float g_bias_eff[512];
__device__ float g_wtail0[512];
// Whh_t as fp16, padded stride (staged to LDS by decode_seq)
__device__ __align__(16) _Float16 g_wht_h16[512 * TSTRIDE];

// ---------------------------------------------------------------------------
__global__ __launch_bounds__(256) void pad_k(const float* __restrict__ note,
                                             int* __restrict__ padf) {
    int wave = threadIdx.x >> 6, lane = threadIdx.x & 63;
    int r = blockIdx.x * 4 + wave;
    const float* row = note + ((size_t)r << 9);
    float s = 0.f;
#pragma unroll
    for (int u = 0; u < 8; ++u) s += row[lane + (u << 6)];
#pragma unroll
    for (int off = 32; off; off >>= 1) s += __shfl_xor(s, off, 64);
    if (lane == 0) padf[r] = (s == 0.0f) ? 1 : 0;
}

// ---------------------------------------------------------------------------
__global__ __launch_bounds__(128) void fold_whh(
    const float* __restrict__ Whh_f, const float* __restrict__ Wih_f,
    const float* __restrict__ W_fc, const float* __restrict__ b_fc) {
    int gr = blockIdx.x;   // 512
    int t = threadIdx.x;   // 128
    __shared__ float tail[OUT_];
    if (t < OUT_) tail[t] = Wih_f[(size_t)gr * 715 + 704 + t];
    __syncthreads();
    float m = Whh_f[(size_t)gr * 128 + t];
#pragma unroll
    for (int d = 0; d < D_; ++d) m += tail[1 + d] * W_fc[d * 128 + t];
    g_whh_eff[(size_t)gr * 128 + t] = m;
    if (t == 0) {
        float bb = 0.f;
#pragma unroll
        for (int d = 0; d < D_; ++d) bb += tail[1 + d] * b_fc[d];
        g_bias_eff[gr] = bb;
        g_wtail0[gr] = tail[0];
    }
}

// ---------------------------------------------------------------------------
__global__ __launch_bounds__(128) void fold_wht(const float* __restrict__ Whh_t) {
    int gr = blockIdx.x, t = threadIdx.x;
    g_wht_h16[(size_t)gr * TSTRIDE + t] = (_Float16)Whh_t[(size_t)gr * 128 + t];
    if (t < TSTRIDE - 128) g_wht_h16[(size_t)gr * TSTRIDE + 128 + t] = (_Float16)0.f;
}

// ---------------------------------------------------------------------------
__global__ __launch_bounds__(256) void tempo_pre_k(
    const float* __restrict__ beat, const float* __restrict__ meas,
    const int* __restrict__ bnum, const int* __restrict__ mnum,
    const float* __restrict__ Wih_t, const float* __restrict__ bih_t,
    const float* __restrict__ bhh_t, float* __restrict__ tpre) {
    __shared__ float sin_[16][192];
    int b = blockIdx.x, qt = blockIdx.y;
    int t = threadIdx.x;
    int bn0 = bnum[b << 11], mn0 = mnum[b << 11];
    for (int idx = t; idx < 16 * 192; idx += 256) {
        int qq = idx / 192, kk = idx - qq * 192;
        int q = qt * 16 + qq;
        float v;
        if (kk < 128) {
            v = beat[(size_t)(b * NBEATS_ + q) * 128 + kk];
        } else {
            int cm = ((q + bn0) >> 2) - mn0;
            if (cm > 63) cm = 63;
            if (cm < 0) cm = 0;
            v = meas[(size_t)(b * NMEAS_ + cm) * 64 + (kk - 128)];
        }
        sin_[qq][kk] = v;
    }
    __syncthreads();
    for (int half = 0; half < 2; ++half) {
        int j = t + half * 256;
        const float* wr = Wih_t + (size_t)j * 203;
        float bias = bih_t[j] + bhh_t[j];
        float acc[16] = {};
        for (int k = 0; k < 192; ++k) {
            float w = wr[k];
#pragma unroll
            for (int qq = 0; qq < 16; ++qq) acc[qq] += w * sin_[qq][k];
        }
        for (int qq = 0; qq < 16; ++qq)
            tpre[(size_t)(b * NBEATS_ + qt * 16 + qq) * 512 + j] = acc[qq] + bias;
    }
}

// ---------------------------------------------------------------------------
__global__ __launch_bounds__(256) void fin_pre_gemm(
    const float* __restrict__ note, const float* __restrict__ beat,
    const float* __restrict__ meas, const int* __restrict__ bnum,
    const int* __restrict__ mnum, const float* __restrict__ Wih_f,
    const float* __restrict__ bih_f, const float* __restrict__ bhh_f,
    float* __restrict__ finp) {
    __shared__ float As[16][64];
    __shared__ float Bs[16][64];
    int t = threadIdx.x;
    int r0 = blockIdx.x * 64;
    int j0 = blockIdx.y * 64;

    int am = t >> 2, alane = t & 3;
    int r = r0 + am;
    int b = r >> 11;
    int rb = b << 11;
    int cb = bnum[r] - bnum[rb];
    int cm = mnum[r] - mnum[rb];
    const float* arow_note = note + ((size_t)r << 9);
    const float* arow_beat = beat + ((size_t)(b * NBEATS_ + cb) << 7);
    const float* arow_meas = meas + ((size_t)(b * NMEAS_ + cm) << 6);

    int jj = t >> 2, blane = t & 3;
    const float* brow = Wih_f + (size_t)(j0 + jj) * 715;

    int tm0 = (t & 15) * 4, tn0 = (t >> 4) * 4;
    float acc[4][4] = {};

    for (int k0 = 0; k0 < 704; k0 += 16) {
        int ka = k0 + alane * 4;
        float4 av;
        if (ka < 512)      av = *(const float4*)(arow_note + ka);
        else if (ka < 640) av = *(const float4*)(arow_beat + (ka - 512));
        else               av = *(const float4*)(arow_meas + (ka - 640));
        int kb = k0 + blane * 4;
        float b0 = brow[kb], b1 = brow[kb + 1], b2 = brow[kb + 2], b3 = brow[kb + 3];
        __syncthreads();
        As[alane * 4 + 0][am] = av.x;
        As[alane * 4 + 1][am] = av.y;
        As[alane * 4 + 2][am] = av.z;
        As[alane * 4 + 3][am] = av.w;
        Bs[blane * 4 + 0][jj] = b0;
        Bs[blane * 4 + 1][jj] = b1;
        Bs[blane * 4 + 2][jj] = b2;
        Bs[blane * 4 + 3][jj] = b3;
        __syncthreads();
#pragma unroll
        for (int kk = 0; kk < 16; ++kk) {
            float4 a4 = *(const float4*)&As[kk][tm0];
            float4 b4 = *(const float4*)&Bs[kk][tn0];
            float aa[4] = {a4.x, a4.y, a4.z, a4.w};
            float bb[4] = {b4.x, b4.y, b4.z, b4.w};
#pragma unroll
            for (int mi = 0; mi < 4; ++mi)
#pragma unroll
                for (int ni = 0; ni < 4; ++ni) acc[mi][ni] += aa[mi] * bb[ni];
        }
    }
    float bias[4];
#pragma unroll
    for (int ni = 0; ni < 4; ++ni) {
        int j = j0 + tn0 + ni;
        bias[ni] = bih_f[j] + bhh_f[j];
    }
#pragma unroll
    for (int mi = 0; mi < 4; ++mi) {
        int rr = r0 + tm0 + mi;
        float4 o;
        o.x = acc[mi][0] + bias[0];
        o.y = acc[mi][1] + bias[1];
        o.z = acc[mi][2] + bias[2];
        o.w = acc[mi][3] + bias[3];
        *(float4*)(finp + ((size_t)rr << 9) + j0 + tn0) = o;
    }
}

// ---------------------------------------------------------------------------
// sequential decoder: full fp32 folded weight row per thread in 32 named
// f32x4s, made UNREMATERIALIZABLE via empty asm touch (asm-defined values
// cannot be re-loaded from memory by the scheduler). Whh_t as fp16 in LDS
// (139 KB -> also forces 1 block/CU -> 256-VGPR budget).
// ---------------------------------------------------------------------------
__global__ __launch_bounds__(512)
__attribute__((amdgpu_waves_per_eu(2, 2)))
void decode_seq(
    const float* __restrict__ finp, const float* __restrict__ tpre,
    const int* __restrict__ bnum, const int* __restrict__ padf,
    const float* __restrict__ Wih_t,
    const float* __restrict__ W_fc, const float* __restrict__ b_fc,
    const float* __restrict__ W_tfc, const float* __restrict__ b_tfc,
    const float* __restrict__ Wa, const float* __restrict__ ba,
    const float* __restrict__ ctx, float* __restrict__ out,
    float* __restrict__ xg) {
    __shared__ __align__(16) _Float16 wht16_s[512 * TSTRIDE];  // 139264 B
    __shared__ __align__(16) _Float16 ht16_s[128];
    __shared__ __align__(16) float hf_s[128];
    __shared__ float cf_s[128];
    __shared__ float ht_s[128];
    __shared__ float ct_s[128];
    __shared__ __align__(16) float g_s[512];
    __shared__ float gt_s[512];
    __shared__ float wtail0_s[512];
    __shared__ float wfcT[128][12];       // W_fc transposed [r][d]
    __shared__ float wtfc_s[128];
    __shared__ float bfc_s[12];
    __shared__ float cur_res[12];
    __shared__ float v_s[12];
    __shared__ float sc_s[4];             // [0]=ba.ctx, [1]=b_tfc, [2]=tempo scalar
    __shared__ unsigned long long padw_s[32];
    __shared__ unsigned short run_start_s[300];
    __shared__ short run_cb_s[300];
    __shared__ int nruns_s;

    int t = threadIdx.x, lane = t & 63, wave = t >> 6;
    int b = blockIdx.x;

    // ---- full fp32 folded weight row in 32 named f32x4 (128 VGPR) ----
    f32x4 w0, w1, w2, w3, w4, w5, w6, w7, w8, w9, w10, w11, w12, w13, w14, w15;
    f32x4 u0, u1, u2, u3, u4, u5, u6, u7, u8, u9, u10, u11, u12, u13, u14, u15;
    {
        const f32x4* wfp = (const f32x4*)(g_whh_eff + (size_t)t * 128);
        w0 = wfp[0];   w1 = wfp[1];   w2 = wfp[2];   w3 = wfp[3];
        w4 = wfp[4];   w5 = wfp[5];   w6 = wfp[6];   w7 = wfp[7];
        w8 = wfp[8];   w9 = wfp[9];   w10 = wfp[10]; w11 = wfp[11];
        w12 = wfp[12]; w13 = wfp[13]; w14 = wfp[14]; w15 = wfp[15];
        u0 = wfp[16];  u1 = wfp[17];  u2 = wfp[18];  u3 = wfp[19];
        u4 = wfp[20];  u5 = wfp[21];  u6 = wfp[22];  u7 = wfp[23];
        u8 = wfp[24];  u9 = wfp[25];  u10 = wfp[26]; u11 = wfp[27];
        u12 = wfp[28]; u13 = wfp[29]; u14 = wfp[30]; u15 = wfp[31];
    }
    // asm touch: values become asm-defined => scheduler cannot rematerialize
    // them from memory; allocator must keep them (or visibly spill to scratch).
    asm volatile("" : "+v"(w0), "+v"(w1), "+v"(w2), "+v"(w3),
                      "+v"(w4), "+v"(w5), "+v"(w6), "+v"(w7));
    asm volatile("" : "+v"(w8), "+v"(w9), "+v"(w10), "+v"(w11),
                      "+v"(w12), "+v"(w13), "+v"(w14), "+v"(w15));
    asm volatile("" : "+v"(u0), "+v"(u1), "+v"(u2), "+v"(u3),
                      "+v"(u4), "+v"(u5), "+v"(u6), "+v"(u7));
    asm volatile("" : "+v"(u8), "+v"(u9), "+v"(u10), "+v"(u11),
                      "+v"(u12), "+v"(u13), "+v"(u14), "+v"(u15));

    float bias_r = g_bias_eff[t];
    float wtail0_r = g_wtail0[t];
    wtail0_s[t] = wtail0_r;
    float wiht_r[OUT_];
#pragma unroll
    for (int u = 0; u < OUT_; ++u) wiht_r[u] = Wih_t[(size_t)t * 203 + 192 + u];

    // stage Whh_t fp16 into LDS (8704 uint4, 17 per thread)
    {
        const uint4* src = (const uint4*)g_wht_h16;
        uint4* dst = (uint4*)wht16_s;
#pragma unroll
        for (int k = 0; k < 17; ++k) dst[t + 512 * k] = src[t + 512 * k];
    }
    for (int k = t; k < 128 * D_; k += 512) {
        int d = k >> 7, r = k & 127;
        wfcT[r][d] = W_fc[k];
    }
    if (t < 128) {
        wtfc_s[t] = W_tfc[t];
        hf_s[t] = 0.f; cf_s[t] = 0.f; ht_s[t] = 0.f; ct_s[t] = 0.f;
        ht16_s[t] = (_Float16)0.f;
    }
    if (t < D_) {
        bfc_s[t] = b_fc[t];
        cur_res[t] = 0.f;
        float vv = 0.f;
        for (int m = 0; m < D_; ++m) vv += ctx[m] * Wa[m * D_ + t];
        v_s[t] = vv;
    }
    if (t == 10) {
        float cc = 0.f;
        for (int m = 0; m < D_; ++m) cc += ba[m] * ctx[m];
        sc_s[0] = cc;
        sc_s[1] = b_tfc[0];
        sc_s[2] = 0.f;
    }
    // pad bitmask: waves 2..5 build 8 words each via ballot
    if (wave >= 2 && wave < 6) {
        for (int jj = 0; jj < 8; ++jj) {
            int j = (wave - 2) * 8 + jj;
            int pv = padf[(b << 11) + j * 64 + lane];
            unsigned long long m = __ballot(pv != 0);
            if (lane == 0) padw_s[j] = m;
        }
    }
    // run-compress beat numbers (prefix scan)
    const int* bnb = bnum + (b << 11);
    int bn0 = bnb[0];
    int base = t * 4;
    int bvm = (base == 0) ? 0 : bnb[base - 1];
    int bv0 = bnb[base], bv1 = bnb[base + 1], bv2 = bnb[base + 2], bv3 = bnb[base + 3];
    if (base == 0) bvm = bv0 - 1;  // force change at i=0
    int c = (bv0 != bvm) + (bv1 != bv0) + (bv2 != bv1) + (bv3 != bv2);
    ((int*)g_s)[t] = c;
    __syncthreads();
    if (wave == 0) {
        int c8[8], s = 0;
#pragma unroll
        for (int j = 0; j < 8; ++j) { c8[j] = ((int*)g_s)[lane * 8 + j]; s += c8[j]; }
        int incl = s;
#pragma unroll
        for (int off = 1; off < 64; off <<= 1) {
            int n = __shfl_up(incl, off, 64);
            if (lane >= off) incl += n;
        }
        int run = incl - s;
#pragma unroll
        for (int j = 0; j < 8; ++j) { ((int*)gt_s)[lane * 8 + j] = run; run += c8[j]; }
        if (lane == 63) nruns_s = incl;
    }
    __syncthreads();
    {
        int O = ((int*)gt_s)[t];
        if (bv0 != bvm) { run_start_s[O] = (unsigned short)(base + 0); run_cb_s[O] = (short)(bv0 - bn0); O++; }
        if (bv1 != bv0) { run_start_s[O] = (unsigned short)(base + 1); run_cb_s[O] = (short)(bv1 - bn0); O++; }
        if (bv2 != bv1) { run_start_s[O] = (unsigned short)(base + 2); run_cb_s[O] = (short)(bv2 - bn0); O++; }
        if (bv3 != bv2) { run_start_s[O] = (unsigned short)(base + 3); run_cb_s[O] = (short)(bv3 - bn0); O++; }
    }
    __syncthreads();
    int nruns_r = nruns_s;

    const float* finrow = finp + ((size_t)b << 11) * 512;
    float* xgb = xg + ((size_t)(b << 11)) * 16;
    float gf_cur = finrow[t];
    float gt_pre = tpre[(size_t)(b * NBEATS_) * 512 + t];  // run0 cb = 0
    int cur_run = -1, next_start = 0, run_s = 0, S_prev = 0;

    for (int i = 0; i < N_; ++i) {
        bool changed = (i == next_start);
        if (changed) {
            cur_run++;
            S_prev = run_s;
            run_s = i;
            next_start = (cur_run + 1 < nruns_r) ? (int)run_start_s[cur_run + 1] : 4096;
        }
        float gf_pre = finrow[(size_t)(i + 1) * 512 + t];
        float prev0 = sc_s[2];

        // ---- main matvec: resident fp32 weights x h (LDS uniform broadcast) ----
        float acc;
        {
            const f32x4* hp = (const f32x4*)hf_s;
            float a0 = DOT4(w0, hp[0]) + DOT4(w1, hp[1]) + DOT4(w2, hp[2]) + DOT4(w3, hp[3]);
            float a1 = DOT4(w4, hp[4]) + DOT4(w5, hp[5]) + DOT4(w6, hp[6]) + DOT4(w7, hp[7]);
            float a2 = DOT4(w8, hp[8]) + DOT4(w9, hp[9]) + DOT4(w10, hp[10]) + DOT4(w11, hp[11]);
            float a3 = DOT4(w12, hp[12]) + DOT4(w13, hp[13]) + DOT4(w14, hp[14]) + DOT4(w15, hp[15]);
            float a4 = DOT4(u0, hp[16]) + DOT4(u1, hp[17]) + DOT4(u2, hp[18]) + DOT4(u3, hp[19]);
            float a5 = DOT4(u4, hp[20]) + DOT4(u5, hp[21]) + DOT4(u6, hp[22]) + DOT4(u7, hp[23]);
            float a6 = DOT4(u8, hp[24]) + DOT4(u9, hp[25]) + DOT4(u10, hp[26]) + DOT4(u11, hp[27]);
            float a7 = DOT4(u12, hp[28]) + DOT4(u13, hp[29]) + DOT4(u14, hp[30]) + DOT4(u15, hp[31]);
            acc = ((a0 + a1) + (a2 + a3)) + ((a4 + a5) + (a6 + a7));
        }
        {
            float g = gf_cur + acc;
            if (i > 0) g += bias_r;               // folded out-feedback bias
            if (!changed) g += wtail0_r * prev0;  // tempo term (changed: added post-update)
            g_s[t] = g;
        }
        gf_cur = gf_pre;

        // wave1: finalize step i-1 outputs (hf_s still = h(i-1))
        if (wave == 1 && i > 0) {
            int dd = lane >> 3, rl = lane & 7;
            int d2i = 8 + dd;
            float po1 = 0.f, po2 = 0.f;
            for (int k2 = 0; k2 < 16; ++k2) {
                int r = rl + (k2 << 3);
                float hv = hf_s[r];
                po1 += hv * wfcT[r][dd];
                if (d2i < D_) po2 += hv * wfcT[r][d2i];
            }
            po1 += __shfl_xor(po1, 1); po1 += __shfl_xor(po1, 2); po1 += __shfl_xor(po1, 4);
            po2 += __shfl_xor(po2, 1); po2 += __shfl_xor(po2, 2); po2 += __shfl_xor(po2, 4);
            int pi = i - 1;
            int pd = (int)((padw_s[pi >> 6] >> (pi & 63)) & 1ULL);
            float* orow = out + (size_t)((b << 11) + pi) * OUT_;
            float* xrow = xgb + (size_t)pi * 16;
            if (rl == 0) {
                float od = po1 + bfc_s[dd];
                xrow[dd] = od;
                orow[1 + dd] = pd ? 0.f : od;
                if (d2i < D_) {
                    float od2 = po2 + bfc_s[d2i];
                    xrow[d2i] = od2;
                    orow[1 + d2i] = pd ? 0.f : od2;
                }
            }
            if (lane == 1) orow[0] = pd ? 0.f : prev0;
        }

        if (changed) {
            // tempo gate partial from LDS fp16 Whh_t: tpre + Whh_t.ht + wiht0*prev0
            float acct;
            {
                const u32x4* wq = (const u32x4*)(wht16_s + (size_t)t * TSTRIDE);
                const u32x4* hq = (const u32x4*)ht16_s;
                float a0 = 0.f, a1 = 0.f, a2 = 0.f, a3 = 0.f;
#pragma unroll
                for (int k = 0; k < 16; ++k) {
                    u32x4 W = wq[k];
                    u32x4 H = hq[k];
                    a0 = dot2f_(W.x, H.x, a0);
                    a1 = dot2f_(W.y, H.y, a1);
                    a2 = dot2f_(W.z, H.z, a2);
                    a3 = dot2f_(W.w, H.w, a3);
                }
                acct = (a0 + a1) + (a2 + a3);
            }
            gt_s[t] = gt_pre + acct + wiht_r[0] * prev0;
        }
        __syncthreads();  // B1

        if (!changed) {
            if (wave < 2) {
                int rr = lane + (wave << 6);
                float gi = g_s[rr], gff = g_s[128 + rr], gg = g_s[256 + rr], go = g_s[384 + rr];
                float c2 = sigm_(gff) * cf_s[rr] + sigm_(gi) * tanhf(gg);
                float h2 = sigm_(go) * tanhf(c2);
                cf_s[rr] = c2;
                hf_s[rr] = h2;
            }
        } else {
            // attention over previous run [S_prev, i) on wave 0, x from global xg
            if (wave == 0) {
                int L = i - S_prev;
                const float4* xb = (const float4*)(xgb + (size_t)S_prev * 16);
                float lmax = -1e30f;
                for (int tt = lane; tt < L; tt += 64) {
                    float4 q0 = xb[tt * 4 + 0], q1 = xb[tt * 4 + 1], q2 = xb[tt * 4 + 2];
                    float s = sc_s[0] + q0.x * v_s[0] + q0.y * v_s[1] + q0.z * v_s[2] +
                              q0.w * v_s[3] + q1.x * v_s[4] + q1.y * v_s[5] +
                              q1.z * v_s[6] + q1.w * v_s[7] + q2.x * v_s[8] + q2.y * v_s[9];
                    lmax = fmaxf(lmax, s);
                }
#pragma unroll
                for (int off = 32; off; off >>= 1)
                    lmax = fmaxf(lmax, __shfl_xor(lmax, off, 64));
                float lsum = 0.f, lacc[D_] = {};
                for (int tt = lane; tt < L; tt += 64) {
                    float4 q0 = xb[tt * 4 + 0], q1 = xb[tt * 4 + 1], q2 = xb[tt * 4 + 2];
                    float s = sc_s[0] + q0.x * v_s[0] + q0.y * v_s[1] + q0.z * v_s[2] +
                              q0.w * v_s[3] + q1.x * v_s[4] + q1.y * v_s[5] +
                              q1.z * v_s[6] + q1.w * v_s[7] + q2.x * v_s[8] + q2.y * v_s[9];
                    float w = expf(s - lmax);
                    lsum += w;
                    lacc[0] += w * q0.x; lacc[1] += w * q0.y; lacc[2] += w * q0.z;
                    lacc[3] += w * q0.w; lacc[4] += w * q1.x; lacc[5] += w * q1.y;
                    lacc[6] += w * q1.z; lacc[7] += w * q1.w; lacc[8] += w * q2.x;
                    lacc[9] += w * q2.y;
                }
#pragma unroll
                for (int off = 32; off; off >>= 1) {
                    lsum += __shfl_xor(lsum, off, 64);
#pragma unroll
                    for (int d = 0; d < D_; ++d) lacc[d] += __shfl_xor(lacc[d], off, 64);
                }
                if (lane == 0) {
                    if (L > 0) {
                        float inv = 1.0f / lsum;
#pragma unroll
                        for (int d = 0; d < D_; ++d) cur_res[d] = lacc[d] * inv;
                    } else {
#pragma unroll
                        for (int d = 0; d < D_; ++d) cur_res[d] = 0.f;
                    }
                }
            }
            __syncthreads();  // B_c2: cur_res visible
            {
                float gv = gt_s[t];
#pragma unroll
                for (int d = 0; d < D_; ++d) gv += wiht_r[1 + d] * cur_res[d];
                gt_s[t] = gv;
            }
            __syncthreads();  // B_c3: tempo gate vector ready
            if (wave == 0) {
                float p = 0.f;
#pragma unroll
                for (int hb = 0; hb < 2; ++hb) {
                    int rr = lane + (hb << 6);
                    float gi = gt_s[rr], gff = gt_s[128 + rr], gg = gt_s[256 + rr],
                          go = gt_s[384 + rr];
                    float c2 = sigm_(gff) * ct_s[rr] + sigm_(gi) * tanhf(gg);
                    float h2 = sigm_(go) * tanhf(c2);
                    ct_s[rr] = c2;
                    ht_s[rr] = h2;
                    ht16_s[rr] = (_Float16)h2;
                    p += h2 * wtfc_s[rr];
                }
#pragma unroll
                for (int off = 32; off; off >>= 1) p += __shfl_xor(p, off, 64);
                float tnew = p + sc_s[1];
                if (lane == 0) sc_s[2] = tnew;
#pragma unroll
                for (int hb = 0; hb < 2; ++hb) {
                    int rr = lane + (hb << 6);
                    float gi = g_s[rr] + wtail0_s[rr] * tnew;
                    float gff = g_s[128 + rr] + wtail0_s[128 + rr] * tnew;
                    float gg = g_s[256 + rr] + wtail0_s[256 + rr] * tnew;
                    float go = g_s[384 + rr] + wtail0_s[384 + rr] * tnew;
                    float c2 = sigm_(gff) * cf_s[rr] + sigm_(gi) * tanhf(gg);
                    float h2 = sigm_(go) * tanhf(c2);
                    cf_s[rr] = c2;
                    hf_s[rr] = h2;
                }
            }
            // prefetch tpre row for next run
            if (cur_run + 1 < nruns_r)
                gt_pre = tpre[(size_t)(b * NBEATS_ + (int)run_cb_s[cur_run + 1]) * 512 + t];
        }
        __syncthreads();  // Bend
    }

    // epilogue: outputs for i = N_-1
    if (wave == 1) {
        int dd = lane >> 3, rl = lane & 7;
        int d2i = 8 + dd;
        float po1 = 0.f, po2 = 0.f;
        for (int k2 = 0; k2 < 16; ++k2) {
            int r = rl + (k2 << 3);
            float hv = hf_s[r];
            po1 += hv * wfcT[r][dd];
            if (d2i < D_) po2 += hv * wfcT[r][d2i];
        }
        po1 += __shfl_xor(po1, 1); po1 += __shfl_xor(po1, 2); po1 += __shfl_xor(po1, 4);
        po2 += __shfl_xor(po2, 1); po2 += __shfl_xor(po2, 2); po2 += __shfl_xor(po2, 4);
        int pi = N_ - 1;
        int pd = (int)((padw_s[pi >> 6] >> (pi & 63)) & 1ULL);
        float* orow = out + (size_t)((b << 11) + pi) * OUT_;
        if (rl == 0) {
            orow[1 + dd] = pd ? 0.f : (po1 + bfc_s[dd]);
            if (d2i < D_) orow[1 + d2i] = pd ? 0.f : (po2 + bfc_s[d2i]);
        }
        if (lane == 1) orow[0] = pd ? 0.f : sc_s[2];
    }
}

// ---------------------------------------------------------------------------
extern "C" void kernel_launch(void* const* d_in, const int* in_sizes, int n_in,
                              void* d_out, int out_size, void* d_ws, size_t ws_size,
                              hipStream_t stream) {
    const float* note  = (const float*)d_in[0];
    const float* beat  = (const float*)d_in[1];
    const float* meas  = (const float*)d_in[2];
    const int*   bnum  = (const int*)d_in[3];
    const int*   mnum  = (const int*)d_in[4];
    const float* Wa    = (const float*)d_in[5];
    const float* ba    = (const float*)d_in[6];
    const float* ctx   = (const float*)d_in[7];
    const float* Wih_t = (const float*)d_in[8];
    const float* Whh_t = (const float*)d_in[9];
    const float* bih_t = (const float*)d_in[10];
    const float* bhh_t = (const float*)d_in[11];
    const float* Wih_f = (const float*)d_in[12];
    const float* Whh_f = (const float*)d_in[13];
    const float* bih_f = (const float*)d_in[14];
    const float* bhh_f = (const float*)d_in[15];
    const float* W_fc  = (const float*)d_in[16];
    const float* b_fc  = (const float*)d_in[17];
    const float* W_tfc = (const float*)d_in[18];
    const float* b_tfc = (const float*)d_in[19];
    float* out = (float*)d_out;

    char* ws = (char*)d_ws;
    float* finp = (float*)ws;                                   // 64 MB
    float* tpre = (float*)(ws + (size_t)64 * 1024 * 1024);      // 8 MB
    int*   padf = (int*)(ws + (size_t)72 * 1024 * 1024);        // 128 KB
    float* xg   = (float*)(ws + (size_t)73 * 1024 * 1024);      // 2 MB

    pad_k<<<8192, 256, 0, stream>>>(note, padf);
    fold_whh<<<512, 128, 0, stream>>>(Whh_f, Wih_f, W_fc, b_fc);
    fold_wht<<<512, 128, 0, stream>>>(Whh_t);
    tempo_pre_k<<<dim3(16, 16), 256, 0, stream>>>(beat, meas, bnum, mnum, Wih_t,
                                                  bih_t, bhh_t, tpre);
    fin_pre_gemm<<<dim3(512, 8), 256, 0, stream>>>(note, beat, meas, bnum, mnum,
                                                   Wih_f, bih_f, bhh_f, finp);
    decode_seq<<<16, 512, 0, stream>>>(finp, tpre, bnum, padf, Wih_t,
                                       W_fc, b_fc, W_tfc, b_tfc, Wa, ba, ctx,
                                       out, xg);
}

// Round 12
// 4208.128 us; speedup vs baseline: 6.9795x; 1.3863x over previous
//
#include <hip/hip_runtime.h>
#include <cstdint>
#include <cstddef>

#define B_      16
#define N_      2048
#define NOTE_   512
#define BEAT_H_ 128
#define MEAS_H_ 64
#define NBEATS_ 256
#define NMEAS_  64
#define OUT_    11
#define D_      10
#define TSTRIDE 136   // fp16 Whh_t LDS row stride (halfs); r8-measured conflict-free
// fin = 715 (512 note + 128 beat + 64 meas + 11 prev_out)
// tin = 203 (128 beat + 64 meas + 1 tempo + 10 beat_results)

typedef float f32x4 __attribute__((ext_vector_type(4)));
typedef unsigned int u32x4 __attribute__((ext_vector_type(4)));
typedef _Float16 h2v __attribute__((ext_vector_type(2)));

__device__ __forceinline__ float fexp2_(float x) {
#if __has_builtin(__builtin_amdgcn_exp2f)
    return __builtin_amdgcn_exp2f(x);
#else
    return exp2f(x);
#endif
}
__device__ __forceinline__ float frcp_(float x) {
#if __has_builtin(__builtin_amdgcn_rcpf)
    return __builtin_amdgcn_rcpf(x);
#else
    return 1.0f / x;
#endif
}
// fast sigmoid / tanh via v_exp_f32 (2^x) + v_rcp_f32; saturate correctly at +-inf
__device__ __forceinline__ float sigm_(float x) {
    return frcp_(1.0f + fexp2_(-1.4426950408889634f * x));
}
__device__ __forceinline__ float tanh_(float x) {
    return 1.0f - 2.0f * frcp_(fexp2_(2.8853900817779268f * x) + 1.0f);
}

#define DOT4(va, vb) ((va).x * (vb).x + (va).y * (vb).y + (va).z * (vb).z + (va).w * (vb).w)

__device__ __forceinline__ float dot2f_(unsigned wu, unsigned hu, float c) {
    union { unsigned u; h2v h; } a, bb;
    a.u = wu; bb.u = hu;
#if __has_builtin(__builtin_amdgcn_fdot2)
    return __builtin_amdgcn_fdot2(a.h, bb.h, c, false);
#else
    return c + (float)a.h[0] * (float)bb.h[0] + (float)a.h[1] * (float)bb.h[1];
#endif
}

// Folded recurrent weights (fp16, row stride 128): Whh_eff = Whh_f + Wih_f[:,705:715] @ W_fc
// bias_eff = Wih_f[:,705:715] @ b_fc (pre-added into finp rows i>0) ; wtail0 = Wih_f[:,704]
__device__ __align__(16) _Float16 g_whh_h16[512 * 128];
__device__ float g_bias_eff[512];
__device__ float g_wtail0[512];
// Whh_t as fp16, padded stride (staged to LDS by decode_seq)
__device__ __align__(16) _Float16 g_wht_h16[512 * TSTRIDE];

// ---------------------------------------------------------------------------
__global__ __launch_bounds__(256) void pad_k(const float* __restrict__ note,
                                             int* __restrict__ padf) {
    int wave = threadIdx.x >> 6, lane = threadIdx.x & 63;
    int r = blockIdx.x * 4 + wave;
    const float* row = note + ((size_t)r << 9);
    float s = 0.f;
#pragma unroll
    for (int u = 0; u < 8; ++u) s += row[lane + (u << 6)];
#pragma unroll
    for (int off = 32; off; off >>= 1) s += __shfl_xor(s, off, 64);
    if (lane == 0) padf[r] = (s == 0.0f) ? 1 : 0;
}

// ---------------------------------------------------------------------------
__global__ __launch_bounds__(128) void fold_whh(
    const float* __restrict__ Whh_f, const float* __restrict__ Wih_f,
    const float* __restrict__ W_fc, const float* __restrict__ b_fc) {
    int gr = blockIdx.x;   // 512
    int t = threadIdx.x;   // 128
    __shared__ float tail[OUT_];
    if (t < OUT_) tail[t] = Wih_f[(size_t)gr * 715 + 704 + t];
    __syncthreads();
    float m = Whh_f[(size_t)gr * 128 + t];
#pragma unroll
    for (int d = 0; d < D_; ++d) m += tail[1 + d] * W_fc[d * 128 + t];
    g_whh_h16[(size_t)gr * 128 + t] = (_Float16)m;
    if (t == 0) {
        float bb = 0.f;
#pragma unroll
        for (int d = 0; d < D_; ++d) bb += tail[1 + d] * b_fc[d];
        g_bias_eff[gr] = bb;
        g_wtail0[gr] = tail[0];
    }
}

// ---------------------------------------------------------------------------
__global__ __launch_bounds__(128) void fold_wht(const float* __restrict__ Whh_t) {
    int gr = blockIdx.x, t = threadIdx.x;
    g_wht_h16[(size_t)gr * TSTRIDE + t] = (_Float16)Whh_t[(size_t)gr * 128 + t];
    if (t < TSTRIDE - 128) g_wht_h16[(size_t)gr * TSTRIDE + 128 + t] = (_Float16)0.f;
}

// ---------------------------------------------------------------------------
__global__ __launch_bounds__(256) void tempo_pre_k(
    const float* __restrict__ beat, const float* __restrict__ meas,
    const int* __restrict__ bnum, const int* __restrict__ mnum,
    const float* __restrict__ Wih_t, const float* __restrict__ bih_t,
    const float* __restrict__ bhh_t, float* __restrict__ tpre) {
    __shared__ float sin_[16][192];
    int b = blockIdx.x, qt = blockIdx.y;
    int t = threadIdx.x;
    int bn0 = bnum[b << 11], mn0 = mnum[b << 11];
    for (int idx = t; idx < 16 * 192; idx += 256) {
        int qq = idx / 192, kk = idx - qq * 192;
        int q = qt * 16 + qq;
        float v;
        if (kk < 128) {
            v = beat[(size_t)(b * NBEATS_ + q) * 128 + kk];
        } else {
            int cm = ((q + bn0) >> 2) - mn0;
            if (cm > 63) cm = 63;
            if (cm < 0) cm = 0;
            v = meas[(size_t)(b * NMEAS_ + cm) * 64 + (kk - 128)];
        }
        sin_[qq][kk] = v;
    }
    __syncthreads();
    for (int half = 0; half < 2; ++half) {
        int j = t + half * 256;
        const float* wr = Wih_t + (size_t)j * 203;
        float bias = bih_t[j] + bhh_t[j];
        float acc[16] = {};
        for (int k = 0; k < 192; ++k) {
            float w = wr[k];
#pragma unroll
            for (int qq = 0; qq < 16; ++qq) acc[qq] += w * sin_[qq][k];
        }
        for (int qq = 0; qq < 16; ++qq)
            tpre[(size_t)(b * NBEATS_ + qt * 16 + qq) * 512 + j] = acc[qq] + bias;
    }
}

// ---------------------------------------------------------------------------
// fin_pre: adds bih+bhh always, and bias_eff (fold bias) for rows i>0.
// ---------------------------------------------------------------------------
__global__ __launch_bounds__(256) void fin_pre_gemm(
    const float* __restrict__ note, const float* __restrict__ beat,
    const float* __restrict__ meas, const int* __restrict__ bnum,
    const int* __restrict__ mnum, const float* __restrict__ Wih_f,
    const float* __restrict__ bih_f, const float* __restrict__ bhh_f,
    float* __restrict__ finp) {
    __shared__ float As[16][64];
    __shared__ float Bs[16][64];
    int t = threadIdx.x;
    int r0 = blockIdx.x * 64;
    int j0 = blockIdx.y * 64;

    int am = t >> 2, alane = t & 3;
    int r = r0 + am;
    int b = r >> 11;
    int rb = b << 11;
    int cb = bnum[r] - bnum[rb];
    int cm = mnum[r] - mnum[rb];
    const float* arow_note = note + ((size_t)r << 9);
    const float* arow_beat = beat + ((size_t)(b * NBEATS_ + cb) << 7);
    const float* arow_meas = meas + ((size_t)(b * NMEAS_ + cm) << 6);

    int jj = t >> 2, blane = t & 3;
    const float* brow = Wih_f + (size_t)(j0 + jj) * 715;

    int tm0 = (t & 15) * 4, tn0 = (t >> 4) * 4;
    float acc[4][4] = {};

    for (int k0 = 0; k0 < 704; k0 += 16) {
        int ka = k0 + alane * 4;
        float4 av;
        if (ka < 512)      av = *(const float4*)(arow_note + ka);
        else if (ka < 640) av = *(const float4*)(arow_beat + (ka - 512));
        else               av = *(const float4*)(arow_meas + (ka - 640));
        int kb = k0 + blane * 4;
        float b0 = brow[kb], b1 = brow[kb + 1], b2 = brow[kb + 2], b3 = brow[kb + 3];
        __syncthreads();
        As[alane * 4 + 0][am] = av.x;
        As[alane * 4 + 1][am] = av.y;
        As[alane * 4 + 2][am] = av.z;
        As[alane * 4 + 3][am] = av.w;
        Bs[blane * 4 + 0][jj] = b0;
        Bs[blane * 4 + 1][jj] = b1;
        Bs[blane * 4 + 2][jj] = b2;
        Bs[blane * 4 + 3][jj] = b3;
        __syncthreads();
#pragma unroll
        for (int kk = 0; kk < 16; ++kk) {
            float4 a4 = *(const float4*)&As[kk][tm0];
            float4 b4 = *(const float4*)&Bs[kk][tn0];
            float aa[4] = {a4.x, a4.y, a4.z, a4.w};
            float bb[4] = {b4.x, b4.y, b4.z, b4.w};
#pragma unroll
            for (int mi = 0; mi < 4; ++mi)
#pragma unroll
                for (int ni = 0; ni < 4; ++ni) acc[mi][ni] += aa[mi] * bb[ni];
        }
    }
    float bias[4], beff[4];
#pragma unroll
    for (int ni = 0; ni < 4; ++ni) {
        int j = j0 + tn0 + ni;
        bias[ni] = bih_f[j] + bhh_f[j];
        beff[ni] = g_bias_eff[j];
    }
#pragma unroll
    for (int mi = 0; mi < 4; ++mi) {
        int rr = r0 + tm0 + mi;
        float eb = (rr & 2047) ? 1.0f : 0.0f;   // fold-bias only for i>0
        float4 o;
        o.x = acc[mi][0] + bias[0] + eb * beff[0];
        o.y = acc[mi][1] + bias[1] + eb * beff[1];
        o.z = acc[mi][2] + bias[2] + eb * beff[2];
        o.w = acc[mi][3] + bias[3] + eb * beff[3];
        *(float4*)(finp + ((size_t)rr << 9) + j0 + tn0) = o;
    }
}

// ---------------------------------------------------------------------------
// sequential decoder: folded Whh as fp16 in 16 named u32x4 registers (64 VGPR,
// asm-touched => unrematerializable, fits arch-VGPRs => no AGPR copy staging).
// Matvec = 64 v_dot2_f32_f16 against hf16 LDS broadcast. Whh_t fp16 in LDS.
// ---------------------------------------------------------------------------
__global__ __launch_bounds__(512)
__attribute__((amdgpu_waves_per_eu(2, 2)))
void decode_seq(
    const float* __restrict__ finp, const float* __restrict__ tpre,
    const int* __restrict__ bnum, const int* __restrict__ padf,
    const float* __restrict__ Wih_t,
    const float* __restrict__ W_fc, const float* __restrict__ b_fc,
    const float* __restrict__ W_tfc, const float* __restrict__ b_tfc,
    const float* __restrict__ Wa, const float* __restrict__ ba,
    const float* __restrict__ ctx, float* __restrict__ out,
    float* __restrict__ xg) {
    __shared__ __align__(16) _Float16 wht16_s[512 * TSTRIDE];  // 139264 B
    __shared__ __align__(16) _Float16 ht16_s[128];
    __shared__ __align__(16) _Float16 hf16_s[128];
    __shared__ __align__(16) float hf_s[128];
    __shared__ float cf_s[128];
    __shared__ float ht_s[128];
    __shared__ float ct_s[128];
    __shared__ __align__(16) float g_s[512];
    __shared__ float gt_s[512];
    __shared__ float wtail0_s[512];
    __shared__ float wfcT[128][12];       // W_fc transposed [r][d]
    __shared__ float wtfc_s[128];
    __shared__ float bfc_s[12];
    __shared__ float cur_res[12];
    __shared__ float v_s[12];
    __shared__ float sc_s[4];             // [0]=ba.ctx, [1]=b_tfc, [2]=tempo scalar
    __shared__ unsigned long long padw_s[32];
    __shared__ unsigned short run_start_s[300];
    __shared__ short run_cb_s[300];
    __shared__ int nruns_s;

    int t = threadIdx.x, lane = t & 63, wave = t >> 6;
    int b = blockIdx.x;

    // ---- folded fp16 weight row in 16 named u32x4 (64 VGPR) ----
    u32x4 wf0, wf1, wf2, wf3, wf4, wf5, wf6, wf7;
    u32x4 wf8, wf9, wf10, wf11, wf12, wf13, wf14, wf15;
    {
        const u32x4* wfp = (const u32x4*)(g_whh_h16 + (size_t)t * 128);
        wf0 = wfp[0];   wf1 = wfp[1];   wf2 = wfp[2];   wf3 = wfp[3];
        wf4 = wfp[4];   wf5 = wfp[5];   wf6 = wfp[6];   wf7 = wfp[7];
        wf8 = wfp[8];   wf9 = wfp[9];   wf10 = wfp[10]; wf11 = wfp[11];
        wf12 = wfp[12]; wf13 = wfp[13]; wf14 = wfp[14]; wf15 = wfp[15];
    }
    // asm touch: asm-defined values cannot be rematerialized from memory.
    asm volatile("" : "+v"(wf0), "+v"(wf1), "+v"(wf2), "+v"(wf3),
                      "+v"(wf4), "+v"(wf5), "+v"(wf6), "+v"(wf7));
    asm volatile("" : "+v"(wf8), "+v"(wf9), "+v"(wf10), "+v"(wf11),
                      "+v"(wf12), "+v"(wf13), "+v"(wf14), "+v"(wf15));

    float wtail0_r = g_wtail0[t];
    wtail0_s[t] = wtail0_r;
    float wiht_r[OUT_];
#pragma unroll
    for (int u = 0; u < OUT_; ++u) wiht_r[u] = Wih_t[(size_t)t * 203 + 192 + u];

    // stage Whh_t fp16 into LDS (8704 uint4, 17 per thread)
    {
        const uint4* src = (const uint4*)g_wht_h16;
        uint4* dst = (uint4*)wht16_s;
#pragma unroll
        for (int k = 0; k < 17; ++k) dst[t + 512 * k] = src[t + 512 * k];
    }
    for (int k = t; k < 128 * D_; k += 512) {
        int d = k >> 7, r = k & 127;
        wfcT[r][d] = W_fc[k];
    }
    if (t < 128) {
        wtfc_s[t] = W_tfc[t];
        hf_s[t] = 0.f; cf_s[t] = 0.f; ht_s[t] = 0.f; ct_s[t] = 0.f;
        ht16_s[t] = (_Float16)0.f;
        hf16_s[t] = (_Float16)0.f;
    }
    if (t < D_) {
        bfc_s[t] = b_fc[t];
        cur_res[t] = 0.f;
        float vv = 0.f;
        for (int m = 0; m < D_; ++m) vv += ctx[m] * Wa[m * D_ + t];
        v_s[t] = vv;
    }
    if (t == 10) {
        float cc = 0.f;
        for (int m = 0; m < D_; ++m) cc += ba[m] * ctx[m];
        sc_s[0] = cc;
        sc_s[1] = b_tfc[0];
        sc_s[2] = 0.f;
    }
    // pad bitmask: waves 2..5 build 8 words each via ballot
    if (wave >= 2 && wave < 6) {
        for (int jj = 0; jj < 8; ++jj) {
            int j = (wave - 2) * 8 + jj;
            int pv = padf[(b << 11) + j * 64 + lane];
            unsigned long long m = __ballot(pv != 0);
            if (lane == 0) padw_s[j] = m;
        }
    }
    // run-compress beat numbers (prefix scan)
    const int* bnb = bnum + (b << 11);
    int bn0 = bnb[0];
    int base = t * 4;
    int bvm = (base == 0) ? 0 : bnb[base - 1];
    int bv0 = bnb[base], bv1 = bnb[base + 1], bv2 = bnb[base + 2], bv3 = bnb[base + 3];
    if (base == 0) bvm = bv0 - 1;  // force change at i=0
    int c = (bv0 != bvm) + (bv1 != bv0) + (bv2 != bv1) + (bv3 != bv2);
    ((int*)g_s)[t] = c;
    __syncthreads();
    if (wave == 0) {
        int c8[8], s = 0;
#pragma unroll
        for (int j = 0; j < 8; ++j) { c8[j] = ((int*)g_s)[lane * 8 + j]; s += c8[j]; }
        int incl = s;
#pragma unroll
        for (int off = 1; off < 64; off <<= 1) {
            int n = __shfl_up(incl, off, 64);
            if (lane >= off) incl += n;
        }
        int run = incl - s;
#pragma unroll
        for (int j = 0; j < 8; ++j) { ((int*)gt_s)[lane * 8 + j] = run; run += c8[j]; }
        if (lane == 63) nruns_s = incl;
    }
    __syncthreads();
    {
        int O = ((int*)gt_s)[t];
        if (bv0 != bvm) { run_start_s[O] = (unsigned short)(base + 0); run_cb_s[O] = (short)(bv0 - bn0); O++; }
        if (bv1 != bv0) { run_start_s[O] = (unsigned short)(base + 1); run_cb_s[O] = (short)(bv1 - bn0); O++; }
        if (bv2 != bv1) { run_start_s[O] = (unsigned short)(base + 2); run_cb_s[O] = (short)(bv2 - bn0); O++; }
        if (bv3 != bv2) { run_start_s[O] = (unsigned short)(base + 3); run_cb_s[O] = (short)(bv3 - bn0); O++; }
    }
    __syncthreads();
    int nruns_r = nruns_s;

    const float* finrow = finp + ((size_t)b << 11) * 512;
    float* xgb = xg + ((size_t)(b << 11)) * 16;
    float gf_cur = finrow[t];
    float gt_pre = tpre[(size_t)(b * NBEATS_) * 512 + t];  // run0 cb = 0
    int cur_run = -1, next_start = 0, run_s = 0, S_prev = 0;

    for (int i = 0; i < N_; ++i) {
        bool changed = (i == next_start);
        if (changed) {
            cur_run++;
            S_prev = run_s;
            run_s = i;
            next_start = (cur_run + 1 < nruns_r) ? (int)run_start_s[cur_run + 1] : 4096;
        }
        float gf_pre = finrow[(size_t)(i + 1) * 512 + t];
        float prev0 = sc_s[2];

        // ---- main matvec: fp16 reg weights x fp16 h (LDS broadcast), fp32 acc ----
        float acc;
        {
            const u32x4* hq = (const u32x4*)hf16_s;
            float a0 = 0.f, a1 = 0.f, a2 = 0.f, a3 = 0.f;
#define MSTEP(W, K)                                            \
            { u32x4 H = hq[K];                                 \
              a0 = dot2f_(W.x, H.x, a0);                       \
              a1 = dot2f_(W.y, H.y, a1);                       \
              a2 = dot2f_(W.z, H.z, a2);                       \
              a3 = dot2f_(W.w, H.w, a3); }
            MSTEP(wf0, 0)   MSTEP(wf1, 1)   MSTEP(wf2, 2)   MSTEP(wf3, 3)
            MSTEP(wf4, 4)   MSTEP(wf5, 5)   MSTEP(wf6, 6)   MSTEP(wf7, 7)
            MSTEP(wf8, 8)   MSTEP(wf9, 9)   MSTEP(wf10, 10) MSTEP(wf11, 11)
            MSTEP(wf12, 12) MSTEP(wf13, 13) MSTEP(wf14, 14) MSTEP(wf15, 15)
#undef MSTEP
            acc = (a0 + a1) + (a2 + a3);
        }
        {
            float g = gf_cur + acc;             // bias_eff pre-folded into finp
            if (!changed) g += wtail0_r * prev0;  // tempo term (changed: added post-update)
            g_s[t] = g;
        }
        gf_cur = gf_pre;

        // wave1: finalize step i-1 outputs (hf_s still = h(i-1))
        if (wave == 1 && i > 0) {
            int dd = lane >> 3, rl = lane & 7;
            int d2i = 8 + dd;
            float po1 = 0.f, po2 = 0.f;
            for (int k2 = 0; k2 < 16; ++k2) {
                int r = rl + (k2 << 3);
                float hv = hf_s[r];
                po1 += hv * wfcT[r][dd];
                if (d2i < D_) po2 += hv * wfcT[r][d2i];
            }
            po1 += __shfl_xor(po1, 1); po1 += __shfl_xor(po1, 2); po1 += __shfl_xor(po1, 4);
            po2 += __shfl_xor(po2, 1); po2 += __shfl_xor(po2, 2); po2 += __shfl_xor(po2, 4);
            int pi = i - 1;
            int pd = (int)((padw_s[pi >> 6] >> (pi & 63)) & 1ULL);
            float* orow = out + (size_t)((b << 11) + pi) * OUT_;
            float* xrow = xgb + (size_t)pi * 16;
            if (rl == 0) {
                float od = po1 + bfc_s[dd];
                xrow[dd] = od;
                orow[1 + dd] = pd ? 0.f : od;
                if (d2i < D_) {
                    float od2 = po2 + bfc_s[d2i];
                    xrow[d2i] = od2;
                    orow[1 + d2i] = pd ? 0.f : od2;
                }
            }
            if (lane == 1) orow[0] = pd ? 0.f : prev0;
        }

        if (changed) {
            // tempo gate partial from LDS fp16 Whh_t: tpre + Whh_t.ht + wiht0*prev0
            float acct;
            {
                const u32x4* wq = (const u32x4*)(wht16_s + (size_t)t * TSTRIDE);
                const u32x4* hq = (const u32x4*)ht16_s;
                float a0 = 0.f, a1 = 0.f, a2 = 0.f, a3 = 0.f;
#pragma unroll
                for (int k = 0; k < 16; ++k) {
                    u32x4 W = wq[k];
                    u32x4 H = hq[k];
                    a0 = dot2f_(W.x, H.x, a0);
                    a1 = dot2f_(W.y, H.y, a1);
                    a2 = dot2f_(W.z, H.z, a2);
                    a3 = dot2f_(W.w, H.w, a3);
                }
                acct = (a0 + a1) + (a2 + a3);
            }
            gt_s[t] = gt_pre + acct + wiht_r[0] * prev0;
        }
        __syncthreads();  // B1

        if (!changed) {
            if (wave < 2) {
                int rr = lane + (wave << 6);
                float gi = g_s[rr], gff = g_s[128 + rr], gg = g_s[256 + rr], go = g_s[384 + rr];
                float c2 = sigm_(gff) * cf_s[rr] + sigm_(gi) * tanh_(gg);
                float h2 = sigm_(go) * tanh_(c2);
                cf_s[rr] = c2;
                hf_s[rr] = h2;
                hf16_s[rr] = (_Float16)h2;
            }
        } else {
            // attention over previous run [S_prev, i) on wave 0, x from global xg
            if (wave == 0) {
                int L = i - S_prev;
                const float4* xb = (const float4*)(xgb + (size_t)S_prev * 16);
                float lmax = -1e30f;
                for (int tt = lane; tt < L; tt += 64) {
                    float4 q0 = xb[tt * 4 + 0], q1 = xb[tt * 4 + 1], q2 = xb[tt * 4 + 2];
                    float s = sc_s[0] + q0.x * v_s[0] + q0.y * v_s[1] + q0.z * v_s[2] +
                              q0.w * v_s[3] + q1.x * v_s[4] + q1.y * v_s[5] +
                              q1.z * v_s[6] + q1.w * v_s[7] + q2.x * v_s[8] + q2.y * v_s[9];
                    lmax = fmaxf(lmax, s);
                }
#pragma unroll
                for (int off = 32; off; off >>= 1)
                    lmax = fmaxf(lmax, __shfl_xor(lmax, off, 64));
                float lsum = 0.f, lacc[D_] = {};
                for (int tt = lane; tt < L; tt += 64) {
                    float4 q0 = xb[tt * 4 + 0], q1 = xb[tt * 4 + 1], q2 = xb[tt * 4 + 2];
                    float s = sc_s[0] + q0.x * v_s[0] + q0.y * v_s[1] + q0.z * v_s[2] +
                              q0.w * v_s[3] + q1.x * v_s[4] + q1.y * v_s[5] +
                              q1.z * v_s[6] + q1.w * v_s[7] + q2.x * v_s[8] + q2.y * v_s[9];
                    float w = fexp2_(1.4426950408889634f * (s - lmax));
                    lsum += w;
                    lacc[0] += w * q0.x; lacc[1] += w * q0.y; lacc[2] += w * q0.z;
                    lacc[3] += w * q0.w; lacc[4] += w * q1.x; lacc[5] += w * q1.y;
                    lacc[6] += w * q1.z; lacc[7] += w * q1.w; lacc[8] += w * q2.x;
                    lacc[9] += w * q2.y;
                }
#pragma unroll
                for (int off = 32; off; off >>= 1) {
                    lsum += __shfl_xor(lsum, off, 64);
#pragma unroll
                    for (int d = 0; d < D_; ++d) lacc[d] += __shfl_xor(lacc[d], off, 64);
                }
                if (lane == 0) {
                    if (L > 0) {
                        float inv = 1.0f / lsum;
#pragma unroll
                        for (int d = 0; d < D_; ++d) cur_res[d] = lacc[d] * inv;
                    } else {
#pragma unroll
                        for (int d = 0; d < D_; ++d) cur_res[d] = 0.f;
                    }
                }
            }
            __syncthreads();  // B_c2: cur_res visible
            {
                float gv = gt_s[t];
#pragma unroll
                for (int d = 0; d < D_; ++d) gv += wiht_r[1 + d] * cur_res[d];
                gt_s[t] = gv;
            }
            __syncthreads();  // B_c3: tempo gate vector ready
            if (wave == 0) {
                float p = 0.f;
#pragma unroll
                for (int hb = 0; hb < 2; ++hb) {
                    int rr = lane + (hb << 6);
                    float gi = gt_s[rr], gff = gt_s[128 + rr], gg = gt_s[256 + rr],
                          go = gt_s[384 + rr];
                    float c2 = sigm_(gff) * ct_s[rr] + sigm_(gi) * tanh_(gg);
                    float h2 = sigm_(go) * tanh_(c2);
                    ct_s[rr] = c2;
                    ht_s[rr] = h2;
                    ht16_s[rr] = (_Float16)h2;
                    p += h2 * wtfc_s[rr];
                }
#pragma unroll
                for (int off = 32; off; off >>= 1) p += __shfl_xor(p, off, 64);
                float tnew = p + sc_s[1];
                if (lane == 0) sc_s[2] = tnew;
#pragma unroll
                for (int hb = 0; hb < 2; ++hb) {
                    int rr = lane + (hb << 6);
                    float gi = g_s[rr] + wtail0_s[rr] * tnew;
                    float gff = g_s[128 + rr] + wtail0_s[128 + rr] * tnew;
                    float gg = g_s[256 + rr] + wtail0_s[256 + rr] * tnew;
                    float go = g_s[384 + rr] + wtail0_s[384 + rr] * tnew;
                    float c2 = sigm_(gff) * cf_s[rr] + sigm_(gi) * tanh_(gg);
                    float h2 = sigm_(go) * tanh_(c2);
                    cf_s[rr] = c2;
                    hf_s[rr] = h2;
                    hf16_s[rr] = (_Float16)h2;
                }
            }
            // prefetch tpre row for next run
            if (cur_run + 1 < nruns_r)
                gt_pre = tpre[(size_t)(b * NBEATS_ + (int)run_cb_s[cur_run + 1]) * 512 + t];
        }
        __syncthreads();  // Bend
    }

    // epilogue: outputs for i = N_-1
    if (wave == 1) {
        int dd = lane >> 3, rl = lane & 7;
        int d2i = 8 + dd;
        float po1 = 0.f, po2 = 0.f;
        for (int k2 = 0; k2 < 16; ++k2) {
            int r = rl + (k2 << 3);
            float hv = hf_s[r];
            po1 += hv * wfcT[r][dd];
            if (d2i < D_) po2 += hv * wfcT[r][d2i];
        }
        po1 += __shfl_xor(po1, 1); po1 += __shfl_xor(po1, 2); po1 += __shfl_xor(po1, 4);
        po2 += __shfl_xor(po2, 1); po2 += __shfl_xor(po2, 2); po2 += __shfl_xor(po2, 4);
        int pi = N_ - 1;
        int pd = (int)((padw_s[pi >> 6] >> (pi & 63)) & 1ULL);
        float* orow = out + (size_t)((b << 11) + pi) * OUT_;
        if (rl == 0) {
            orow[1 + dd] = pd ? 0.f : (po1 + bfc_s[dd]);
            if (d2i < D_) orow[1 + d2i] = pd ? 0.f : (po2 + bfc_s[d2i]);
        }
        if (lane == 1) orow[0] = pd ? 0.f : sc_s[2];
    }
}

// ---------------------------------------------------------------------------
extern "C" void kernel_launch(void* const* d_in, const int* in_sizes, int n_in,
                              void* d_out, int out_size, void* d_ws, size_t ws_size,
                              hipStream_t stream) {
    const float* note  = (const float*)d_in[0];
    const float* beat  = (const float*)d_in[1];
    const float* meas  = (const float*)d_in[2];
    const int*   bnum  = (const int*)d_in[3];
    const int*   mnum  = (const int*)d_in[4];
    const float* Wa    = (const float*)d_in[5];
    const float* ba    = (const float*)d_in[6];
    const float* ctx   = (const float*)d_in[7];
    const float* Wih_t = (const float*)d_in[8];
    const float* Whh_t = (const float*)d_in[9];
    const float* bih_t = (const float*)d_in[10];
    const float* bhh_t = (const float*)d_in[11];
    const float* Wih_f = (const float*)d_in[12];
    const float* Whh_f = (const float*)d_in[13];
    const float* bih_f = (const float*)d_in[14];
    const float* bhh_f = (const float*)d_in[15];
    const float* W_fc  = (const float*)d_in[16];
    const float* b_fc  = (const float*)d_in[17];
    const float* W_tfc = (const float*)d_in[18];
    const float* b_tfc = (const float*)d_in[19];
    float* out = (float*)d_out;

    char* ws = (char*)d_ws;
    float* finp = (float*)ws;                                   // 64 MB
    float* tpre = (float*)(ws + (size_t)64 * 1024 * 1024);      // 8 MB
    int*   padf = (int*)(ws + (size_t)72 * 1024 * 1024);        // 128 KB
    float* xg   = (float*)(ws + (size_t)73 * 1024 * 1024);      // 2 MB

    pad_k<<<8192, 256, 0, stream>>>(note, padf);
    fold_whh<<<512, 128, 0, stream>>>(Whh_f, Wih_f, W_fc, b_fc);
    fold_wht<<<512, 128, 0, stream>>>(Whh_t);
    tempo_pre_k<<<dim3(16, 16), 256, 0, stream>>>(beat, meas, bnum, mnum, Wih_t,
                                                  bih_t, bhh_t, tpre);
    fin_pre_gemm<<<dim3(512, 8), 256, 0, stream>>>(note, beat, meas, bnum, mnum,
                                                   Wih_f, bih_f, bhh_f, finp);
    decode_seq<<<16, 512, 0, stream>>>(finp, tpre, bnum, padf, Wih_t,
                                       W_fc, b_fc, W_tfc, b_tfc, Wa, ba, ctx,
                                       out, xg);
}